// Round 1
// baseline (1990.586 us; speedup 1.0000x reference)
//
#include <hip/hip_runtime.h>
#include <math.h>

#define N_NODES 10000
#define E_EDGES 320000
#define D_INF   256
#define HIDF    128
#define M_TRAIN 100000
#define P_PAIRS 15000
#define TILES   157   // ceil(10000/64)

__device__ __forceinline__ float wred64(float v) {
#pragma unroll
    for (int o = 32; o > 0; o >>= 1) v += __shfl_xor(v, o, 64);
    return v;
}

// ---------------- GEMM: sup = x @ W + b  (N x 256) @ (256 x 128) ------------
__global__ __launch_bounds__(256) void k_gemm(const float* __restrict__ x,
                                              const float* __restrict__ W,
                                              const float* __restrict__ b,
                                              float* __restrict__ sup) {
    __shared__ float xs[16 * 256];
    const int t = threadIdx.x, blk = blockIdx.x;
    const float4* xg = (const float4*)(x + (size_t)blk * 16 * 256);
    float4* xs4 = (float4*)xs;
#pragma unroll
    for (int v = 0; v < 4; v++) xs4[v * 256 + t] = xg[v * 256 + t];
    __syncthreads();
    const int col = t & 127, rg = t >> 7;
    float acc[8];
    const float bb = b[col];
#pragma unroll
    for (int r = 0; r < 8; r++) acc[r] = bb;
    const float* xrow = xs + rg * 8 * 256;
    for (int k = 0; k < 256; k++) {
        const float w = W[k * 128 + col];
#pragma unroll
        for (int r = 0; r < 8; r++) acc[r] += xrow[r * 256 + k] * w;
    }
    float* outp = sup + ((size_t)blk * 16 + rg * 8) * 128 + col;
#pragma unroll
    for (int r = 0; r < 8; r++) outp[r * 128] = acc[r];
}

// ---------------- scatter: h[dst] += sup[src] * val -------------------------
__global__ __launch_bounds__(256) void k_scatter(const float* __restrict__ sup,
                                                 const int* __restrict__ src,
                                                 const int* __restrict__ dst,
                                                 const float* __restrict__ val,
                                                 float* __restrict__ h) {
    const int t = blockIdx.x * 256 + threadIdx.x;
    const int e = t >> 5, g = t & 31;
    const int s = src[e], d = dst[e];
    const float v = val[e];
    const float4 m = ((const float4*)sup)[s * 32 + g];
    float* hp = h + (size_t)d * 128 + g * 4;
    atomicAdd(hp + 0, m.x * v);
    atomicAdd(hp + 1, m.y * v);
    atomicAdd(hp + 2, m.z * v);
    atomicAdd(hp + 3, m.w * v);
}

// ------------- per-half L2 normalize, write into x_all (d_out) --------------
__global__ __launch_bounds__(256) void k_halfnorm(const float* __restrict__ h,
                                                  float* __restrict__ out, int c) {
    const int t = threadIdx.x;
    const int node = blockIdx.x * 4 + (t >> 6), lane = t & 63;
    const float2 v = ((const float2*)h)[node * 64 + lane];
    const float s = wred64(v.x * v.x + v.y * v.y);
    const float inv = 1.0f / sqrtf(s);
    ((float2*)out)[node * 128 + c * 64 + lane] = make_float2(v.x * inv, v.y * inv);
}

// ------------- rn[i] = 1/||x_all[i]|| ---------------------------------------
__global__ __launch_bounds__(256) void k_rownorm(const float* __restrict__ xall,
                                                 float* __restrict__ rn) {
    const int t = threadIdx.x;
    const int node = blockIdx.x * 4 + (t >> 6), lane = t & 63;
    const float4 v = ((const float4*)xall)[node * 64 + lane];
    const float s = wred64(v.x * v.x + v.y * v.y + v.z * v.z + v.w * v.w);
    if (lane == 0) rn[node] = 1.0f / sqrtf(s);
}

// ------------- neg_s[i] = cos(x_i, x_negrow[i]) -----------------------------
__global__ __launch_bounds__(256) void k_negs(const float* __restrict__ xall,
                                              const float* __restrict__ rn,
                                              const int* __restrict__ neg_row,
                                              float* __restrict__ neg_s) {
    const int t = threadIdx.x;
    const int node = blockIdx.x * 4 + (t >> 6), lane = t & 63;
    const int j = neg_row[node];
    const float4 a = ((const float4*)xall)[node * 64 + lane];
    const float4 b = ((const float4*)xall)[j * 64 + lane];
    const float d = wred64(a.x * b.x + a.y * b.y + a.z * b.z + a.w * b.w);
    if (lane == 0) neg_s[node] = d * rn[node] * rn[j];
}

// ------------- lc partials: gamma^(L+1) * log_sigmoid(sim/tau) --------------
__global__ __launch_bounds__(256) void k_lc(const float* __restrict__ xall,
                                            const float* __restrict__ rn,
                                            const int* __restrict__ na,
                                            const int* __restrict__ nb,
                                            const int* __restrict__ nl,
                                            float* __restrict__ partial) {
    __shared__ float wsum[4];
    const int t = threadIdx.x, wid = t >> 6, lane = t & 63;
    const int p = blockIdx.x * 4 + wid;
    const int a = na[p], b = nb[p];
    const float4 av = ((const float4*)xall)[a * 64 + lane];
    const float4 bv = ((const float4*)xall)[b * 64 + lane];
    const float d = wred64(av.x * bv.x + av.y * bv.y + av.z * bv.z + av.w * bv.w);
    if (lane == 0) {
        const float sim = d * rn[a] * rn[b];
        const float z = sim / 0.5f;                 // sim / TAU0
        const float logsig = -log1pf(expf(-z));     // log_sigmoid(z)
        const float g = ldexpf(1.0f, -(nl[p] + 1)); // 0.5^(L+1), exact
        wsum[wid] = g * logsig;
    }
    __syncthreads();
    if (t == 0) partial[blockIdx.x] = wsum[0] + wsum[1] + wsum[2] + wsum[3];
}

// ------------- loss_real partials -------------------------------------------
__global__ __launch_bounds__(256) void k_real(const float* __restrict__ xall,
                                              const float* __restrict__ rn,
                                              const int* __restrict__ train,
                                              const int* __restrict__ negidx,
                                              float* __restrict__ partial) {
    __shared__ float wsum[4];
    const int t = threadIdx.x, wid = t >> 6, lane = t & 63;
    const int m = blockIdx.x * 4 + wid;
    const int s = train[2 * m], e = train[2 * m + 1], g = negidx[m];
    const float4* X4 = (const float4*)xall;
    const float4 a = X4[s * 64 + lane];
    const float4 b = X4[e * 64 + lane];
    const float4 c = X4[g * 64 + lane];
    float dp = a.x * b.x + a.y * b.y + a.z * b.z + a.w * b.w;
    float dn = a.x * c.x + a.y * c.y + a.z * c.z + a.w * c.w;
    dp = wred64(dp);
    dn = wred64(dn);
    if (lane == 0) {
        const float rs = rn[s];
        const float pos = dp * rs * rn[e];
        const float neg = dn * rs * rn[g];
        const float d0 = (pos - 0.1f) * (1.0f / 0.9f);
        const float w = d0 * d0;
        wsum[wid] = w * log1pf(expf(neg - pos));
    }
    __syncthreads();
    if (t == 0) partial[blockIdx.x] = wsum[0] + wsum[1] + wsum[2] + wsum[3];
}

// ------------- loss_pseudo: fused tiled xn@xn^T + threshold epilogue --------
// 64x64 tile per block, 256 threads, 4x4 micro-tile per thread, BK=32.
__global__ __launch_bounds__(256) void k_pseudo(const float* __restrict__ xall,
                                                const float* __restrict__ rn,
                                                const float* __restrict__ neg_s,
                                                float* __restrict__ partial) {
    const int ti = blockIdx.y, tj = blockIdx.x;
    const int bid = ti * TILES + tj;
    const int t = threadIdx.x;
    if (tj < ti) {                 // lower-triangular tile: contributes nothing
        if (t == 0) partial[bid] = 0.0f;
        return;
    }
    __shared__ float As[64 * 36];  // [i][k], pad 36 keeps 16B align, spreads banks
    __shared__ float Bs[64 * 36];
    __shared__ float wsum[4];
    const int tx = t & 15, ty = t >> 4;
    float acc[4][4] = {};
    const int i0 = ti * 64, j0 = tj * 64;
    const float4* X4 = (const float4*)xall;
    const int li = t >> 2, kg = t & 3;

    for (int kt = 0; kt < 8; kt++) {
        {   // stage 64x32 A and B tiles (each thread: 8 floats of each)
            const int gi = i0 + li;
            float4 v0 = {0, 0, 0, 0}, v1 = {0, 0, 0, 0};
            if (gi < N_NODES) {
                v0 = X4[gi * 64 + kt * 8 + kg * 2];
                v1 = X4[gi * 64 + kt * 8 + kg * 2 + 1];
            }
            *(float4*)&As[li * 36 + kg * 8]     = v0;
            *(float4*)&As[li * 36 + kg * 8 + 4] = v1;
            const int gj = j0 + li;
            float4 w0 = {0, 0, 0, 0}, w1 = {0, 0, 0, 0};
            if (gj < N_NODES) {
                w0 = X4[gj * 64 + kt * 8 + kg * 2];
                w1 = X4[gj * 64 + kt * 8 + kg * 2 + 1];
            }
            *(float4*)&Bs[li * 36 + kg * 8]     = w0;
            *(float4*)&Bs[li * 36 + kg * 8 + 4] = w1;
        }
        __syncthreads();
#pragma unroll
        for (int k = 0; k < 32; k += 2) {
            float2 av[4], bv[4];
#pragma unroll
            for (int r = 0; r < 4; r++) {
                av[r] = *(const float2*)&As[(ty * 4 + r) * 36 + k];
                bv[r] = *(const float2*)&Bs[(tx * 4 + r) * 36 + k];
            }
#pragma unroll
            for (int r = 0; r < 4; r++)
#pragma unroll
                for (int c = 0; c < 4; c++)
                    acc[r][c] += av[r].x * bv[c].x + av[r].y * bv[c].y;
        }
        __syncthreads();
    }

    float local = 0.0f;
#pragma unroll
    for (int r = 0; r < 4; r++) {
        const int i = i0 + ty * 4 + r;
        if (i >= N_NODES) continue;
        const float rni = rn[i];
        const float nsi = neg_s[i];
#pragma unroll
        for (int c = 0; c < 4; c++) {
            const int j = j0 + tx * 4 + c;
            if (j < N_NODES && j > i) {
                const float s = acc[r][c] * rni * rn[j];
                if (s > 0.95f) {
                    const float d0 = (s - 0.1f) * (1.0f / 0.9f);
                    local += d0 * d0 * log1pf(expf(nsi - s));
                }
            }
        }
    }
    local = wred64(local);
    if ((t & 63) == 0) wsum[t >> 6] = local;
    __syncthreads();
    if (t == 0) partial[bid] = wsum[0] + wsum[1] + wsum[2] + wsum[3];
}

// ------------- final reduction: loss = real + pseudo - sum(lc)/P ------------
__global__ __launch_bounds__(256) void k_final(const float* __restrict__ preal,
                                               const float* __restrict__ ppseudo,
                                               const float* __restrict__ plc,
                                               float* __restrict__ out_loss) {
    __shared__ float wsum[4];
    const int t = threadIdx.x;
    float sr = 0.0f, sp = 0.0f, sl = 0.0f;
    for (int i = t; i < 25000; i += 256) sr += preal[i];
    for (int i = t; i < TILES * TILES; i += 256) sp += ppseudo[i];
    for (int i = t; i < 3750; i += 256) sl += plc[i];
    float contrib = sr + sp - sl * (1.0f / (float)P_PAIRS);
    contrib = wred64(contrib);
    if ((t & 63) == 0) wsum[t >> 6] = contrib;
    __syncthreads();
    if (t == 0) out_loss[0] = wsum[0] + wsum[1] + wsum[2] + wsum[3];
}

extern "C" void kernel_launch(void* const* d_in, const int* in_sizes, int n_in,
                              void* d_out, int out_size, void* d_ws, size_t ws_size,
                              hipStream_t stream) {
    const float* x0   = (const float*)d_in[0];
    const float* x1   = (const float*)d_in[1];
    const int*   a0s  = (const int*)d_in[2];
    const int*   a0d  = (const int*)d_in[3];
    const float* a0v  = (const float*)d_in[4];
    const int*   a1s  = (const int*)d_in[5];
    const int*   a1d  = (const int*)d_in[6];
    const float* a1v  = (const float*)d_in[7];
    const int*   trn  = (const int*)d_in[8];
    const int*   ngi  = (const int*)d_in[9];
    const int*   ngr  = (const int*)d_in[10];
    const int*   na   = (const int*)d_in[11];
    const int*   nb   = (const int*)d_in[12];
    const int*   nl   = (const int*)d_in[13];
    const float* W0   = (const float*)d_in[14];
    const float* b0   = (const float*)d_in[15];
    const float* W1   = (const float*)d_in[16];
    const float* b1   = (const float*)d_in[17];

    float* xall = (float*)d_out;                 // N x 256
    float* loss = xall + (size_t)N_NODES * 256;  // scalar

    float* ws      = (float*)d_ws;
    float* sup     = ws;                 // 1,280,000 floats
    float* h       = ws + 1280000;       // 1,280,000
    float* rn      = ws + 2560000;       // 10,000
    float* negs    = ws + 2570000;       // 10,000
    float* preal   = ws + 2580000;       // 25,000
    float* ppseudo = ws + 2605000;       // 24,649
    float* plc     = ws + 2630000;       // 3,750

    for (int c = 0; c < 2; c++) {
        const float* x = c ? x1 : x0;
        const float* W = c ? W1 : W0;
        const float* b = c ? b1 : b0;
        const int*   es = c ? a1s : a0s;
        const int*   ed = c ? a1d : a0d;
        const float* ev = c ? a1v : a0v;
        k_gemm<<<625, 256, 0, stream>>>(x, W, b, sup);
        hipMemsetAsync(h, 0, (size_t)1280000 * sizeof(float), stream);
        k_scatter<<<E_EDGES * 32 / 256, 256, 0, stream>>>(sup, es, ed, ev, h);
        k_halfnorm<<<2500, 256, 0, stream>>>(h, xall, c);
    }
    k_rownorm<<<2500, 256, 0, stream>>>(xall, rn);
    k_negs<<<2500, 256, 0, stream>>>(xall, rn, ngr, negs);
    k_lc<<<3750, 256, 0, stream>>>(xall, rn, na, nb, nl, plc);
    k_real<<<25000, 256, 0, stream>>>(xall, rn, trn, ngi, preal);
    dim3 gp(TILES, TILES);
    k_pseudo<<<gp, 256, 0, stream>>>(xall, rn, negs, ppseudo);
    k_final<<<1, 256, 0, stream>>>(preal, ppseudo, plc, loss);
}

// Round 2
// 562.555 us; speedup vs baseline: 3.5385x; 3.5385x over previous
//
#include <hip/hip_runtime.h>
#include <math.h>

#define N_NODES 10000
#define E_EDGES 320000
#define M_TRAIN 100000
#define P_PAIRS 15000
#define TILES   157           // ceil(10000/64)
#define NTRI    12403         // TILES*(TILES+1)/2
#define NPAD    10048         // padded row count for bf16 matrix (157*64)
#define EXACT_BLOCKS 256

typedef __attribute__((ext_vector_type(8))) short short8;   // 8 bf16 (4 VGPRs)
typedef __attribute__((ext_vector_type(4))) float f32x4;

__device__ __forceinline__ float wred64(float v) {
#pragma unroll
    for (int o = 32; o > 0; o >>= 1) v += __shfl_xor(v, o, 64);
    return v;
}

__device__ __forceinline__ unsigned short f2bf(float f) {   // RNE float->bf16
    unsigned u = __float_as_uint(f);
    u += 0x7fffu + ((u >> 16) & 1u);
    return (unsigned short)(u >> 16);
}

// ---------------- GEMM: sup = x @ W + b  (N x 256) @ (256 x 128) ------------
__global__ __launch_bounds__(256) void k_gemm(const float* __restrict__ x,
                                              const float* __restrict__ W,
                                              const float* __restrict__ b,
                                              float* __restrict__ sup) {
    __shared__ float xs[16 * 256];
    const int t = threadIdx.x, blk = blockIdx.x;
    const float4* xg = (const float4*)(x + (size_t)blk * 16 * 256);
    float4* xs4 = (float4*)xs;
#pragma unroll
    for (int v = 0; v < 4; v++) xs4[v * 256 + t] = xg[v * 256 + t];
    __syncthreads();
    const int col = t & 127, rg = t >> 7;
    float acc[8];
    const float bb = b[col];
#pragma unroll
    for (int r = 0; r < 8; r++) acc[r] = bb;
    const float* xrow = xs + rg * 8 * 256;
    for (int k = 0; k < 256; k++) {
        const float w = W[k * 128 + col];
#pragma unroll
        for (int r = 0; r < 8; r++) acc[r] += xrow[r * 256 + k] * w;
    }
    float* outp = sup + ((size_t)blk * 16 + rg * 8) * 128 + col;
#pragma unroll
    for (int r = 0; r < 8; r++) outp[r * 128] = acc[r];
}

// ---------------- counting sort of edges by dst -----------------------------
__global__ __launch_bounds__(256) void k_hist(const int* __restrict__ dst,
                                              int* __restrict__ hist) {
    const int e = blockIdx.x * 256 + threadIdx.x;
    atomicAdd(&hist[dst[e]], 1);
}

__global__ __launch_bounds__(256) void k_scan(const int* __restrict__ hist,
                                              int* __restrict__ off,
                                              int* __restrict__ cur) {
    __shared__ int s[256];
    const int t = threadIdx.x;
    int loc[40];
    int sum = 0;
    const int base = t * 40;
#pragma unroll
    for (int i = 0; i < 40; i++) { loc[i] = hist[base + i]; sum += loc[i]; }
    s[t] = sum;
    __syncthreads();
    for (int o = 1; o < 256; o <<= 1) {
        int v = (t >= o) ? s[t - o] : 0;
        __syncthreads();
        s[t] += v;
        __syncthreads();
    }
    int run = s[t] - sum;   // exclusive prefix
#pragma unroll
    for (int i = 0; i < 40; i++) {
        off[base + i] = run;
        cur[base + i] = run;
        run += loc[i];
    }
}

__global__ __launch_bounds__(256) void k_reorder(const int* __restrict__ src,
                                                 const int* __restrict__ dst,
                                                 const float* __restrict__ val,
                                                 int* __restrict__ cur,
                                                 int* __restrict__ src_s,
                                                 float* __restrict__ val_s) {
    const int e = blockIdx.x * 256 + threadIdx.x;
    const int d = dst[e];
    const int p = atomicAdd(&cur[d], 1);
    src_s[p] = src[e];
    val_s[p] = val[e];
}

// ---- CSR aggregate + fused per-half L2 normalize: one wave per dst node ----
__global__ __launch_bounds__(256) void k_agg(const float* __restrict__ sup,
                                             const int* __restrict__ off,
                                             const int* __restrict__ hist,
                                             const int* __restrict__ src_s,
                                             const float* __restrict__ val_s,
                                             float* __restrict__ xall, int c) {
    const int t = threadIdx.x;
    const int node = blockIdx.x * 4 + (t >> 6), lane = t & 63;
    const int s0 = off[node], cnt = hist[node];
    const float2* S2 = (const float2*)sup;
    float2 a0 = {0.f, 0.f}, a1 = {0.f, 0.f};
    int e = s0;
    const int end = s0 + cnt;
    for (; e + 1 < end; e += 2) {
        const int sA = src_s[e], sB = src_s[e + 1];
        const float vA = val_s[e], vB = val_s[e + 1];
        const float2 mA = S2[(size_t)sA * 64 + lane];
        const float2 mB = S2[(size_t)sB * 64 + lane];
        a0.x += mA.x * vA; a0.y += mA.y * vA;
        a1.x += mB.x * vB; a1.y += mB.y * vB;
    }
    if (e < end) {
        const int sA = src_s[e];
        const float vA = val_s[e];
        const float2 mA = S2[(size_t)sA * 64 + lane];
        a0.x += mA.x * vA; a0.y += mA.y * vA;
    }
    a0.x += a1.x; a0.y += a1.y;
    const float s = wred64(a0.x * a0.x + a0.y * a0.y);
    const float inv = 1.0f / sqrtf(s);
    ((float2*)xall)[(size_t)node * 128 + c * 64 + lane] =
        make_float2(a0.x * inv, a0.y * inv);
}

// ------------- rn[i] = 1/||x_all[i]|| ---------------------------------------
__global__ __launch_bounds__(256) void k_rownorm(const float* __restrict__ xall,
                                                 float* __restrict__ rn) {
    const int t = threadIdx.x;
    const int node = blockIdx.x * 4 + (t >> 6), lane = t & 63;
    const float4 v = ((const float4*)xall)[node * 64 + lane];
    const float s = wred64(v.x * v.x + v.y * v.y + v.z * v.z + v.w * v.w);
    if (lane == 0) rn[node] = 1.0f / sqrtf(s);
}

// ------------- xbf[i][k] = bf16(xall[i][k] * rn[i]), zero-padded rows -------
__global__ __launch_bounds__(256) void k_tobf(const float* __restrict__ xall,
                                              const float* __restrict__ rn,
                                              unsigned short* __restrict__ xbf) {
    const int tid = blockIdx.x * 256 + threadIdx.x;  // 1 float4 per thread
    const int row = tid >> 6, cq = tid & 63;
    unsigned o0 = 0, o1 = 0;
    if (row < N_NODES) {
        float4 v = ((const float4*)xall)[(size_t)row * 64 + cq];
        const float r = rn[row];
        o0 = (unsigned)f2bf(v.x * r) | ((unsigned)f2bf(v.y * r) << 16);
        o1 = (unsigned)f2bf(v.z * r) | ((unsigned)f2bf(v.w * r) << 16);
    }
    ((uint2*)xbf)[tid] = make_uint2(o0, o1);
}

// ------------- neg_s[i] = cos(x_i, x_negrow[i]) -----------------------------
__global__ __launch_bounds__(256) void k_negs(const float* __restrict__ xall,
                                              const float* __restrict__ rn,
                                              const int* __restrict__ neg_row,
                                              float* __restrict__ neg_s) {
    const int t = threadIdx.x;
    const int node = blockIdx.x * 4 + (t >> 6), lane = t & 63;
    const int j = neg_row[node];
    const float4 a = ((const float4*)xall)[node * 64 + lane];
    const float4 b = ((const float4*)xall)[j * 64 + lane];
    const float d = wred64(a.x * b.x + a.y * b.y + a.z * b.z + a.w * b.w);
    if (lane == 0) neg_s[node] = d * rn[node] * rn[j];
}

// ------------- lc partials --------------------------------------------------
__global__ __launch_bounds__(256) void k_lc(const float* __restrict__ xall,
                                            const float* __restrict__ rn,
                                            const int* __restrict__ na,
                                            const int* __restrict__ nb,
                                            const int* __restrict__ nl,
                                            float* __restrict__ partial) {
    __shared__ float wsum[4];
    const int t = threadIdx.x, wid = t >> 6, lane = t & 63;
    const int p = blockIdx.x * 4 + wid;
    const int a = na[p], b = nb[p];
    const float4 av = ((const float4*)xall)[a * 64 + lane];
    const float4 bv = ((const float4*)xall)[b * 64 + lane];
    const float d = wred64(av.x * bv.x + av.y * bv.y + av.z * bv.z + av.w * bv.w);
    if (lane == 0) {
        const float sim = d * rn[a] * rn[b];
        const float z = sim / 0.5f;
        const float logsig = -log1pf(expf(-z));
        const float g = ldexpf(1.0f, -(nl[p] + 1));
        wsum[wid] = g * logsig;
    }
    __syncthreads();
    if (t == 0) partial[blockIdx.x] = wsum[0] + wsum[1] + wsum[2] + wsum[3];
}

// ------------- loss_real partials -------------------------------------------
__global__ __launch_bounds__(256) void k_real(const float* __restrict__ xall,
                                              const float* __restrict__ rn,
                                              const int* __restrict__ train,
                                              const int* __restrict__ negidx,
                                              float* __restrict__ partial) {
    __shared__ float wsum[4];
    const int t = threadIdx.x, wid = t >> 6, lane = t & 63;
    const int m = blockIdx.x * 4 + wid;
    const int s = train[2 * m], e = train[2 * m + 1], g = negidx[m];
    const float4* X4 = (const float4*)xall;
    const float4 a = X4[s * 64 + lane];
    const float4 b = X4[e * 64 + lane];
    const float4 c = X4[g * 64 + lane];
    float dp = a.x * b.x + a.y * b.y + a.z * b.z + a.w * b.w;
    float dn = a.x * c.x + a.y * c.y + a.z * c.z + a.w * c.w;
    dp = wred64(dp);
    dn = wred64(dn);
    if (lane == 0) {
        const float rs = rn[s];
        const float pos = dp * rs * rn[e];
        const float neg = dn * rs * rn[g];
        const float d0 = (pos - 0.1f) * (1.0f / 0.9f);
        wsum[wid] = d0 * d0 * log1pf(expf(neg - pos));
    }
    __syncthreads();
    if (t == 0) partial[blockIdx.x] = wsum[0] + wsum[1] + wsum[2] + wsum[3];
}

// ------------- phase A: bf16 MFMA filter over upper-tri 64x64 tiles ---------
// 4 waves/block; wave w computes 32x32 quadrant via 2x2 of 16x16x32 MFMAs.
// Layouts (HW-verified, guide §3): A[m=lane&15][k=(lane>>4)*8+j],
// B[n=lane&15][k=(lane>>4)*8+j] (B operand = X^T), C/D col=lane&15,
// row=(lane>>4)*4+reg.
__global__ __launch_bounds__(256) void k_filter(const unsigned short* __restrict__ xbf,
                                                int* __restrict__ count,
                                                int* __restrict__ list) {
    __shared__ int bflag;
    const int u = blockIdx.x;
    // decode upper-triangular (ti,tj), row-major, diagonal included
    int i = (int)((2.0 * TILES + 1.0 -
                   sqrt((2.0 * TILES + 1.0) * (2.0 * TILES + 1.0) - 8.0 * (double)u)) * 0.5);
    if (i < 0) i = 0;
    while ((i + 1) * TILES - ((i + 1) * i) / 2 <= u) i++;
    while (i * TILES - (i * (i - 1)) / 2 > u) i--;
    const int ti = i;
    const int tj = i + (u - (i * TILES - (i * (i - 1)) / 2));

    const int t = threadIdx.x, wave = t >> 6, lane = t & 63;
    if (t == 0) bflag = 0;
    __syncthreads();

    const int wi = wave >> 1, wj = wave & 1;
    const int r0 = ti * 64 + wi * 32, c0 = tj * 64 + wj * 32;
    const int m = lane & 15, kq = lane >> 4;

    f32x4 acc00 = {0.f, 0.f, 0.f, 0.f}, acc01 = acc00, acc10 = acc00, acc11 = acc00;
#pragma unroll
    for (int k0 = 0; k0 < 256; k0 += 32) {
        const short8 a0 = *(const short8*)(xbf + (size_t)(r0 + m) * 256 + k0 + kq * 8);
        const short8 a1 = *(const short8*)(xbf + (size_t)(r0 + 16 + m) * 256 + k0 + kq * 8);
        const short8 b0 = *(const short8*)(xbf + (size_t)(c0 + m) * 256 + k0 + kq * 8);
        const short8 b1 = *(const short8*)(xbf + (size_t)(c0 + 16 + m) * 256 + k0 + kq * 8);
        acc00 = __builtin_amdgcn_mfma_f32_16x16x32_bf16(a0, b0, acc00, 0, 0, 0);
        acc01 = __builtin_amdgcn_mfma_f32_16x16x32_bf16(a0, b1, acc01, 0, 0, 0);
        acc10 = __builtin_amdgcn_mfma_f32_16x16x32_bf16(a1, b0, acc10, 0, 0, 0);
        acc11 = __builtin_amdgcn_mfma_f32_16x16x32_bf16(a1, b1, acc11, 0, 0, 0);
    }

    bool hit = false;
#pragma unroll
    for (int R = 0; R < 2; R++)
#pragma unroll
        for (int C = 0; C < 2; C++) {
            const f32x4 a = R ? (C ? acc11 : acc10) : (C ? acc01 : acc00);
#pragma unroll
            for (int reg = 0; reg < 4; reg++) {
                const int ii = r0 + R * 16 + kq * 4 + reg;
                const int jj = c0 + C * 16 + m;
                if (jj > ii && ii < N_NODES && jj < N_NODES && a[reg] > 0.94f)
                    hit = true;
            }
        }
    if (hit) bflag = 1;
    __syncthreads();
    if (t == 0 && bflag) {
        const int slot = atomicAdd(count, 1);
        list[slot] = (ti << 16) | tj;
    }
}

// ------------- phase B: exact fp32 recompute of flagged tiles ---------------
__global__ __launch_bounds__(256) void k_exact(const float* __restrict__ xall,
                                               const float* __restrict__ rn,
                                               const float* __restrict__ neg_s,
                                               const int* __restrict__ count,
                                               const int* __restrict__ list,
                                               float* __restrict__ pexact) {
    __shared__ float As[64 * 36];
    __shared__ float Bs[64 * 36];
    __shared__ float wsum[4];
    const int t = threadIdx.x;
    const int tx = t & 15, ty = t >> 4;
    const int li = t >> 2, kg = t & 3;
    const float4* X4 = (const float4*)xall;
    const int cnt = *count;
    float total = 0.0f;

    for (int idx = blockIdx.x; idx < cnt; idx += EXACT_BLOCKS) {
        const int pk = list[idx];
        const int ti = pk >> 16, tj = pk & 0xffff;
        const int i0 = ti * 64, j0 = tj * 64;
        float acc[4][4] = {};
        for (int kt = 0; kt < 8; kt++) {
            {
                const int gi = i0 + li;
                float4 v0 = {0, 0, 0, 0}, v1 = {0, 0, 0, 0};
                if (gi < N_NODES) {
                    v0 = X4[gi * 64 + kt * 8 + kg * 2];
                    v1 = X4[gi * 64 + kt * 8 + kg * 2 + 1];
                }
                *(float4*)&As[li * 36 + kg * 8]     = v0;
                *(float4*)&As[li * 36 + kg * 8 + 4] = v1;
                const int gj = j0 + li;
                float4 w0 = {0, 0, 0, 0}, w1 = {0, 0, 0, 0};
                if (gj < N_NODES) {
                    w0 = X4[gj * 64 + kt * 8 + kg * 2];
                    w1 = X4[gj * 64 + kt * 8 + kg * 2 + 1];
                }
                *(float4*)&Bs[li * 36 + kg * 8]     = w0;
                *(float4*)&Bs[li * 36 + kg * 8 + 4] = w1;
            }
            __syncthreads();
#pragma unroll
            for (int k = 0; k < 32; k += 2) {
                float2 av[4], bv[4];
#pragma unroll
                for (int r = 0; r < 4; r++) {
                    av[r] = *(const float2*)&As[(ty * 4 + r) * 36 + k];
                    bv[r] = *(const float2*)&Bs[(tx * 4 + r) * 36 + k];
                }
#pragma unroll
                for (int r = 0; r < 4; r++)
#pragma unroll
                    for (int c = 0; c < 4; c++)
                        acc[r][c] += av[r].x * bv[c].x + av[r].y * bv[c].y;
            }
            __syncthreads();
        }
#pragma unroll
        for (int r = 0; r < 4; r++) {
            const int i = i0 + ty * 4 + r;
            if (i >= N_NODES) continue;
            const float rni = rn[i];
            const float nsi = neg_s[i];
#pragma unroll
            for (int c = 0; c < 4; c++) {
                const int j = j0 + tx * 4 + c;
                if (j < N_NODES && j > i) {
                    const float s = acc[r][c] * rni * rn[j];
                    if (s > 0.95f) {
                        const float d0 = (s - 0.1f) * (1.0f / 0.9f);
                        total += d0 * d0 * log1pf(expf(nsi - s));
                    }
                }
            }
        }
    }
    float red = wred64(total);
    if ((t & 63) == 0) wsum[t >> 6] = red;
    __syncthreads();
    if (t == 0) pexact[blockIdx.x] = wsum[0] + wsum[1] + wsum[2] + wsum[3];
}

// ------------- final reduction ----------------------------------------------
__global__ __launch_bounds__(256) void k_final(const float* __restrict__ preal,
                                               const float* __restrict__ pexact,
                                               const float* __restrict__ plc,
                                               float* __restrict__ out_loss) {
    __shared__ float wsum[4];
    const int t = threadIdx.x;
    float sr = 0.0f, sp = 0.0f, sl = 0.0f;
    for (int i = t; i < 25000; i += 256) sr += preal[i];
    if (t < EXACT_BLOCKS) sp = pexact[t];
    for (int i = t; i < 3750; i += 256) sl += plc[i];
    float contrib = sr + sp - sl * (1.0f / (float)P_PAIRS);
    contrib = wred64(contrib);
    if ((t & 63) == 0) wsum[t >> 6] = contrib;
    __syncthreads();
    if (t == 0) out_loss[0] = wsum[0] + wsum[1] + wsum[2] + wsum[3];
}

extern "C" void kernel_launch(void* const* d_in, const int* in_sizes, int n_in,
                              void* d_out, int out_size, void* d_ws, size_t ws_size,
                              hipStream_t stream) {
    const float* x0   = (const float*)d_in[0];
    const float* x1   = (const float*)d_in[1];
    const int*   a0s  = (const int*)d_in[2];
    const int*   a0d  = (const int*)d_in[3];
    const float* a0v  = (const float*)d_in[4];
    const int*   a1s  = (const int*)d_in[5];
    const int*   a1d  = (const int*)d_in[6];
    const float* a1v  = (const float*)d_in[7];
    const int*   trn  = (const int*)d_in[8];
    const int*   ngi  = (const int*)d_in[9];
    const int*   ngr  = (const int*)d_in[10];
    const int*   na   = (const int*)d_in[11];
    const int*   nb   = (const int*)d_in[12];
    const int*   nl   = (const int*)d_in[13];
    const float* W0   = (const float*)d_in[14];
    const float* b0   = (const float*)d_in[15];
    const float* W1   = (const float*)d_in[16];
    const float* b1   = (const float*)d_in[17];

    float* xall = (float*)d_out;                 // N x 256
    float* loss = xall + (size_t)N_NODES * 256;  // scalar

    float* ws = (float*)d_ws;
    size_t o = 0;
    float*          sup   = ws;                       // union with xbf
    unsigned short* xbf   = (unsigned short*)ws;      // NPAD x 256 bf16
    o += 1286144;                                     // max(1280000, 1286144)
    int*   src_s = (int*)(ws + o);   o += E_EDGES;
    float* val_s = ws + o;           o += E_EDGES;
    int*   hist  = (int*)(ws + o);   o += 10240;
    int*   off   = (int*)(ws + o);   o += 10240;
    int*   cur   = (int*)(ws + o);   o += 10240;
    float* rn    = ws + o;           o += 10000;
    float* negs  = ws + o;           o += 10000;
    float* preal = ws + o;           o += 25000;
    float* plc   = ws + o;           o += 3750;
    float* pexact= ws + o;           o += EXACT_BLOCKS;
    int*   count = (int*)(ws + o);   o += 16;
    int*   list  = (int*)(ws + o);   o += NTRI + 1;

    for (int c = 0; c < 2; c++) {
        const float* x  = c ? x1 : x0;
        const float* W  = c ? W1 : W0;
        const float* b  = c ? b1 : b0;
        const int*   es = c ? a1s : a0s;
        const int*   ed = c ? a1d : a0d;
        const float* ev = c ? a1v : a0v;
        k_gemm<<<625, 256, 0, stream>>>(x, W, b, sup);
        hipMemsetAsync(hist, 0, 10240 * sizeof(int), stream);
        k_hist<<<1250, 256, 0, stream>>>(ed, hist);
        k_scan<<<1, 256, 0, stream>>>(hist, off, cur);
        k_reorder<<<1250, 256, 0, stream>>>(es, ed, ev, cur, src_s, val_s);
        k_agg<<<2500, 256, 0, stream>>>(sup, off, hist, src_s, val_s, xall, c);
    }
    k_rownorm<<<2500, 256, 0, stream>>>(xall, rn);
    k_tobf<<<2512, 256, 0, stream>>>(xall, rn, xbf);     // overwrites sup region
    k_negs<<<2500, 256, 0, stream>>>(xall, rn, ngr, negs);
    k_lc<<<3750, 256, 0, stream>>>(xall, rn, na, nb, nl, plc);
    k_real<<<25000, 256, 0, stream>>>(xall, rn, trn, ngi, preal);
    hipMemsetAsync(count, 0, sizeof(int), stream);
    k_filter<<<NTRI, 256, 0, stream>>>(xbf, count, list);
    k_exact<<<EXACT_BLOCKS, 256, 0, stream>>>(xall, rn, negs, count, list, pexact);
    k_final<<<1, 256, 0, stream>>>(preal, pexact, plc, loss);
}

// Round 3
// 423.111 us; speedup vs baseline: 4.7046x; 1.3296x over previous
//
#include <hip/hip_runtime.h>
#include <math.h>

#define N_NODES 10000
#define E_EDGES 320000
#define M_TRAIN 100000
#define P_PAIRS 15000
#define TILES   157           // 64-tile count (k_exact coords)
#define TILES2  79            // 128-tile count: ceil(10000/128)
#define NTRI2   3160          // TILES2*(TILES2+1)/2
#define NPAD2   10112         // 79*128 padded rows for bf16 matrix
#define EXACT_BLOCKS 256

typedef __attribute__((ext_vector_type(8))) short short8;   // 8 bf16 (4 VGPRs)
typedef __attribute__((ext_vector_type(4))) float f32x4;

__device__ __forceinline__ float wred64(float v) {
#pragma unroll
    for (int o = 32; o > 0; o >>= 1) v += __shfl_xor(v, o, 64);
    return v;
}

__device__ __forceinline__ unsigned short f2bf(float f) {   // RNE float->bf16
    unsigned u = __float_as_uint(f);
    u += 0x7fffu + ((u >> 16) & 1u);
    return (unsigned short)(u >> 16);
}

// ---------------- GEMM: sup = x @ W + b  (N x 256) @ (256 x 128) ------------
__global__ __launch_bounds__(256) void k_gemm(const float* __restrict__ x,
                                              const float* __restrict__ W,
                                              const float* __restrict__ b,
                                              float* __restrict__ sup) {
    __shared__ float xs[16 * 256];
    const int t = threadIdx.x, blk = blockIdx.x;
    const float4* xg = (const float4*)(x + (size_t)blk * 16 * 256);
    float4* xs4 = (float4*)xs;
#pragma unroll
    for (int v = 0; v < 4; v++) xs4[v * 256 + t] = xg[v * 256 + t];
    __syncthreads();
    const int col = t & 127, rg = t >> 7;
    float acc[8];
    const float bb = b[col];
#pragma unroll
    for (int r = 0; r < 8; r++) acc[r] = bb;
    const float* xrow = xs + rg * 8 * 256;
    for (int k = 0; k < 256; k++) {
        const float w = W[k * 128 + col];
#pragma unroll
        for (int r = 0; r < 8; r++) acc[r] += xrow[r * 256 + k] * w;
    }
    float* outp = sup + ((size_t)blk * 16 + rg * 8) * 128 + col;
#pragma unroll
    for (int r = 0; r < 8; r++) outp[r * 128] = acc[r];
}

// ---------------- counting sort of edges by dst -----------------------------
__global__ __launch_bounds__(256) void k_hist(const int* __restrict__ dst,
                                              int* __restrict__ hist) {
    const int e = blockIdx.x * 256 + threadIdx.x;
    atomicAdd(&hist[dst[e]], 1);
}

__global__ __launch_bounds__(256) void k_scan(const int* __restrict__ hist,
                                              int* __restrict__ off,
                                              int* __restrict__ cur) {
    __shared__ int s[256];
    const int t = threadIdx.x;
    int loc[40];
    int sum = 0;
    const int base = t * 40;
#pragma unroll
    for (int i = 0; i < 40; i++) { loc[i] = hist[base + i]; sum += loc[i]; }
    s[t] = sum;
    __syncthreads();
    for (int o = 1; o < 256; o <<= 1) {
        int v = (t >= o) ? s[t - o] : 0;
        __syncthreads();
        s[t] += v;
        __syncthreads();
    }
    int run = s[t] - sum;   // exclusive prefix
#pragma unroll
    for (int i = 0; i < 40; i++) {
        off[base + i] = run;
        cur[base + i] = run;
        run += loc[i];
    }
}

__global__ __launch_bounds__(256) void k_reorder(const int* __restrict__ src,
                                                 const int* __restrict__ dst,
                                                 const float* __restrict__ val,
                                                 int* __restrict__ cur,
                                                 int* __restrict__ src_s,
                                                 float* __restrict__ val_s) {
    const int e = blockIdx.x * 256 + threadIdx.x;
    const int d = dst[e];
    const int p = atomicAdd(&cur[d], 1);
    src_s[p] = src[e];
    val_s[p] = val[e];
}

// ---- CSR aggregate + fused per-half L2 normalize: one wave per dst node ----
__global__ __launch_bounds__(256) void k_agg(const float* __restrict__ sup,
                                             const int* __restrict__ off,
                                             const int* __restrict__ hist,
                                             const int* __restrict__ src_s,
                                             const float* __restrict__ val_s,
                                             float* __restrict__ xall, int c) {
    const int t = threadIdx.x;
    const int node = blockIdx.x * 4 + (t >> 6), lane = t & 63;
    const int s0 = off[node], cnt = hist[node];
    const float2* S2 = (const float2*)sup;
    float2 a0 = {0.f, 0.f}, a1 = {0.f, 0.f}, a2 = {0.f, 0.f}, a3 = {0.f, 0.f};
    int e = s0;
    const int end = s0 + cnt;
    for (; e + 3 < end; e += 4) {
        const int sA = src_s[e],     sB = src_s[e + 1];
        const int sC = src_s[e + 2], sD = src_s[e + 3];
        const float vA = val_s[e],     vB = val_s[e + 1];
        const float vC = val_s[e + 2], vD = val_s[e + 3];
        const float2 mA = S2[(size_t)sA * 64 + lane];
        const float2 mB = S2[(size_t)sB * 64 + lane];
        const float2 mC = S2[(size_t)sC * 64 + lane];
        const float2 mD = S2[(size_t)sD * 64 + lane];
        a0.x += mA.x * vA; a0.y += mA.y * vA;
        a1.x += mB.x * vB; a1.y += mB.y * vB;
        a2.x += mC.x * vC; a2.y += mC.y * vC;
        a3.x += mD.x * vD; a3.y += mD.y * vD;
    }
    for (; e < end; e++) {
        const int sA = src_s[e];
        const float vA = val_s[e];
        const float2 mA = S2[(size_t)sA * 64 + lane];
        a0.x += mA.x * vA; a0.y += mA.y * vA;
    }
    a0.x += a1.x + a2.x + a3.x;
    a0.y += a1.y + a2.y + a3.y;
    const float s = wred64(a0.x * a0.x + a0.y * a0.y);
    const float inv = 1.0f / sqrtf(s);
    ((float2*)xall)[(size_t)node * 128 + c * 64 + lane] =
        make_float2(a0.x * inv, a0.y * inv);
}

// ------------- rn[i] = 1/||x_all[i]|| ---------------------------------------
__global__ __launch_bounds__(256) void k_rownorm(const float* __restrict__ xall,
                                                 float* __restrict__ rn) {
    const int t = threadIdx.x;
    const int node = blockIdx.x * 4 + (t >> 6), lane = t & 63;
    const float4 v = ((const float4*)xall)[node * 64 + lane];
    const float s = wred64(v.x * v.x + v.y * v.y + v.z * v.z + v.w * v.w);
    if (lane == 0) rn[node] = 1.0f / sqrtf(s);
}

// ------------- xbf[i][k] = bf16(xall[i][k] * rn[i]), zero-padded rows -------
__global__ __launch_bounds__(256) void k_tobf(const float* __restrict__ xall,
                                              const float* __restrict__ rn,
                                              unsigned short* __restrict__ xbf) {
    const int tid = blockIdx.x * 256 + threadIdx.x;  // 1 float4 per thread
    const int row = tid >> 6, cq = tid & 63;
    unsigned o0 = 0, o1 = 0;
    if (row < N_NODES) {
        float4 v = ((const float4*)xall)[(size_t)row * 64 + cq];
        const float r = rn[row];
        o0 = (unsigned)f2bf(v.x * r) | ((unsigned)f2bf(v.y * r) << 16);
        o1 = (unsigned)f2bf(v.z * r) | ((unsigned)f2bf(v.w * r) << 16);
    }
    ((uint2*)xbf)[tid] = make_uint2(o0, o1);
}

// ------------- neg_s[i] = cos(x_i, x_negrow[i]) -----------------------------
__global__ __launch_bounds__(256) void k_negs(const float* __restrict__ xall,
                                              const float* __restrict__ rn,
                                              const int* __restrict__ neg_row,
                                              float* __restrict__ neg_s) {
    const int t = threadIdx.x;
    const int node = blockIdx.x * 4 + (t >> 6), lane = t & 63;
    const int j = neg_row[node];
    const float4 a = ((const float4*)xall)[node * 64 + lane];
    const float4 b = ((const float4*)xall)[j * 64 + lane];
    const float d = wred64(a.x * b.x + a.y * b.y + a.z * b.z + a.w * b.w);
    if (lane == 0) neg_s[node] = d * rn[node] * rn[j];
}

// ------------- lc partials --------------------------------------------------
__global__ __launch_bounds__(256) void k_lc(const float* __restrict__ xall,
                                            const float* __restrict__ rn,
                                            const int* __restrict__ na,
                                            const int* __restrict__ nb,
                                            const int* __restrict__ nl,
                                            float* __restrict__ partial) {
    __shared__ float wsum[4];
    const int t = threadIdx.x, wid = t >> 6, lane = t & 63;
    const int p = blockIdx.x * 4 + wid;
    const int a = na[p], b = nb[p];
    const float4 av = ((const float4*)xall)[a * 64 + lane];
    const float4 bv = ((const float4*)xall)[b * 64 + lane];
    const float d = wred64(av.x * bv.x + av.y * bv.y + av.z * bv.z + av.w * bv.w);
    if (lane == 0) {
        const float sim = d * rn[a] * rn[b];
        const float z = sim / 0.5f;
        const float logsig = -log1pf(expf(-z));
        const float g = ldexpf(1.0f, -(nl[p] + 1));
        wsum[wid] = g * logsig;
    }
    __syncthreads();
    if (t == 0) partial[blockIdx.x] = wsum[0] + wsum[1] + wsum[2] + wsum[3];
}

// ------------- loss_real partials -------------------------------------------
__global__ __launch_bounds__(256) void k_real(const float* __restrict__ xall,
                                              const float* __restrict__ rn,
                                              const int* __restrict__ train,
                                              const int* __restrict__ negidx,
                                              float* __restrict__ partial) {
    __shared__ float wsum[4];
    const int t = threadIdx.x, wid = t >> 6, lane = t & 63;
    const int m = blockIdx.x * 4 + wid;
    const int s = train[2 * m], e = train[2 * m + 1], g = negidx[m];
    const float4* X4 = (const float4*)xall;
    const float4 a = X4[s * 64 + lane];
    const float4 b = X4[e * 64 + lane];
    const float4 c = X4[g * 64 + lane];
    float dp = a.x * b.x + a.y * b.y + a.z * b.z + a.w * b.w;
    float dn = a.x * c.x + a.y * c.y + a.z * c.z + a.w * c.w;
    dp = wred64(dp);
    dn = wred64(dn);
    if (lane == 0) {
        const float rs = rn[s];
        const float pos = dp * rs * rn[e];
        const float neg = dn * rs * rn[g];
        const float d0 = (pos - 0.1f) * (1.0f / 0.9f);
        wsum[wid] = d0 * d0 * log1pf(expf(neg - pos));
    }
    __syncthreads();
    if (t == 0) partial[blockIdx.x] = wsum[0] + wsum[1] + wsum[2] + wsum[3];
}

// ------------- phase A: bf16 MFMA filter, 128x128 tiles, LDS-staged ---------
// 4 waves/block; wave w=(wi,wj) owns the 64x64 quadrant (rows wi*64.., cols
// wj*64..) as a 4x4 grid of 16x16x32 MFMAs. K-loop BK=32, staged via
// global_load_lds width=16 (wave-uniform LDS base + lane*16 deposit).
// A-frag: lane reads A[m=lane&15][k=kq*8..+8]; C/D: col=lane&15, row=kq*4+reg.
__global__ __launch_bounds__(256) void k_filter(const unsigned short* __restrict__ xbf,
                                                int* __restrict__ count,
                                                int* __restrict__ list) {
    __shared__ unsigned short As[128 * 32];
    __shared__ unsigned short Bs[128 * 32];
    const int u = blockIdx.x;
    // decode upper-triangular (ti,tj) over TILES2, row-major, diagonal incl.
    int i = (int)((2.0 * TILES2 + 1.0 -
                   sqrt((2.0 * TILES2 + 1.0) * (2.0 * TILES2 + 1.0) - 8.0 * (double)u)) * 0.5);
    if (i < 0) i = 0;
    while ((i + 1) * TILES2 - ((i + 1) * i) / 2 <= u) i++;
    while (i * TILES2 - (i * (i - 1)) / 2 > u) i--;
    const int ti = i;
    const int tj = i + (u - (i * TILES2 - (i * (i - 1)) / 2));

    const int t = threadIdx.x, wave = t >> 6, lane = t & 63;
    const int wi = wave >> 1, wj = wave & 1;
    const int i0 = ti * 128, j0 = tj * 128;
    const int m = lane & 15, kq = lane >> 4;
    const int srow = lane >> 2, scol = lane & 3;   // staging: row-in-16, col-quad

    f32x4 acc[4][4];
#pragma unroll
    for (int r = 0; r < 4; r++)
#pragma unroll
        for (int c = 0; c < 4; c++) acc[r][c] = (f32x4){0.f, 0.f, 0.f, 0.f};

    for (int kt = 0; kt < 8; kt++) {
        const int k0 = kt * 32;
        // stage A (128x32) and B (128x32): 2 insts each per wave
#pragma unroll
        for (int p = 0; p < 2; p++) {
            const int grp = wave * 2 + p;             // 16-row group 0..7
            const size_t ga = (size_t)(i0 + grp * 16 + srow) * 256 + k0 + scol * 8;
            __builtin_amdgcn_global_load_lds(
                (const __attribute__((address_space(1))) void*)(xbf + ga),
                (__attribute__((address_space(3))) void*)(As + grp * 512), 16, 0, 0);
            const size_t gb = (size_t)(j0 + grp * 16 + srow) * 256 + k0 + scol * 8;
            __builtin_amdgcn_global_load_lds(
                (const __attribute__((address_space(1))) void*)(xbf + gb),
                (__attribute__((address_space(3))) void*)(Bs + grp * 512), 16, 0, 0);
        }
        __syncthreads();
        short8 af[4], bfr[4];
#pragma unroll
        for (int mt = 0; mt < 4; mt++)
            af[mt] = *(const short8*)&As[(wi * 64 + mt * 16 + m) * 32 + kq * 8];
#pragma unroll
        for (int nt = 0; nt < 4; nt++)
            bfr[nt] = *(const short8*)&Bs[(wj * 64 + nt * 16 + m) * 32 + kq * 8];
#pragma unroll
        for (int mt = 0; mt < 4; mt++)
#pragma unroll
            for (int nt = 0; nt < 4; nt++)
                acc[mt][nt] = __builtin_amdgcn_mfma_f32_16x16x32_bf16(
                    af[mt], bfr[nt], acc[mt][nt], 0, 0, 0);
        __syncthreads();
    }

    bool hit = false;
    const int rbase = i0 + wi * 64 + kq * 4;
    const int cbase = j0 + wj * 64 + m;
#pragma unroll
    for (int mt = 0; mt < 4; mt++)
#pragma unroll
        for (int nt = 0; nt < 4; nt++) {
            const f32x4 a = acc[mt][nt];
#pragma unroll
            for (int reg = 0; reg < 4; reg++) {
                if (a[reg] > 0.94f) {
                    const int ii = rbase + mt * 16 + reg;
                    const int jj = cbase + nt * 16;
                    if (jj > ii && ii < N_NODES && jj < N_NODES) hit = true;
                }
            }
        }
    if (__ballot(hit) != 0ull && lane == 0) {
        const int slot = atomicAdd(count, 1);
        list[slot] = ((ti * 2 + wi) << 16) | (tj * 2 + wj);   // 64-tile coords
    }
}

// ------------- phase B: exact fp32 recompute of flagged 64x64 tiles ---------
__global__ __launch_bounds__(256) void k_exact(const float* __restrict__ xall,
                                               const float* __restrict__ rn,
                                               const float* __restrict__ neg_s,
                                               const int* __restrict__ count,
                                               const int* __restrict__ list,
                                               float* __restrict__ pexact) {
    __shared__ float As[64 * 36];
    __shared__ float Bs[64 * 36];
    __shared__ float wsum[4];
    const int t = threadIdx.x;
    const int tx = t & 15, ty = t >> 4;
    const int li = t >> 2, kg = t & 3;
    const float4* X4 = (const float4*)xall;
    const int cnt = *count;
    float total = 0.0f;

    for (int idx = blockIdx.x; idx < cnt; idx += EXACT_BLOCKS) {
        const int pk = list[idx];
        const int ti = pk >> 16, tj = pk & 0xffff;
        const int i0 = ti * 64, j0 = tj * 64;
        float acc[4][4] = {};
        for (int kt = 0; kt < 8; kt++) {
            {
                const int gi = i0 + li;
                float4 v0 = {0, 0, 0, 0}, v1 = {0, 0, 0, 0};
                if (gi < N_NODES) {
                    v0 = X4[gi * 64 + kt * 8 + kg * 2];
                    v1 = X4[gi * 64 + kt * 8 + kg * 2 + 1];
                }
                *(float4*)&As[li * 36 + kg * 8]     = v0;
                *(float4*)&As[li * 36 + kg * 8 + 4] = v1;
                const int gj = j0 + li;
                float4 w0 = {0, 0, 0, 0}, w1 = {0, 0, 0, 0};
                if (gj < N_NODES) {
                    w0 = X4[gj * 64 + kt * 8 + kg * 2];
                    w1 = X4[gj * 64 + kt * 8 + kg * 2 + 1];
                }
                *(float4*)&Bs[li * 36 + kg * 8]     = w0;
                *(float4*)&Bs[li * 36 + kg * 8 + 4] = w1;
            }
            __syncthreads();
#pragma unroll
            for (int k = 0; k < 32; k += 2) {
                float2 av[4], bv[4];
#pragma unroll
                for (int r = 0; r < 4; r++) {
                    av[r] = *(const float2*)&As[(ty * 4 + r) * 36 + k];
                    bv[r] = *(const float2*)&Bs[(tx * 4 + r) * 36 + k];
                }
#pragma unroll
                for (int r = 0; r < 4; r++)
#pragma unroll
                    for (int c = 0; c < 4; c++)
                        acc[r][c] += av[r].x * bv[c].x + av[r].y * bv[c].y;
            }
            __syncthreads();
        }
#pragma unroll
        for (int r = 0; r < 4; r++) {
            const int i = i0 + ty * 4 + r;
            if (i >= N_NODES) continue;
            const float rni = rn[i];
            const float nsi = neg_s[i];
#pragma unroll
            for (int c = 0; c < 4; c++) {
                const int j = j0 + tx * 4 + c;
                if (j < N_NODES && j > i) {
                    const float s = acc[r][c] * rni * rn[j];
                    if (s > 0.95f) {
                        const float d0 = (s - 0.1f) * (1.0f / 0.9f);
                        total += d0 * d0 * log1pf(expf(nsi - s));
                    }
                }
            }
        }
    }
    float red = wred64(total);
    if ((t & 63) == 0) wsum[t >> 6] = red;
    __syncthreads();
    if (t == 0) pexact[blockIdx.x] = wsum[0] + wsum[1] + wsum[2] + wsum[3];
}

// ------------- final reduction ----------------------------------------------
__global__ __launch_bounds__(256) void k_final(const float* __restrict__ preal,
                                               const float* __restrict__ pexact,
                                               const float* __restrict__ plc,
                                               float* __restrict__ out_loss) {
    __shared__ float wsum[4];
    const int t = threadIdx.x;
    float sr = 0.0f, sp = 0.0f, sl = 0.0f;
    for (int i = t; i < 25000; i += 256) sr += preal[i];
    if (t < EXACT_BLOCKS) sp = pexact[t];
    for (int i = t; i < 3750; i += 256) sl += plc[i];
    float contrib = sr + sp - sl * (1.0f / (float)P_PAIRS);
    contrib = wred64(contrib);
    if ((t & 63) == 0) wsum[t >> 6] = contrib;
    __syncthreads();
    if (t == 0) out_loss[0] = wsum[0] + wsum[1] + wsum[2] + wsum[3];
}

extern "C" void kernel_launch(void* const* d_in, const int* in_sizes, int n_in,
                              void* d_out, int out_size, void* d_ws, size_t ws_size,
                              hipStream_t stream) {
    const float* x0   = (const float*)d_in[0];
    const float* x1   = (const float*)d_in[1];
    const int*   a0s  = (const int*)d_in[2];
    const int*   a0d  = (const int*)d_in[3];
    const float* a0v  = (const float*)d_in[4];
    const int*   a1s  = (const int*)d_in[5];
    const int*   a1d  = (const int*)d_in[6];
    const float* a1v  = (const float*)d_in[7];
    const int*   trn  = (const int*)d_in[8];
    const int*   ngi  = (const int*)d_in[9];
    const int*   ngr  = (const int*)d_in[10];
    const int*   na   = (const int*)d_in[11];
    const int*   nb   = (const int*)d_in[12];
    const int*   nl   = (const int*)d_in[13];
    const float* W0   = (const float*)d_in[14];
    const float* b0   = (const float*)d_in[15];
    const float* W1   = (const float*)d_in[16];
    const float* b1   = (const float*)d_in[17];

    float* xall = (float*)d_out;                 // N x 256
    float* loss = xall + (size_t)N_NODES * 256;  // scalar

    float* ws = (float*)d_ws;
    size_t o = 0;
    float*          sup   = ws;                       // union with xbf
    unsigned short* xbf   = (unsigned short*)ws;      // NPAD2 x 256 bf16
    o += 1294400;                                     // max(1280000, 1294336)
    int*   src_s = (int*)(ws + o);   o += E_EDGES;
    float* val_s = ws + o;           o += E_EDGES;
    int*   hist  = (int*)(ws + o);   o += 10240;
    int*   off   = (int*)(ws + o);   o += 10240;
    int*   cur   = (int*)(ws + o);   o += 10240;
    float* rn    = ws + o;           o += 10000;
    float* negs  = ws + o;           o += 10000;
    float* preal = ws + o;           o += 25000;
    float* plc   = ws + o;           o += 3750;
    float* pexact= ws + o;           o += EXACT_BLOCKS;
    int*   count = (int*)(ws + o);   o += 16;
    int*   list  = (int*)(ws + o);   o += NTRI2 * 4 + 16;

    for (int c = 0; c < 2; c++) {
        const float* x  = c ? x1 : x0;
        const float* W  = c ? W1 : W0;
        const float* b  = c ? b1 : b0;
        const int*   es = c ? a1s : a0s;
        const int*   ed = c ? a1d : a0d;
        const float* ev = c ? a1v : a0v;
        k_gemm<<<625, 256, 0, stream>>>(x, W, b, sup);
        hipMemsetAsync(hist, 0, 10240 * sizeof(int), stream);
        k_hist<<<1250, 256, 0, stream>>>(ed, hist);
        k_scan<<<1, 256, 0, stream>>>(hist, off, cur);
        k_reorder<<<1250, 256, 0, stream>>>(es, ed, ev, cur, src_s, val_s);
        k_agg<<<2500, 256, 0, stream>>>(sup, off, hist, src_s, val_s, xall, c);
    }
    k_rownorm<<<2500, 256, 0, stream>>>(xall, rn);
    k_tobf<<<2528, 256, 0, stream>>>(xall, rn, xbf);     // overwrites sup region
    k_negs<<<2500, 256, 0, stream>>>(xall, rn, ngr, negs);
    k_lc<<<3750, 256, 0, stream>>>(xall, rn, na, nb, nl, plc);
    k_real<<<25000, 256, 0, stream>>>(xall, rn, trn, ngi, preal);
    hipMemsetAsync(count, 0, sizeof(int), stream);
    k_filter<<<NTRI2, 256, 0, stream>>>(xbf, count, list);
    k_exact<<<EXACT_BLOCKS, 256, 0, stream>>>(xall, rn, negs, count, list, pexact);
    k_final<<<1, 256, 0, stream>>>(preal, pexact, plc, loss);
}

// Round 4
// 365.551 us; speedup vs baseline: 5.4454x; 1.1575x over previous
//
#include <hip/hip_runtime.h>
#include <math.h>

#define N_NODES 10000
#define E_EDGES 320000
#define M_TRAIN 100000
#define P_PAIRS 15000
#define TILES2  79            // 128-tile count: ceil(10000/128)
#define NTRI2   3160          // TILES2*(TILES2+1)/2
#define NPAD2   10112         // 79*128 padded rows for bf16 matrix
#define EXACT_BLOCKS 256

typedef __attribute__((ext_vector_type(8))) short short8;   // 8 bf16 (4 VGPRs)
typedef __attribute__((ext_vector_type(4))) float f32x4;

__device__ __forceinline__ float wred64(float v) {
#pragma unroll
    for (int o = 32; o > 0; o >>= 1) v += __shfl_xor(v, o, 64);
    return v;
}

__device__ __forceinline__ unsigned short f2bf(float f) {   // RNE float->bf16
    unsigned u = __float_as_uint(f);
    u += 0x7fffu + ((u >> 16) & 1u);
    return (unsigned short)(u >> 16);
}

// ------- GEMM both halves: sup_c = x_c @ W_c + b_c  (N x 256)@(256 x 128) ---
__global__ __launch_bounds__(256) void k_gemm2(const float* __restrict__ x0,
                                               const float* __restrict__ x1,
                                               const float* __restrict__ W0,
                                               const float* __restrict__ b0,
                                               const float* __restrict__ W1,
                                               const float* __restrict__ b1,
                                               float* __restrict__ sup0,
                                               float* __restrict__ sup1) {
    __shared__ float xs[16 * 256];
    int blk = blockIdx.x;
    const float *x, *W, *b;
    float* sup;
    if (blk < 625) { x = x0; W = W0; b = b0; sup = sup0; }
    else { blk -= 625; x = x1; W = W1; b = b1; sup = sup1; }
    const int t = threadIdx.x;
    const float4* xg = (const float4*)(x + (size_t)blk * 16 * 256);
    float4* xs4 = (float4*)xs;
#pragma unroll
    for (int v = 0; v < 4; v++) xs4[v * 256 + t] = xg[v * 256 + t];
    __syncthreads();
    const int col = t & 127, rg = t >> 7;
    float acc[8];
    const float bb = b[col];
#pragma unroll
    for (int r = 0; r < 8; r++) acc[r] = bb;
    const float* xrow = xs + rg * 8 * 256;
    for (int k = 0; k < 256; k++) {
        const float w = W[k * 128 + col];
#pragma unroll
        for (int r = 0; r < 8; r++) acc[r] += xrow[r * 256 + k] * w;
    }
    float* outp = sup + ((size_t)blk * 16 + rg * 8) * 128 + col;
#pragma unroll
    for (int r = 0; r < 8; r++) outp[r * 128] = acc[r];
}

// ------- histogram both halves ----------------------------------------------
__global__ __launch_bounds__(256) void k_hist2(const int* __restrict__ d0,
                                               const int* __restrict__ d1,
                                               int* __restrict__ hist) {
    int b = blockIdx.x;
    const int* dst;
    int* h;
    if (b < 1250) { dst = d0; h = hist; }
    else { b -= 1250; dst = d1; h = hist + 10240; }
    const int e = b * 256 + threadIdx.x;
    atomicAdd(&h[dst[e]], 1);
}

// ------- exclusive scan, one block per half ---------------------------------
__global__ __launch_bounds__(256) void k_scan2(const int* __restrict__ hist_,
                                               int* __restrict__ off_,
                                               int* __restrict__ cur_) {
    const int h = blockIdx.x;
    const int* hist = hist_ + h * 10240;
    int* off = off_ + h * 10240;
    int* cur = cur_ + h * 10240;
    __shared__ int s[256];
    const int t = threadIdx.x;
    int loc[40];
    int sum = 0;
    const int base = t * 40;
#pragma unroll
    for (int i = 0; i < 40; i++) { loc[i] = hist[base + i]; sum += loc[i]; }
    s[t] = sum;
    __syncthreads();
    for (int o = 1; o < 256; o <<= 1) {
        int v = (t >= o) ? s[t - o] : 0;
        __syncthreads();
        s[t] += v;
        __syncthreads();
    }
    int run = s[t] - sum;   // exclusive prefix
#pragma unroll
    for (int i = 0; i < 40; i++) {
        off[base + i] = run;
        cur[base + i] = run;
        run += loc[i];
    }
}

// ------- reorder both halves: packed (src, val) -----------------------------
__global__ __launch_bounds__(256) void k_reorder2(const int* __restrict__ s0,
                                                  const int* __restrict__ d0,
                                                  const float* __restrict__ v0,
                                                  const int* __restrict__ s1,
                                                  const int* __restrict__ d1,
                                                  const float* __restrict__ v1,
                                                  int* __restrict__ cur,
                                                  int2* __restrict__ packed) {
    int b = blockIdx.x;
    const int *src, *dst;
    const float* val;
    int* c;
    int2* pk;
    if (b < 1250) { src = s0; dst = d0; val = v0; c = cur; pk = packed; }
    else { b -= 1250; src = s1; dst = d1; val = v1; c = cur + 10240; pk = packed + E_EDGES; }
    const int e = b * 256 + threadIdx.x;
    const int d = dst[e];
    const int p = atomicAdd(&c[d], 1);
    pk[p] = make_int2(src[e], __float_as_int(val[e]));
}

// ------- CSR aggregate + fused per-half L2 normalize, both halves -----------
__global__ __launch_bounds__(256) void k_agg2(const float* __restrict__ sup0,
                                              const float* __restrict__ sup1,
                                              const int* __restrict__ off_,
                                              const int* __restrict__ hist_,
                                              const int2* __restrict__ packed_,
                                              float* __restrict__ xall) {
    int b = blockIdx.x;
    const float* sup;
    const int *off, *hist;
    const int2* pk;
    int c;
    if (b < 2500) { sup = sup0; off = off_; hist = hist_; pk = packed_; c = 0; }
    else { b -= 2500; sup = sup1; off = off_ + 10240; hist = hist_ + 10240;
           pk = packed_ + E_EDGES; c = 1; }
    const int t = threadIdx.x;
    const int node = b * 4 + (t >> 6), lane = t & 63;
    const int s0 = off[node], cnt = hist[node];
    const float2* S2 = (const float2*)sup;
    float2 a0 = {0.f, 0.f}, a1 = {0.f, 0.f}, a2 = {0.f, 0.f}, a3 = {0.f, 0.f};
    int e = s0;
    const int end = s0 + cnt;
    for (; e + 3 < end; e += 4) {
        const int2 pA = pk[e],     pB = pk[e + 1];
        const int2 pC = pk[e + 2], pD = pk[e + 3];
        const float vA = __int_as_float(pA.y), vB = __int_as_float(pB.y);
        const float vC = __int_as_float(pC.y), vD = __int_as_float(pD.y);
        const float2 mA = S2[(size_t)pA.x * 64 + lane];
        const float2 mB = S2[(size_t)pB.x * 64 + lane];
        const float2 mC = S2[(size_t)pC.x * 64 + lane];
        const float2 mD = S2[(size_t)pD.x * 64 + lane];
        a0.x += mA.x * vA; a0.y += mA.y * vA;
        a1.x += mB.x * vB; a1.y += mB.y * vB;
        a2.x += mC.x * vC; a2.y += mC.y * vC;
        a3.x += mD.x * vD; a3.y += mD.y * vD;
    }
    for (; e < end; e++) {
        const int2 pA = pk[e];
        const float vA = __int_as_float(pA.y);
        const float2 mA = S2[(size_t)pA.x * 64 + lane];
        a0.x += mA.x * vA; a0.y += mA.y * vA;
    }
    a0.x += a1.x + a2.x + a3.x;
    a0.y += a1.y + a2.y + a3.y;
    const float s = wred64(a0.x * a0.x + a0.y * a0.y);
    const float inv = 1.0f / sqrtf(s);
    ((float2*)xall)[(size_t)node * 128 + c * 64 + lane] =
        make_float2(a0.x * inv, a0.y * inv);
}

// ------- fused: rn[i] = 1/||x_all[i]||, xbf row = bf16(x_all[i]*rn[i]) ------
__global__ __launch_bounds__(256) void k_rowtobf(const float* __restrict__ xall,
                                                 float* __restrict__ rn,
                                                 unsigned short* __restrict__ xbf) {
    const int t = threadIdx.x;
    const int row = blockIdx.x * 4 + (t >> 6), lane = t & 63;
    unsigned o0 = 0, o1 = 0;
    if (row < N_NODES) {
        const float4 v = ((const float4*)xall)[(size_t)row * 64 + lane];
        const float s = wred64(v.x * v.x + v.y * v.y + v.z * v.z + v.w * v.w);
        const float inv = 1.0f / sqrtf(s);
        if (lane == 0) rn[row] = inv;
        o0 = (unsigned)f2bf(v.x * inv) | ((unsigned)f2bf(v.y * inv) << 16);
        o1 = (unsigned)f2bf(v.z * inv) | ((unsigned)f2bf(v.w * inv) << 16);
    }
    ((uint2*)xbf)[(size_t)row * 64 + lane] = make_uint2(o0, o1);
}

// ------- fused pair losses: negs / lc / real by block range -----------------
__global__ __launch_bounds__(256) void k_pairs(const float* __restrict__ xall,
                                               const float* __restrict__ rn,
                                               const int* __restrict__ neg_row,
                                               const int* __restrict__ na,
                                               const int* __restrict__ nb,
                                               const int* __restrict__ nl,
                                               const int* __restrict__ train,
                                               const int* __restrict__ negidx,
                                               float* __restrict__ neg_s,
                                               float* __restrict__ plc,
                                               float* __restrict__ preal) {
    __shared__ float wsum[4];
    const int t = threadIdx.x, wid = t >> 6, lane = t & 63;
    const int blk = blockIdx.x;
    const float4* X4 = (const float4*)xall;
    if (blk < 2500) {                       // ---- neg_s ----
        const int node = blk * 4 + wid;
        const int j = neg_row[node];
        const float4 a = X4[(size_t)node * 64 + lane];
        const float4 b = X4[(size_t)j * 64 + lane];
        const float d = wred64(a.x * b.x + a.y * b.y + a.z * b.z + a.w * b.w);
        if (lane == 0) neg_s[node] = d * rn[node] * rn[j];
    } else if (blk < 6250) {                // ---- lc partials ----
        const int p = (blk - 2500) * 4 + wid;
        const int a = na[p], b = nb[p];
        const float4 av = X4[(size_t)a * 64 + lane];
        const float4 bv = X4[(size_t)b * 64 + lane];
        const float d = wred64(av.x * bv.x + av.y * bv.y + av.z * bv.z + av.w * bv.w);
        if (lane == 0) {
            const float sim = d * rn[a] * rn[b];
            const float z = sim / 0.5f;                 // sim / TAU0
            const float logsig = -log1pf(expf(-z));     // log_sigmoid(z)
            const float g = ldexpf(1.0f, -(nl[p] + 1)); // 0.5^(L+1), exact
            wsum[wid] = g * logsig;
        }
        __syncthreads();
        if (t == 0) plc[blk - 2500] = wsum[0] + wsum[1] + wsum[2] + wsum[3];
    } else {                                // ---- loss_real partials ----
        const int m = (blk - 6250) * 4 + wid;
        const int s = train[2 * m], e = train[2 * m + 1], g = negidx[m];
        const float4 a = X4[(size_t)s * 64 + lane];
        const float4 b = X4[(size_t)e * 64 + lane];
        const float4 c = X4[(size_t)g * 64 + lane];
        float dp = a.x * b.x + a.y * b.y + a.z * b.z + a.w * b.w;
        float dn = a.x * c.x + a.y * c.y + a.z * c.z + a.w * c.w;
        dp = wred64(dp);
        dn = wred64(dn);
        if (lane == 0) {
            const float rs = rn[s];
            const float pos = dp * rs * rn[e];
            const float neg = dn * rs * rn[g];
            const float d0 = (pos - 0.1f) * (1.0f / 0.9f);
            wsum[wid] = d0 * d0 * log1pf(expf(neg - pos));
        }
        __syncthreads();
        if (t == 0) preal[blk - 6250] = wsum[0] + wsum[1] + wsum[2] + wsum[3];
    }
}

// ------------- phase A: bf16 MFMA filter, 128x128 tiles, LDS-staged ---------
__global__ __launch_bounds__(256) void k_filter(const unsigned short* __restrict__ xbf,
                                                int* __restrict__ count,
                                                int* __restrict__ list) {
    __shared__ unsigned short As[128 * 32];
    __shared__ unsigned short Bs[128 * 32];
    const int u = blockIdx.x;
    // decode upper-triangular (ti,tj) over TILES2, row-major, diagonal incl.
    int i = (int)((2.0 * TILES2 + 1.0 -
                   sqrt((2.0 * TILES2 + 1.0) * (2.0 * TILES2 + 1.0) - 8.0 * (double)u)) * 0.5);
    if (i < 0) i = 0;
    while ((i + 1) * TILES2 - ((i + 1) * i) / 2 <= u) i++;
    while (i * TILES2 - (i * (i - 1)) / 2 > u) i--;
    const int ti = i;
    const int tj = i + (u - (i * TILES2 - (i * (i - 1)) / 2));

    const int t = threadIdx.x, wave = t >> 6, lane = t & 63;
    const int wi = wave >> 1, wj = wave & 1;
    const int i0 = ti * 128, j0 = tj * 128;
    const int m = lane & 15, kq = lane >> 4;
    const int srow = lane >> 2, scol = lane & 3;   // staging: row-in-16, col-quad

    f32x4 acc[4][4];
#pragma unroll
    for (int r = 0; r < 4; r++)
#pragma unroll
        for (int c = 0; c < 4; c++) acc[r][c] = (f32x4){0.f, 0.f, 0.f, 0.f};

    for (int kt = 0; kt < 8; kt++) {
        const int k0 = kt * 32;
#pragma unroll
        for (int p = 0; p < 2; p++) {
            const int grp = wave * 2 + p;             // 16-row group 0..7
            const size_t ga = (size_t)(i0 + grp * 16 + srow) * 256 + k0 + scol * 8;
            __builtin_amdgcn_global_load_lds(
                (const __attribute__((address_space(1))) void*)(xbf + ga),
                (__attribute__((address_space(3))) void*)(As + grp * 512), 16, 0, 0);
            const size_t gb = (size_t)(j0 + grp * 16 + srow) * 256 + k0 + scol * 8;
            __builtin_amdgcn_global_load_lds(
                (const __attribute__((address_space(1))) void*)(xbf + gb),
                (__attribute__((address_space(3))) void*)(Bs + grp * 512), 16, 0, 0);
        }
        __syncthreads();
        short8 af[4], bfr[4];
#pragma unroll
        for (int mt = 0; mt < 4; mt++)
            af[mt] = *(const short8*)&As[(wi * 64 + mt * 16 + m) * 32 + kq * 8];
#pragma unroll
        for (int nt = 0; nt < 4; nt++)
            bfr[nt] = *(const short8*)&Bs[(wj * 64 + nt * 16 + m) * 32 + kq * 8];
#pragma unroll
        for (int mt = 0; mt < 4; mt++)
#pragma unroll
            for (int nt = 0; nt < 4; nt++)
                acc[mt][nt] = __builtin_amdgcn_mfma_f32_16x16x32_bf16(
                    af[mt], bfr[nt], acc[mt][nt], 0, 0, 0);
        __syncthreads();
    }

    bool hit = false;
    const int rbase = i0 + wi * 64 + kq * 4;
    const int cbase = j0 + wj * 64 + m;
#pragma unroll
    for (int mt = 0; mt < 4; mt++)
#pragma unroll
        for (int nt = 0; nt < 4; nt++) {
            const f32x4 a = acc[mt][nt];
#pragma unroll
            for (int reg = 0; reg < 4; reg++) {
                if (a[reg] > 0.94f) {
                    const int ii = rbase + mt * 16 + reg;
                    const int jj = cbase + nt * 16;
                    if (jj > ii && ii < N_NODES && jj < N_NODES) hit = true;
                }
            }
        }
    if (__ballot(hit) != 0ull && lane == 0) {
        const int slot = atomicAdd(count, 1);
        list[slot] = ((ti * 2 + wi) << 16) | (tj * 2 + wj);   // 64-tile coords
    }
}

// ------------- phase B: exact fp32 recompute of flagged 64x64 tiles ---------
__global__ __launch_bounds__(256) void k_exact(const float* __restrict__ xall,
                                               const float* __restrict__ rn,
                                               const float* __restrict__ neg_s,
                                               const int* __restrict__ count,
                                               const int* __restrict__ list,
                                               float* __restrict__ pexact) {
    __shared__ float As[64 * 36];
    __shared__ float Bs[64 * 36];
    __shared__ float wsum[4];
    const int t = threadIdx.x;
    const int tx = t & 15, ty = t >> 4;
    const int li = t >> 2, kg = t & 3;
    const float4* X4 = (const float4*)xall;
    const int cnt = *count;
    float total = 0.0f;

    for (int idx = blockIdx.x; idx < cnt; idx += EXACT_BLOCKS) {
        const int pk = list[idx];
        const int ti = pk >> 16, tj = pk & 0xffff;
        const int i0 = ti * 64, j0 = tj * 64;
        float acc[4][4] = {};
        for (int kt = 0; kt < 8; kt++) {
            {
                const int gi = i0 + li;
                float4 v0 = {0, 0, 0, 0}, v1 = {0, 0, 0, 0};
                if (gi < N_NODES) {
                    v0 = X4[gi * 64 + kt * 8 + kg * 2];
                    v1 = X4[gi * 64 + kt * 8 + kg * 2 + 1];
                }
                *(float4*)&As[li * 36 + kg * 8]     = v0;
                *(float4*)&As[li * 36 + kg * 8 + 4] = v1;
                const int gj = j0 + li;
                float4 w0 = {0, 0, 0, 0}, w1 = {0, 0, 0, 0};
                if (gj < N_NODES) {
                    w0 = X4[gj * 64 + kt * 8 + kg * 2];
                    w1 = X4[gj * 64 + kt * 8 + kg * 2 + 1];
                }
                *(float4*)&Bs[li * 36 + kg * 8]     = w0;
                *(float4*)&Bs[li * 36 + kg * 8 + 4] = w1;
            }
            __syncthreads();
#pragma unroll
            for (int k = 0; k < 32; k += 2) {
                float2 av[4], bv[4];
#pragma unroll
                for (int r = 0; r < 4; r++) {
                    av[r] = *(const float2*)&As[(ty * 4 + r) * 36 + k];
                    bv[r] = *(const float2*)&Bs[(tx * 4 + r) * 36 + k];
                }
#pragma unroll
                for (int r = 0; r < 4; r++)
#pragma unroll
                    for (int c = 0; c < 4; c++)
                        acc[r][c] += av[r].x * bv[c].x + av[r].y * bv[c].y;
            }
            __syncthreads();
        }
#pragma unroll
        for (int r = 0; r < 4; r++) {
            const int i = i0 + ty * 4 + r;
            if (i >= N_NODES) continue;
            const float rni = rn[i];
            const float nsi = neg_s[i];
#pragma unroll
            for (int c = 0; c < 4; c++) {
                const int j = j0 + tx * 4 + c;
                if (j < N_NODES && j > i) {
                    const float s = acc[r][c] * rni * rn[j];
                    if (s > 0.95f) {
                        const float d0 = (s - 0.1f) * (1.0f / 0.9f);
                        total += d0 * d0 * log1pf(expf(nsi - s));
                    }
                }
            }
        }
    }
    float red = wred64(total);
    if ((t & 63) == 0) wsum[t >> 6] = red;
    __syncthreads();
    if (t == 0) pexact[blockIdx.x] = wsum[0] + wsum[1] + wsum[2] + wsum[3];
}

// ------------- final reduction ----------------------------------------------
__global__ __launch_bounds__(256) void k_final(const float* __restrict__ preal,
                                               const float* __restrict__ pexact,
                                               const float* __restrict__ plc,
                                               float* __restrict__ out_loss) {
    __shared__ float wsum[4];
    const int t = threadIdx.x;
    float sr = 0.0f, sp = 0.0f, sl = 0.0f;
    for (int i = t; i < 25000; i += 256) sr += preal[i];
    if (t < EXACT_BLOCKS) sp = pexact[t];
    for (int i = t; i < 3750; i += 256) sl += plc[i];
    float contrib = sr + sp - sl * (1.0f / (float)P_PAIRS);
    contrib = wred64(contrib);
    if ((t & 63) == 0) wsum[t >> 6] = contrib;
    __syncthreads();
    if (t == 0) out_loss[0] = wsum[0] + wsum[1] + wsum[2] + wsum[3];
}

extern "C" void kernel_launch(void* const* d_in, const int* in_sizes, int n_in,
                              void* d_out, int out_size, void* d_ws, size_t ws_size,
                              hipStream_t stream) {
    const float* x0   = (const float*)d_in[0];
    const float* x1   = (const float*)d_in[1];
    const int*   a0s  = (const int*)d_in[2];
    const int*   a0d  = (const int*)d_in[3];
    const float* a0v  = (const float*)d_in[4];
    const int*   a1s  = (const int*)d_in[5];
    const int*   a1d  = (const int*)d_in[6];
    const float* a1v  = (const float*)d_in[7];
    const int*   trn  = (const int*)d_in[8];
    const int*   ngi  = (const int*)d_in[9];
    const int*   ngr  = (const int*)d_in[10];
    const int*   na   = (const int*)d_in[11];
    const int*   nb   = (const int*)d_in[12];
    const int*   nl   = (const int*)d_in[13];
    const float* W0   = (const float*)d_in[14];
    const float* b0   = (const float*)d_in[15];
    const float* W1   = (const float*)d_in[16];
    const float* b1   = (const float*)d_in[17];

    float* xall = (float*)d_out;                 // N x 256
    float* loss = xall + (size_t)N_NODES * 256;  // scalar

    float* ws = (float*)d_ws;
    size_t o = 0;
    float*          sup0  = ws;                       // union with xbf
    unsigned short* xbf   = (unsigned short*)ws;      // NPAD2 x 256 bf16
    o += 1294400;                                     // max(1280000, 1294336)
    float* sup1  = ws + o;           o += 1280000;
    int2*  packed= (int2*)(ws + o);  o += 1280000;    // 2 x E int2
    int*   hist  = (int*)(ws + o);   o += 20480;      // both halves
    int*   count = (int*)(ws + o);   o += 16;         // zeroed with hist
    int*   off   = (int*)(ws + o);   o += 20480;
    int*   cur   = (int*)(ws + o);   o += 20480;
    float* rn    = ws + o;           o += 10000;
    float* negs  = ws + o;           o += 10000;
    float* preal = ws + o;           o += 25000;
    float* plc   = ws + o;           o += 3750;
    float* pexact= ws + o;           o += EXACT_BLOCKS;
    int*   list  = (int*)(ws + o);   o += NTRI2 * 4 + 16;

    hipMemsetAsync(hist, 0, 20496 * sizeof(int), stream);   // hist both + count
    k_gemm2<<<1250, 256, 0, stream>>>(x0, x1, W0, b0, W1, b1, sup0, sup1);
    k_hist2<<<2500, 256, 0, stream>>>(a0d, a1d, hist);
    k_scan2<<<2, 256, 0, stream>>>(hist, off, cur);
    k_reorder2<<<2500, 256, 0, stream>>>(a0s, a0d, a0v, a1s, a1d, a1v, cur, packed);
    k_agg2<<<5000, 256, 0, stream>>>(sup0, sup1, off, hist, packed, xall);
    k_rowtobf<<<2528, 256, 0, stream>>>(xall, rn, xbf);   // overwrites sup0
    k_pairs<<<31250, 256, 0, stream>>>(xall, rn, ngr, na, nb, nl, trn, ngi,
                                       negs, plc, preal);
    k_filter<<<NTRI2, 256, 0, stream>>>(xbf, count, list);
    k_exact<<<EXACT_BLOCKS, 256, 0, stream>>>(xall, rn, negs, count, list, pexact);
    k_final<<<1, 256, 0, stream>>>(preal, pexact, plc, loss);
}

// Round 5
// 308.958 us; speedup vs baseline: 6.4429x; 1.1832x over previous
//
#include <hip/hip_runtime.h>
#include <math.h>

#define N_NODES 10000
#define E_EDGES 320000
#define M_TRAIN 100000
#define P_PAIRS 15000
#define TILES2  79            // 128-tile count: ceil(10000/128)
#define NTRI2   3160          // TILES2*(TILES2+1)/2
#define NPAD2   10112         // 79*128 padded rows for bf16 matrix
#define EXACT_BLOCKS 256
#define RB 1563               // real-loss blocks (6250 groups / 4 waves)
#define LB 235                // lc blocks (938 groups / 4 waves)
#define NB 157                // negs blocks (625 groups / 4 waves)

typedef __attribute__((ext_vector_type(8))) short short8;   // 8 bf16 (4 VGPRs)
typedef __attribute__((ext_vector_type(4))) float f32x4;

__device__ __forceinline__ float wred64(float v) {
#pragma unroll
    for (int o = 32; o > 0; o >>= 1) v += __shfl_xor(v, o, 64);
    return v;
}

__device__ __forceinline__ unsigned short f2bf(float f) {   // RNE float->bf16
    unsigned u = __float_as_uint(f);
    u += 0x7fffu + ((u >> 16) & 1u);
    return (unsigned short)(u >> 16);
}

// ------- fused: GEMM both halves (blocks 0..1249) + hist both (1250..3749) --
__global__ __launch_bounds__(256) void k_gemmhist(const float* __restrict__ x0,
                                                  const float* __restrict__ x1,
                                                  const float* __restrict__ W0,
                                                  const float* __restrict__ b0,
                                                  const float* __restrict__ W1,
                                                  const float* __restrict__ b1,
                                                  float* __restrict__ sup0,
                                                  float* __restrict__ sup1,
                                                  const int* __restrict__ d0,
                                                  const int* __restrict__ d1,
                                                  int* __restrict__ hist) {
    __shared__ float xs[16 * 256];
    int blk = blockIdx.x;
    const int t = threadIdx.x;
    if (blk >= 1250) {                      // ---- histogram ----
        blk -= 1250;
        const int* dst;
        int* h;
        if (blk < 1250) { dst = d0; h = hist; }
        else { blk -= 1250; dst = d1; h = hist + 10240; }
        const int e = blk * 256 + t;
        atomicAdd(&h[dst[e]], 1);
        return;
    }
    const float *x, *W, *b;
    float* sup;
    if (blk < 625) { x = x0; W = W0; b = b0; sup = sup0; }
    else { blk -= 625; x = x1; W = W1; b = b1; sup = sup1; }
    const float4* xg = (const float4*)(x + (size_t)blk * 16 * 256);
    float4* xs4 = (float4*)xs;
#pragma unroll
    for (int v = 0; v < 4; v++) xs4[v * 256 + t] = xg[v * 256 + t];
    __syncthreads();
    const int col = t & 127, rg = t >> 7;
    float acc[8];
    const float bb = b[col];
#pragma unroll
    for (int r = 0; r < 8; r++) acc[r] = bb;
    const float* xrow = xs + rg * 8 * 256;
    for (int k = 0; k < 256; k++) {
        const float w = W[k * 128 + col];
#pragma unroll
        for (int r = 0; r < 8; r++) acc[r] += xrow[r * 256 + k] * w;
    }
    float* outp = sup + ((size_t)blk * 16 + rg * 8) * 128 + col;
#pragma unroll
    for (int r = 0; r < 8; r++) outp[r * 128] = acc[r];
}

// ------- exclusive scan, one block per half ---------------------------------
__global__ __launch_bounds__(256) void k_scan2(const int* __restrict__ hist_,
                                               int* __restrict__ off_,
                                               int* __restrict__ cur_) {
    const int h = blockIdx.x;
    const int* hist = hist_ + h * 10240;
    int* off = off_ + h * 10240;
    int* cur = cur_ + h * 10240;
    __shared__ int s[256];
    const int t = threadIdx.x;
    int loc[40];
    int sum = 0;
    const int base = t * 40;
#pragma unroll
    for (int i = 0; i < 40; i++) { loc[i] = hist[base + i]; sum += loc[i]; }
    s[t] = sum;
    __syncthreads();
    for (int o = 1; o < 256; o <<= 1) {
        int v = (t >= o) ? s[t - o] : 0;
        __syncthreads();
        s[t] += v;
        __syncthreads();
    }
    int run = s[t] - sum;   // exclusive prefix
#pragma unroll
    for (int i = 0; i < 40; i++) {
        off[base + i] = run;
        cur[base + i] = run;
        run += loc[i];
    }
}

// ------- reorder both halves: packed (src, val) -----------------------------
__global__ __launch_bounds__(256) void k_reorder2(const int* __restrict__ s0,
                                                  const int* __restrict__ d0,
                                                  const float* __restrict__ v0,
                                                  const int* __restrict__ s1,
                                                  const int* __restrict__ d1,
                                                  const float* __restrict__ v1,
                                                  int* __restrict__ cur,
                                                  int2* __restrict__ packed) {
    int b = blockIdx.x;
    const int *src, *dst;
    const float* val;
    int* c;
    int2* pk;
    if (b < 1250) { src = s0; dst = d0; val = v0; c = cur; pk = packed; }
    else { b -= 1250; src = s1; dst = d1; val = v1; c = cur + 10240; pk = packed + E_EDGES; }
    const int e = b * 256 + threadIdx.x;
    const int d = dst[e];
    const int p = atomicAdd(&c[d], 1);
    pk[p] = make_int2(src[e], __float_as_int(val[e]));
}

// ------- CSR aggregate + fused per-half L2 normalize, both halves -----------
__global__ __launch_bounds__(256) void k_agg2(const float* __restrict__ sup0,
                                              const float* __restrict__ sup1,
                                              const int* __restrict__ off_,
                                              const int* __restrict__ hist_,
                                              const int2* __restrict__ packed_,
                                              float* __restrict__ xall) {
    int b = blockIdx.x;
    const float* sup;
    const int *off, *hist;
    const int2* pk;
    int c;
    if (b < 2500) { sup = sup0; off = off_; hist = hist_; pk = packed_; c = 0; }
    else { b -= 2500; sup = sup1; off = off_ + 10240; hist = hist_ + 10240;
           pk = packed_ + E_EDGES; c = 1; }
    const int t = threadIdx.x;
    const int node = b * 4 + (t >> 6), lane = t & 63;
    const int s0 = off[node], cnt = hist[node];
    const float2* S2 = (const float2*)sup;
    float2 a0 = {0.f, 0.f}, a1 = {0.f, 0.f}, a2 = {0.f, 0.f}, a3 = {0.f, 0.f};
    int e = s0;
    const int end = s0 + cnt;
    for (; e + 3 < end; e += 4) {
        const int2 pA = pk[e],     pB = pk[e + 1];
        const int2 pC = pk[e + 2], pD = pk[e + 3];
        const float vA = __int_as_float(pA.y), vB = __int_as_float(pB.y);
        const float vC = __int_as_float(pC.y), vD = __int_as_float(pD.y);
        const float2 mA = S2[(size_t)pA.x * 64 + lane];
        const float2 mB = S2[(size_t)pB.x * 64 + lane];
        const float2 mC = S2[(size_t)pC.x * 64 + lane];
        const float2 mD = S2[(size_t)pD.x * 64 + lane];
        a0.x += mA.x * vA; a0.y += mA.y * vA;
        a1.x += mB.x * vB; a1.y += mB.y * vB;
        a2.x += mC.x * vC; a2.y += mC.y * vC;
        a3.x += mD.x * vD; a3.y += mD.y * vD;
    }
    for (; e < end; e++) {
        const int2 pA = pk[e];
        const float vA = __int_as_float(pA.y);
        const float2 mA = S2[(size_t)pA.x * 64 + lane];
        a0.x += mA.x * vA; a0.y += mA.y * vA;
    }
    a0.x += a1.x + a2.x + a3.x;
    a0.y += a1.y + a2.y + a3.y;
    const float s = wred64(a0.x * a0.x + a0.y * a0.y);
    const float inv = 1.0f / sqrtf(s);
    ((float2*)xall)[(size_t)node * 128 + c * 64 + lane] =
        make_float2(a0.x * inv, a0.y * inv);
}

// ------- fused: rn[i] = 1/||x_all[i]||, xbf row = bf16(x_all[i]*rn[i]) ------
__global__ __launch_bounds__(256) void k_rowtobf(const float* __restrict__ xall,
                                                 float* __restrict__ rn,
                                                 unsigned short* __restrict__ xbf) {
    const int t = threadIdx.x;
    const int row = blockIdx.x * 4 + (t >> 6), lane = t & 63;
    unsigned o0 = 0, o1 = 0;
    if (row < N_NODES) {
        const float4 v = ((const float4*)xall)[(size_t)row * 64 + lane];
        const float s = wred64(v.x * v.x + v.y * v.y + v.z * v.z + v.w * v.w);
        const float inv = 1.0f / sqrtf(s);
        if (lane == 0) rn[row] = inv;
        o0 = (unsigned)f2bf(v.x * inv) | ((unsigned)f2bf(v.y * inv) << 16);
        o1 = (unsigned)f2bf(v.z * inv) | ((unsigned)f2bf(v.w * inv) << 16);
    }
    ((uint2*)xbf)[(size_t)row * 64 + lane] = make_uint2(o0, o1);
}

// ======= mega-kernel: MFMA filter (blocks 0..3159) + MFMA pair losses =======
// Pair segments process 16 pairs/wave: A,B = bf16 rows, P = A·B^T via
// 16x16x32 MFMA; diag P[m][m] lives on lane (m&15)+16*(m>>2), reg m&3.
__global__ __launch_bounds__(256) void k_fp(const unsigned short* __restrict__ xbf,
                                            int* __restrict__ count,
                                            int* __restrict__ list,
                                            const int* __restrict__ train,
                                            const int* __restrict__ negidx,
                                            const int* __restrict__ na,
                                            const int* __restrict__ nb,
                                            const int* __restrict__ nl,
                                            const int* __restrict__ neg_row,
                                            float* __restrict__ neg_s,
                                            float* __restrict__ preal,
                                            float* __restrict__ plc) {
    __shared__ unsigned short As[128 * 32];
    __shared__ unsigned short Bs[128 * 32];
    __shared__ float wsum[4];
    const int b = blockIdx.x;
    const int t = threadIdx.x, wave = t >> 6, lane = t & 63;
    const int m = lane & 15, kq = lane >> 4;
    const int dreg = ((m >> 2) == kq) ? (m & 3) : -1;   // diag ownership

    if (b < NTRI2) {   // ================= filter =================
        const int u = b;
        int i = (int)((2.0 * TILES2 + 1.0 -
                       sqrt((2.0 * TILES2 + 1.0) * (2.0 * TILES2 + 1.0) - 8.0 * (double)u)) * 0.5);
        if (i < 0) i = 0;
        while ((i + 1) * TILES2 - ((i + 1) * i) / 2 <= u) i++;
        while (i * TILES2 - (i * (i - 1)) / 2 > u) i--;
        const int ti = i;
        const int tj = i + (u - (i * TILES2 - (i * (i - 1)) / 2));

        const int wi = wave >> 1, wj = wave & 1;
        const int i0 = ti * 128, j0 = tj * 128;
        const int srow = lane >> 2, scol = lane & 3;

        f32x4 acc[4][4];
#pragma unroll
        for (int r = 0; r < 4; r++)
#pragma unroll
            for (int c = 0; c < 4; c++) acc[r][c] = (f32x4){0.f, 0.f, 0.f, 0.f};

        for (int kt = 0; kt < 8; kt++) {
            const int k0 = kt * 32;
#pragma unroll
            for (int p = 0; p < 2; p++) {
                const int grp = wave * 2 + p;
                const size_t ga = (size_t)(i0 + grp * 16 + srow) * 256 + k0 + scol * 8;
                __builtin_amdgcn_global_load_lds(
                    (const __attribute__((address_space(1))) void*)(xbf + ga),
                    (__attribute__((address_space(3))) void*)(As + grp * 512), 16, 0, 0);
                const size_t gb = (size_t)(j0 + grp * 16 + srow) * 256 + k0 + scol * 8;
                __builtin_amdgcn_global_load_lds(
                    (const __attribute__((address_space(1))) void*)(xbf + gb),
                    (__attribute__((address_space(3))) void*)(Bs + grp * 512), 16, 0, 0);
            }
            __syncthreads();
            short8 af[4], bfr[4];
#pragma unroll
            for (int mt = 0; mt < 4; mt++)
                af[mt] = *(const short8*)&As[(wi * 64 + mt * 16 + m) * 32 + kq * 8];
#pragma unroll
            for (int nt = 0; nt < 4; nt++)
                bfr[nt] = *(const short8*)&Bs[(wj * 64 + nt * 16 + m) * 32 + kq * 8];
#pragma unroll
            for (int mt = 0; mt < 4; mt++)
#pragma unroll
                for (int nt = 0; nt < 4; nt++)
                    acc[mt][nt] = __builtin_amdgcn_mfma_f32_16x16x32_bf16(
                        af[mt], bfr[nt], acc[mt][nt], 0, 0, 0);
            __syncthreads();
        }

        bool hit = false;
        const int rbase = i0 + wi * 64 + kq * 4;
        const int cbase = j0 + wj * 64 + m;
#pragma unroll
        for (int mt = 0; mt < 4; mt++)
#pragma unroll
            for (int nt = 0; nt < 4; nt++) {
                const f32x4 a = acc[mt][nt];
#pragma unroll
                for (int reg = 0; reg < 4; reg++) {
                    if (a[reg] > 0.94f) {
                        const int ii = rbase + mt * 16 + reg;
                        const int jj = cbase + nt * 16;
                        if (jj > ii && ii < N_NODES && jj < N_NODES) hit = true;
                    }
                }
            }
        if (__ballot(hit) != 0ull && lane == 0) {
            const int slot = atomicAdd(count, 1);
            list[slot] = ((ti * 2 + wi) << 16) | (tj * 2 + wj);   // 64-tile coords
        }
        return;
    }

    const int ridx = b - NTRI2;
    if (ridx < RB) {   // ================= loss_real =================
        const int g = ridx * 4 + wave;
        float sum = 0.f;
        if (g < 6250) {
            const int p = g * 16 + m;
            const int2 se = ((const int2*)train)[p];
            const int ng = negidx[p];
            const unsigned short* pa = xbf + (size_t)se.x * 256 + kq * 8;
            const unsigned short* pb = xbf + (size_t)se.y * 256 + kq * 8;
            const unsigned short* pc = xbf + (size_t)ng * 256 + kq * 8;
            f32x4 P = {0.f, 0.f, 0.f, 0.f}, Q = P;
#pragma unroll
            for (int kt = 0; kt < 8; kt++) {
                const short8 a  = *(const short8*)(pa + kt * 32);
                const short8 bb = *(const short8*)(pb + kt * 32);
                const short8 cc = *(const short8*)(pc + kt * 32);
                P = __builtin_amdgcn_mfma_f32_16x16x32_bf16(a, bb, P, 0, 0, 0);
                Q = __builtin_amdgcn_mfma_f32_16x16x32_bf16(a, cc, Q, 0, 0, 0);
            }
            if (dreg >= 0) {
                const float pos = P[dreg], neg = Q[dreg];
                const float d0 = (pos - 0.1f) * (1.0f / 0.9f);
                sum = d0 * d0 * log1pf(expf(neg - pos));
            }
        }
        sum = wred64(sum);
        if (lane == 0) wsum[wave] = sum;
        __syncthreads();
        if (t == 0) preal[ridx] = wsum[0] + wsum[1] + wsum[2] + wsum[3];
    } else if (ridx < RB + LB) {   // ================= lc =================
        const int bi = ridx - RB;
        const int g = bi * 4 + wave;
        float sum = 0.f;
        if (g < 938) {
            const int p = g * 16 + m;
            const bool valid = p < P_PAIRS;
            const int pc_ = valid ? p : (P_PAIRS - 1);
            const int a_ = na[pc_], b_ = nb[pc_];
            const unsigned short* pa = xbf + (size_t)a_ * 256 + kq * 8;
            const unsigned short* pb = xbf + (size_t)b_ * 256 + kq * 8;
            f32x4 P = {0.f, 0.f, 0.f, 0.f};
#pragma unroll
            for (int kt = 0; kt < 8; kt++) {
                const short8 a  = *(const short8*)(pa + kt * 32);
                const short8 bb = *(const short8*)(pb + kt * 32);
                P = __builtin_amdgcn_mfma_f32_16x16x32_bf16(a, bb, P, 0, 0, 0);
            }
            if (dreg >= 0 && valid) {
                const float sim = P[dreg];
                const float z = sim * 2.0f;                 // sim / TAU0
                const float logsig = -log1pf(expf(-z));
                const float gw = ldexpf(1.0f, -(nl[pc_] + 1));
                sum = gw * logsig;
            }
        }
        sum = wred64(sum);
        if (lane == 0) wsum[wave] = sum;
        __syncthreads();
        if (t == 0) plc[bi] = wsum[0] + wsum[1] + wsum[2] + wsum[3];
    } else {   // ================= neg_s =================
        const int bi = ridx - RB - LB;
        const int g = bi * 4 + wave;
        if (g < 625) {
            const int node = g * 16 + m;
            const int j = neg_row[node];
            const unsigned short* pa = xbf + (size_t)node * 256 + kq * 8;
            const unsigned short* pb = xbf + (size_t)j * 256 + kq * 8;
            f32x4 P = {0.f, 0.f, 0.f, 0.f};
#pragma unroll
            for (int kt = 0; kt < 8; kt++) {
                const short8 a  = *(const short8*)(pa + kt * 32);
                const short8 bb = *(const short8*)(pb + kt * 32);
                P = __builtin_amdgcn_mfma_f32_16x16x32_bf16(a, bb, P, 0, 0, 0);
            }
            if (dreg >= 0) neg_s[node] = P[dreg];
        }
    }
}

// ------------- phase B: exact fp32 recompute of flagged 64x64 tiles ---------
__global__ __launch_bounds__(256) void k_exact(const float* __restrict__ xall,
                                               const float* __restrict__ rn,
                                               const float* __restrict__ neg_s,
                                               const int* __restrict__ count,
                                               const int* __restrict__ list,
                                               float* __restrict__ pexact) {
    __shared__ float As[64 * 36];
    __shared__ float Bs[64 * 36];
    __shared__ float wsum[4];
    const int t = threadIdx.x;
    const int tx = t & 15, ty = t >> 4;
    const int li = t >> 2, kg = t & 3;
    const float4* X4 = (const float4*)xall;
    const int cnt = *count;
    float total = 0.0f;

    for (int idx = blockIdx.x; idx < cnt; idx += EXACT_BLOCKS) {
        const int pk = list[idx];
        const int ti = pk >> 16, tj = pk & 0xffff;
        const int i0 = ti * 64, j0 = tj * 64;
        float acc[4][4] = {};
        for (int kt = 0; kt < 8; kt++) {
            {
                const int gi = i0 + li;
                float4 v0 = {0, 0, 0, 0}, v1 = {0, 0, 0, 0};
                if (gi < N_NODES) {
                    v0 = X4[gi * 64 + kt * 8 + kg * 2];
                    v1 = X4[gi * 64 + kt * 8 + kg * 2 + 1];
                }
                *(float4*)&As[li * 36 + kg * 8]     = v0;
                *(float4*)&As[li * 36 + kg * 8 + 4] = v1;
                const int gj = j0 + li;
                float4 w0 = {0, 0, 0, 0}, w1 = {0, 0, 0, 0};
                if (gj < N_NODES) {
                    w0 = X4[gj * 64 + kt * 8 + kg * 2];
                    w1 = X4[gj * 64 + kt * 8 + kg * 2 + 1];
                }
                *(float4*)&Bs[li * 36 + kg * 8]     = w0;
                *(float4*)&Bs[li * 36 + kg * 8 + 4] = w1;
            }
            __syncthreads();
#pragma unroll
            for (int k = 0; k < 32; k += 2) {
                float2 av[4], bv[4];
#pragma unroll
                for (int r = 0; r < 4; r++) {
                    av[r] = *(const float2*)&As[(ty * 4 + r) * 36 + k];
                    bv[r] = *(const float2*)&Bs[(tx * 4 + r) * 36 + k];
                }
#pragma unroll
                for (int r = 0; r < 4; r++)
#pragma unroll
                    for (int c = 0; c < 4; c++)
                        acc[r][c] += av[r].x * bv[c].x + av[r].y * bv[c].y;
            }
            __syncthreads();
        }
#pragma unroll
        for (int r = 0; r < 4; r++) {
            const int i = i0 + ty * 4 + r;
            if (i >= N_NODES) continue;
            const float rni = rn[i];
            const float nsi = neg_s[i];
#pragma unroll
            for (int c = 0; c < 4; c++) {
                const int j = j0 + tx * 4 + c;
                if (j < N_NODES && j > i) {
                    const float s = acc[r][c] * rni * rn[j];
                    if (s > 0.95f) {
                        const float d0 = (s - 0.1f) * (1.0f / 0.9f);
                        total += d0 * d0 * log1pf(expf(nsi - s));
                    }
                }
            }
        }
    }
    float red = wred64(total);
    if ((t & 63) == 0) wsum[t >> 6] = red;
    __syncthreads();
    if (t == 0) pexact[blockIdx.x] = wsum[0] + wsum[1] + wsum[2] + wsum[3];
}

// ------------- final reduction ----------------------------------------------
__global__ __launch_bounds__(256) void k_final(const float* __restrict__ preal,
                                               const float* __restrict__ pexact,
                                               const float* __restrict__ plc,
                                               float* __restrict__ out_loss) {
    __shared__ float wsum[4];
    const int t = threadIdx.x;
    float sr = 0.0f, sp = 0.0f, sl = 0.0f;
    for (int i = t; i < RB; i += 256) sr += preal[i];
    if (t < EXACT_BLOCKS) sp = pexact[t];
    if (t < LB) sl = plc[t];
    float contrib = sr + sp - sl * (1.0f / (float)P_PAIRS);
    contrib = wred64(contrib);
    if ((t & 63) == 0) wsum[t >> 6] = contrib;
    __syncthreads();
    if (t == 0) out_loss[0] = wsum[0] + wsum[1] + wsum[2] + wsum[3];
}

extern "C" void kernel_launch(void* const* d_in, const int* in_sizes, int n_in,
                              void* d_out, int out_size, void* d_ws, size_t ws_size,
                              hipStream_t stream) {
    const float* x0   = (const float*)d_in[0];
    const float* x1   = (const float*)d_in[1];
    const int*   a0s  = (const int*)d_in[2];
    const int*   a0d  = (const int*)d_in[3];
    const float* a0v  = (const float*)d_in[4];
    const int*   a1s  = (const int*)d_in[5];
    const int*   a1d  = (const int*)d_in[6];
    const float* a1v  = (const float*)d_in[7];
    const int*   trn  = (const int*)d_in[8];
    const int*   ngi  = (const int*)d_in[9];
    const int*   ngr  = (const int*)d_in[10];
    const int*   na   = (const int*)d_in[11];
    const int*   nb   = (const int*)d_in[12];
    const int*   nl   = (const int*)d_in[13];
    const float* W0   = (const float*)d_in[14];
    const float* b0   = (const float*)d_in[15];
    const float* W1   = (const float*)d_in[16];
    const float* b1   = (const float*)d_in[17];

    float* xall = (float*)d_out;                 // N x 256
    float* loss = xall + (size_t)N_NODES * 256;  // scalar

    float* ws = (float*)d_ws;
    size_t o = 0;
    float*          sup0  = ws;                       // union with xbf
    unsigned short* xbf   = (unsigned short*)ws;      // NPAD2 x 256 bf16
    o += 1294400;                                     // max(1280000, 1294336)
    float* sup1  = ws + o;           o += 1280000;
    int2*  packed= (int2*)(ws + o);  o += 1280000;    // 2 x E int2
    int*   hist  = (int*)(ws + o);   o += 20480;      // both halves
    int*   count = (int*)(ws + o);   o += 16;         // zeroed with hist
    int*   off   = (int*)(ws + o);   o += 20480;
    int*   cur   = (int*)(ws + o);   o += 20480;
    float* rn    = ws + o;           o += 10000;
    float* negs  = ws + o;           o += 10000;
    float* preal = ws + o;           o += RB;
    float* plc   = ws + o;           o += LB;
    float* pexact= ws + o;           o += EXACT_BLOCKS;
    int*   list  = (int*)(ws + o);   o += NTRI2 * 4 + 16;

    hipMemsetAsync(hist, 0, 20496 * sizeof(int), stream);   // hist both + count
    k_gemmhist<<<3750, 256, 0, stream>>>(x0, x1, W0, b0, W1, b1, sup0, sup1,
                                         a0d, a1d, hist);
    k_scan2<<<2, 256, 0, stream>>>(hist, off, cur);
    k_reorder2<<<2500, 256, 0, stream>>>(a0s, a0d, a0v, a1s, a1d, a1v, cur, packed);
    k_agg2<<<5000, 256, 0, stream>>>(sup0, sup1, off, hist, packed, xall);
    k_rowtobf<<<2528, 256, 0, stream>>>(xall, rn, xbf);   // overwrites sup0
    k_fp<<<NTRI2 + RB + LB + NB, 256, 0, stream>>>(xbf, count, list, trn, ngi,
                                                   na, nb, nl, ngr,
                                                   negs, preal, plc);
    k_exact<<<EXACT_BLOCKS, 256, 0, stream>>>(xall, rn, negs, count, list, pexact);
    k_final<<<1, 256, 0, stream>>>(preal, pexact, plc, loss);
}

// Round 6
// 300.699 us; speedup vs baseline: 6.6199x; 1.0275x over previous
//
#include <hip/hip_runtime.h>
#include <math.h>

#define N_NODES 10000
#define E_EDGES 320000
#define M_TRAIN 100000
#define P_PAIRS 15000
#define TILES2  79            // 128-tile count: ceil(10000/128)
#define NTRI2   3160          // TILES2*(TILES2+1)/2
#define NPAD2   10112         // 79*128 padded rows
#define EXACT_BLOCKS 256
#define RB 1563               // real-loss blocks (6250 groups / 4 waves)
#define LB 235                // lc blocks (938 groups / 4 waves)
#define NB 157                // negs blocks (625 groups / 4 waves)

typedef __attribute__((ext_vector_type(8))) short short8;   // 8 bf16 (4 VGPRs)
typedef __attribute__((ext_vector_type(4))) float f32x4;

__device__ __forceinline__ float wred64(float v) {
#pragma unroll
    for (int o = 32; o > 0; o >>= 1) v += __shfl_xor(v, o, 64);
    return v;
}

__device__ __forceinline__ unsigned short f2bf(float f) {   // RNE float->bf16
    unsigned u = __float_as_uint(f);
    u += 0x7fffu + ((u >> 16) & 1u);
    return (unsigned short)(u >> 16);
}
__device__ __forceinline__ float bf2f(unsigned short h) {
    return __uint_as_float((unsigned)h << 16);
}

// ======= prep: x hi/lo bf16 split + W^T hi/lo + edge histograms =============
// blocks [0,5056): x-split (2528/half); [5056,5312): W^T (128/half);
// [5312,7812): hist (1250/half)
__global__ __launch_bounds__(256) void k_prep(const float* __restrict__ x0,
                                              const float* __restrict__ x1,
                                              const float* __restrict__ W0,
                                              const float* __restrict__ W1,
                                              const int* __restrict__ d0,
                                              const int* __restrict__ d1,
                                              unsigned short* __restrict__ xh,
                                              unsigned short* __restrict__ xl,
                                              unsigned short* __restrict__ wth,
                                              unsigned short* __restrict__ wtl,
                                              int* __restrict__ hist) {
    int b = blockIdx.x;
    const int t = threadIdx.x;
    if (b < 5056) {                         // ---- x hi/lo split ----
        const int half = b >= 2528;
        if (half) b -= 2528;
        const float* x = half ? x1 : x0;
        unsigned short* ph = xh + (size_t)half * NPAD2 * 256;
        unsigned short* pl = xl + (size_t)half * NPAD2 * 256;
        const int tid = b * 256 + t;        // one float4 per thread
        const int row = tid >> 6;
        uint2 ho = {0, 0}, lo = {0, 0};
        if (row < N_NODES) {
            const float4 v = ((const float4*)x)[tid];
            const unsigned short h0 = f2bf(v.x), h1 = f2bf(v.y);
            const unsigned short h2 = f2bf(v.z), h3 = f2bf(v.w);
            ho.x = (unsigned)h0 | ((unsigned)h1 << 16);
            ho.y = (unsigned)h2 | ((unsigned)h3 << 16);
            lo.x = (unsigned)f2bf(v.x - bf2f(h0)) |
                   ((unsigned)f2bf(v.y - bf2f(h1)) << 16);
            lo.y = (unsigned)f2bf(v.z - bf2f(h2)) |
                   ((unsigned)f2bf(v.w - bf2f(h3)) << 16);
        }
        ((uint2*)ph)[tid] = ho;
        ((uint2*)pl)[tid] = lo;
    } else if (b < 5312) {                  // ---- W^T hi/lo ----
        b -= 5056;
        const int half = b >= 128;
        if (half) b -= 128;
        const float* W = half ? W1 : W0;
        unsigned short* th = wth + half * 32768;
        unsigned short* tl = wtl + half * 32768;
        const int idx = b * 256 + t;        // idx = k*128 + n
        const int k = idx >> 7, n = idx & 127;
        const float v = W[idx];
        const unsigned short h = f2bf(v);
        th[n * 256 + k] = h;
        tl[n * 256 + k] = f2bf(v - bf2f(h));
    } else {                                // ---- histogram ----
        b -= 5312;
        const int* dst;
        int* h;
        if (b < 1250) { dst = d0; h = hist; }
        else { b -= 1250; dst = d1; h = hist + 10240; }
        atomicAdd(&h[dst[b * 256 + t]], 1);
    }
}

// ======= MFMA GEMM (bf16x2-split): sup = x@W + b; + fused scan ==============
// blocks [0,158): gemm (79/half, 128 rows x 128 cols); [158,160): scan.
__global__ __launch_bounds__(256) void k_gemmscan(const unsigned short* __restrict__ xh,
                                                  const unsigned short* __restrict__ xl,
                                                  const unsigned short* __restrict__ wth,
                                                  const unsigned short* __restrict__ wtl,
                                                  const float* __restrict__ b0,
                                                  const float* __restrict__ b1,
                                                  float* __restrict__ sup0,
                                                  float* __restrict__ sup1,
                                                  const int* __restrict__ hist_,
                                                  int* __restrict__ off_,
                                                  int* __restrict__ cur_) {
    __shared__ unsigned short Ah[128 * 32], Al[128 * 32];
    __shared__ unsigned short Bh[128 * 32], Bl[128 * 32];
    __shared__ int ss[256];
    const int b = blockIdx.x;
    const int t = threadIdx.x;
    if (b >= 158) {                         // ---- scan ----
        const int h = b - 158;
        const int* hist = hist_ + h * 10240;
        int* off = off_ + h * 10240;
        int* cur = cur_ + h * 10240;
        int loc[40];
        int sum = 0;
        const int base = t * 40;
#pragma unroll
        for (int i = 0; i < 40; i++) { loc[i] = hist[base + i]; sum += loc[i]; }
        ss[t] = sum;
        __syncthreads();
        for (int o = 1; o < 256; o <<= 1) {
            int v = (t >= o) ? ss[t - o] : 0;
            __syncthreads();
            ss[t] += v;
            __syncthreads();
        }
        int run = ss[t] - sum;
#pragma unroll
        for (int i = 0; i < 40; i++) {
            off[base + i] = run;
            cur[base + i] = run;
            run += loc[i];
        }
        return;
    }
    const int half = b >= 79;
    const int mt_ = half ? b - 79 : b;
    const unsigned short* xhp = xh + (size_t)half * NPAD2 * 256;
    const unsigned short* xlp = xl + (size_t)half * NPAD2 * 256;
    const unsigned short* bhp = wth + half * 32768;
    const unsigned short* blp = wtl + half * 32768;
    const float* bias = half ? b1 : b0;
    float* sup = half ? sup1 : sup0;
    const int i0 = mt_ * 128;
    const int wave = t >> 6, lane = t & 63;
    const int wi = wave >> 1, wj = wave & 1;
    const int m = lane & 15, kq = lane >> 4;
    const int srow = lane >> 2, scol = lane & 3;

    f32x4 acc[4][4];
#pragma unroll
    for (int r = 0; r < 4; r++)
#pragma unroll
        for (int c = 0; c < 4; c++) acc[r][c] = (f32x4){0.f, 0.f, 0.f, 0.f};

    for (int kt = 0; kt < 8; kt++) {
        const int k0 = kt * 32;
#pragma unroll
        for (int p = 0; p < 2; p++) {
            const int grp = wave * 2 + p;
            const size_t ra = (size_t)(i0 + grp * 16 + srow) * 256 + k0 + scol * 8;
            __builtin_amdgcn_global_load_lds(
                (const __attribute__((address_space(1))) void*)(xhp + ra),
                (__attribute__((address_space(3))) void*)(Ah + grp * 512), 16, 0, 0);
            __builtin_amdgcn_global_load_lds(
                (const __attribute__((address_space(1))) void*)(xlp + ra),
                (__attribute__((address_space(3))) void*)(Al + grp * 512), 16, 0, 0);
            const size_t rb = (size_t)(grp * 16 + srow) * 256 + k0 + scol * 8;
            __builtin_amdgcn_global_load_lds(
                (const __attribute__((address_space(1))) void*)(bhp + rb),
                (__attribute__((address_space(3))) void*)(Bh + grp * 512), 16, 0, 0);
            __builtin_amdgcn_global_load_lds(
                (const __attribute__((address_space(1))) void*)(blp + rb),
                (__attribute__((address_space(3))) void*)(Bl + grp * 512), 16, 0, 0);
        }
        __syncthreads();
        short8 ah[4], al[4], bh[4], bl[4];
#pragma unroll
        for (int mt = 0; mt < 4; mt++) {
            ah[mt] = *(const short8*)&Ah[(wi * 64 + mt * 16 + m) * 32 + kq * 8];
            al[mt] = *(const short8*)&Al[(wi * 64 + mt * 16 + m) * 32 + kq * 8];
        }
#pragma unroll
        for (int nt = 0; nt < 4; nt++) {
            bh[nt] = *(const short8*)&Bh[(wj * 64 + nt * 16 + m) * 32 + kq * 8];
            bl[nt] = *(const short8*)&Bl[(wj * 64 + nt * 16 + m) * 32 + kq * 8];
        }
#pragma unroll
        for (int mt = 0; mt < 4; mt++)
#pragma unroll
            for (int nt = 0; nt < 4; nt++) {
                acc[mt][nt] = __builtin_amdgcn_mfma_f32_16x16x32_bf16(
                    ah[mt], bh[nt], acc[mt][nt], 0, 0, 0);
                acc[mt][nt] = __builtin_amdgcn_mfma_f32_16x16x32_bf16(
                    ah[mt], bl[nt], acc[mt][nt], 0, 0, 0);
                acc[mt][nt] = __builtin_amdgcn_mfma_f32_16x16x32_bf16(
                    al[mt], bh[nt], acc[mt][nt], 0, 0, 0);
            }
        __syncthreads();
    }
    float bv[4];
#pragma unroll
    for (int nt = 0; nt < 4; nt++) bv[nt] = bias[wj * 64 + nt * 16 + m];
#pragma unroll
    for (int mt = 0; mt < 4; mt++)
#pragma unroll
        for (int nt = 0; nt < 4; nt++)
#pragma unroll
            for (int reg = 0; reg < 4; reg++) {
                const int row = i0 + wi * 64 + mt * 16 + kq * 4 + reg;
                if (row < N_NODES)
                    sup[(size_t)row * 128 + wj * 64 + nt * 16 + m] =
                        acc[mt][nt][reg] + bv[nt];
            }
}

// ------- reorder both halves: packed (src, val) -----------------------------
__global__ __launch_bounds__(256) void k_reorder2(const int* __restrict__ s0,
                                                  const int* __restrict__ d0,
                                                  const float* __restrict__ v0,
                                                  const int* __restrict__ s1,
                                                  const int* __restrict__ d1,
                                                  const float* __restrict__ v1,
                                                  int* __restrict__ cur,
                                                  int2* __restrict__ packed) {
    int b = blockIdx.x;
    const int *src, *dst;
    const float* val;
    int* c;
    int2* pk;
    if (b < 1250) { src = s0; dst = d0; val = v0; c = cur; pk = packed; }
    else { b -= 1250; src = s1; dst = d1; val = v1; c = cur + 10240; pk = packed + E_EDGES; }
    const int e = b * 256 + threadIdx.x;
    const int d = dst[e];
    const int p = atomicAdd(&c[d], 1);
    pk[p] = make_int2(src[e], __float_as_int(val[e]));
}

// ------- CSR aggregate + fused per-half L2 normalize, both halves -----------
__global__ __launch_bounds__(256) void k_agg2(const float* __restrict__ sup0,
                                              const float* __restrict__ sup1,
                                              const int* __restrict__ off_,
                                              const int* __restrict__ hist_,
                                              const int2* __restrict__ packed_,
                                              float* __restrict__ xall) {
    int b = blockIdx.x;
    const float* sup;
    const int *off, *hist;
    const int2* pk;
    int c;
    if (b < 2500) { sup = sup0; off = off_; hist = hist_; pk = packed_; c = 0; }
    else { b -= 2500; sup = sup1; off = off_ + 10240; hist = hist_ + 10240;
           pk = packed_ + E_EDGES; c = 1; }
    const int t = threadIdx.x;
    const int node = b * 4 + (t >> 6), lane = t & 63;
    const int s0 = off[node], cnt = hist[node];
    const float2* S2 = (const float2*)sup;
    float2 a0 = {0.f, 0.f}, a1 = {0.f, 0.f}, a2 = {0.f, 0.f}, a3 = {0.f, 0.f};
    int e = s0;
    const int end = s0 + cnt;
    for (; e + 3 < end; e += 4) {
        const int2 pA = pk[e],     pB = pk[e + 1];
        const int2 pC = pk[e + 2], pD = pk[e + 3];
        const float vA = __int_as_float(pA.y), vB = __int_as_float(pB.y);
        const float vC = __int_as_float(pC.y), vD = __int_as_float(pD.y);
        const float2 mA = S2[(size_t)pA.x * 64 + lane];
        const float2 mB = S2[(size_t)pB.x * 64 + lane];
        const float2 mC = S2[(size_t)pC.x * 64 + lane];
        const float2 mD = S2[(size_t)pD.x * 64 + lane];
        a0.x += mA.x * vA; a0.y += mA.y * vA;
        a1.x += mB.x * vB; a1.y += mB.y * vB;
        a2.x += mC.x * vC; a2.y += mC.y * vC;
        a3.x += mD.x * vD; a3.y += mD.y * vD;
    }
    for (; e < end; e++) {
        const int2 pA = pk[e];
        const float vA = __int_as_float(pA.y);
        const float2 mA = S2[(size_t)pA.x * 64 + lane];
        a0.x += mA.x * vA; a0.y += mA.y * vA;
    }
    a0.x += a1.x + a2.x + a3.x;
    a0.y += a1.y + a2.y + a3.y;
    const float s = wred64(a0.x * a0.x + a0.y * a0.y);
    const float inv = 1.0f / sqrtf(s);
    ((float2*)xall)[(size_t)node * 128 + c * 64 + lane] =
        make_float2(a0.x * inv, a0.y * inv);
}

// ------- fused: rn[i] = 1/||x_all[i]||, xbf row = bf16(x_all[i]*rn[i]) ------
__global__ __launch_bounds__(256) void k_rowtobf(const float* __restrict__ xall,
                                                 float* __restrict__ rn,
                                                 unsigned short* __restrict__ xbf) {
    const int t = threadIdx.x;
    const int row = blockIdx.x * 4 + (t >> 6), lane = t & 63;
    unsigned o0 = 0, o1 = 0;
    if (row < N_NODES) {
        const float4 v = ((const float4*)xall)[(size_t)row * 64 + lane];
        const float s = wred64(v.x * v.x + v.y * v.y + v.z * v.z + v.w * v.w);
        const float inv = 1.0f / sqrtf(s);
        if (lane == 0) rn[row] = inv;
        o0 = (unsigned)f2bf(v.x * inv) | ((unsigned)f2bf(v.y * inv) << 16);
        o1 = (unsigned)f2bf(v.z * inv) | ((unsigned)f2bf(v.w * inv) << 16);
    }
    ((uint2*)xbf)[(size_t)row * 64 + lane] = make_uint2(o0, o1);
}

// ======= mega-kernel: MFMA filter (blocks 0..3159) + MFMA pair losses =======
__global__ __launch_bounds__(256) void k_fp(const unsigned short* __restrict__ xbf,
                                            int* __restrict__ count,
                                            int* __restrict__ list,
                                            const int* __restrict__ train,
                                            const int* __restrict__ negidx,
                                            const int* __restrict__ na,
                                            const int* __restrict__ nb,
                                            const int* __restrict__ nl,
                                            const int* __restrict__ neg_row,
                                            float* __restrict__ neg_s,
                                            float* __restrict__ preal,
                                            float* __restrict__ plc) {
    __shared__ unsigned short As[128 * 32];
    __shared__ unsigned short Bs[128 * 32];
    __shared__ float wsum[4];
    const int b = blockIdx.x;
    const int t = threadIdx.x, wave = t >> 6, lane = t & 63;
    const int m = lane & 15, kq = lane >> 4;
    const int dreg = ((m >> 2) == kq) ? (m & 3) : -1;   // diag ownership

    if (b < NTRI2) {   // ================= filter =================
        const int u = b;
        int i = (int)((2.0 * TILES2 + 1.0 -
                       sqrt((2.0 * TILES2 + 1.0) * (2.0 * TILES2 + 1.0) - 8.0 * (double)u)) * 0.5);
        if (i < 0) i = 0;
        while ((i + 1) * TILES2 - ((i + 1) * i) / 2 <= u) i++;
        while (i * TILES2 - (i * (i - 1)) / 2 > u) i--;
        const int ti = i;
        const int tj = i + (u - (i * TILES2 - (i * (i - 1)) / 2));

        const int wi = wave >> 1, wj = wave & 1;
        const int i0 = ti * 128, j0 = tj * 128;
        const int srow = lane >> 2, scol = lane & 3;

        f32x4 acc[4][4];
#pragma unroll
        for (int r = 0; r < 4; r++)
#pragma unroll
            for (int c = 0; c < 4; c++) acc[r][c] = (f32x4){0.f, 0.f, 0.f, 0.f};

        for (int kt = 0; kt < 8; kt++) {
            const int k0 = kt * 32;
#pragma unroll
            for (int p = 0; p < 2; p++) {
                const int grp = wave * 2 + p;
                const size_t ga = (size_t)(i0 + grp * 16 + srow) * 256 + k0 + scol * 8;
                __builtin_amdgcn_global_load_lds(
                    (const __attribute__((address_space(1))) void*)(xbf + ga),
                    (__attribute__((address_space(3))) void*)(As + grp * 512), 16, 0, 0);
                const size_t gb = (size_t)(j0 + grp * 16 + srow) * 256 + k0 + scol * 8;
                __builtin_amdgcn_global_load_lds(
                    (const __attribute__((address_space(1))) void*)(xbf + gb),
                    (__attribute__((address_space(3))) void*)(Bs + grp * 512), 16, 0, 0);
            }
            __syncthreads();
            short8 af[4], bfr[4];
#pragma unroll
            for (int mt = 0; mt < 4; mt++)
                af[mt] = *(const short8*)&As[(wi * 64 + mt * 16 + m) * 32 + kq * 8];
#pragma unroll
            for (int nt = 0; nt < 4; nt++)
                bfr[nt] = *(const short8*)&Bs[(wj * 64 + nt * 16 + m) * 32 + kq * 8];
#pragma unroll
            for (int mt = 0; mt < 4; mt++)
#pragma unroll
                for (int nt = 0; nt < 4; nt++)
                    acc[mt][nt] = __builtin_amdgcn_mfma_f32_16x16x32_bf16(
                        af[mt], bfr[nt], acc[mt][nt], 0, 0, 0);
            __syncthreads();
        }

        bool hit = false;
        const int rbase = i0 + wi * 64 + kq * 4;
        const int cbase = j0 + wj * 64 + m;
#pragma unroll
        for (int mt = 0; mt < 4; mt++)
#pragma unroll
            for (int nt = 0; nt < 4; nt++) {
                const f32x4 a = acc[mt][nt];
#pragma unroll
                for (int reg = 0; reg < 4; reg++) {
                    if (a[reg] > 0.94f) {
                        const int ii = rbase + mt * 16 + reg;
                        const int jj = cbase + nt * 16;
                        if (jj > ii && ii < N_NODES && jj < N_NODES) hit = true;
                    }
                }
            }
        if (__ballot(hit) != 0ull && lane == 0) {
            const int slot = atomicAdd(count, 1);
            list[slot] = ((ti * 2 + wi) << 16) | (tj * 2 + wj);   // 64-tile coords
        }
        return;
    }

    const int ridx = b - NTRI2;
    if (ridx < RB) {   // ================= loss_real =================
        const int g = ridx * 4 + wave;
        float sum = 0.f;
        if (g < 6250) {
            const int p = g * 16 + m;
            const int2 se = ((const int2*)train)[p];
            const int ng = negidx[p];
            const unsigned short* pa = xbf + (size_t)se.x * 256 + kq * 8;
            const unsigned short* pb = xbf + (size_t)se.y * 256 + kq * 8;
            const unsigned short* pc = xbf + (size_t)ng * 256 + kq * 8;
            f32x4 P = {0.f, 0.f, 0.f, 0.f}, Q = P;
#pragma unroll
            for (int kt = 0; kt < 8; kt++) {
                const short8 a  = *(const short8*)(pa + kt * 32);
                const short8 bb = *(const short8*)(pb + kt * 32);
                const short8 cc = *(const short8*)(pc + kt * 32);
                P = __builtin_amdgcn_mfma_f32_16x16x32_bf16(a, bb, P, 0, 0, 0);
                Q = __builtin_amdgcn_mfma_f32_16x16x32_bf16(a, cc, Q, 0, 0, 0);
            }
            if (dreg >= 0) {
                const float pos = P[dreg], neg = Q[dreg];
                const float d0 = (pos - 0.1f) * (1.0f / 0.9f);
                sum = d0 * d0 * log1pf(expf(neg - pos));
            }
        }
        sum = wred64(sum);
        if (lane == 0) wsum[wave] = sum;
        __syncthreads();
        if (t == 0) preal[ridx] = wsum[0] + wsum[1] + wsum[2] + wsum[3];
    } else if (ridx < RB + LB) {   // ================= lc =================
        const int bi = ridx - RB;
        const int g = bi * 4 + wave;
        float sum = 0.f;
        if (g < 938) {
            const int p = g * 16 + m;
            const bool valid = p < P_PAIRS;
            const int pc_ = valid ? p : (P_PAIRS - 1);
            const int a_ = na[pc_], b_ = nb[pc_];
            const unsigned short* pa = xbf + (size_t)a_ * 256 + kq * 8;
            const unsigned short* pb = xbf + (size_t)b_ * 256 + kq * 8;
            f32x4 P = {0.f, 0.f, 0.f, 0.f};
#pragma unroll
            for (int kt = 0; kt < 8; kt++) {
                const short8 a  = *(const short8*)(pa + kt * 32);
                const short8 bb = *(const short8*)(pb + kt * 32);
                P = __builtin_amdgcn_mfma_f32_16x16x32_bf16(a, bb, P, 0, 0, 0);
            }
            if (dreg >= 0 && valid) {
                const float sim = P[dreg];
                const float z = sim * 2.0f;                 // sim / TAU0
                const float logsig = -log1pf(expf(-z));
                const float gw = ldexpf(1.0f, -(nl[pc_] + 1));
                sum = gw * logsig;
            }
        }
        sum = wred64(sum);
        if (lane == 0) wsum[wave] = sum;
        __syncthreads();
        if (t == 0) plc[bi] = wsum[0] + wsum[1] + wsum[2] + wsum[3];
    } else {   // ================= neg_s =================
        const int bi = ridx - RB - LB;
        const int g = bi * 4 + wave;
        if (g < 625) {
            const int node = g * 16 + m;
            const int j = neg_row[node];
            const unsigned short* pa = xbf + (size_t)node * 256 + kq * 8;
            const unsigned short* pb = xbf + (size_t)j * 256 + kq * 8;
            f32x4 P = {0.f, 0.f, 0.f, 0.f};
#pragma unroll
            for (int kt = 0; kt < 8; kt++) {
                const short8 a  = *(const short8*)(pa + kt * 32);
                const short8 bb = *(const short8*)(pb + kt * 32);
                P = __builtin_amdgcn_mfma_f32_16x16x32_bf16(a, bb, P, 0, 0, 0);
            }
            if (dreg >= 0) neg_s[node] = P[dreg];
        }
    }
}

// ------------- phase B: exact fp32 recompute of flagged 64x64 tiles ---------
__global__ __launch_bounds__(256) void k_exact(const float* __restrict__ xall,
                                               const float* __restrict__ rn,
                                               const float* __restrict__ neg_s,
                                               const int* __restrict__ count,
                                               const int* __restrict__ list,
                                               float* __restrict__ pexact) {
    __shared__ float As[64 * 36];
    __shared__ float Bs[64 * 36];
    __shared__ float wsum[4];
    const int t = threadIdx.x;
    const int tx = t & 15, ty = t >> 4;
    const int li = t >> 2, kg = t & 3;
    const float4* X4 = (const float4*)xall;
    const int cnt = *count;
    float total = 0.0f;

    for (int idx = blockIdx.x; idx < cnt; idx += EXACT_BLOCKS) {
        const int pk = list[idx];
        const int ti = pk >> 16, tj = pk & 0xffff;
        const int i0 = ti * 64, j0 = tj * 64;
        float acc[4][4] = {};
        for (int kt = 0; kt < 8; kt++) {
            {
                const int gi = i0 + li;
                float4 v0 = {0, 0, 0, 0}, v1 = {0, 0, 0, 0};
                if (gi < N_NODES) {
                    v0 = X4[gi * 64 + kt * 8 + kg * 2];
                    v1 = X4[gi * 64 + kt * 8 + kg * 2 + 1];
                }
                *(float4*)&As[li * 36 + kg * 8]     = v0;
                *(float4*)&As[li * 36 + kg * 8 + 4] = v1;
                const int gj = j0 + li;
                float4 w0 = {0, 0, 0, 0}, w1 = {0, 0, 0, 0};
                if (gj < N_NODES) {
                    w0 = X4[gj * 64 + kt * 8 + kg * 2];
                    w1 = X4[gj * 64 + kt * 8 + kg * 2 + 1];
                }
                *(float4*)&Bs[li * 36 + kg * 8]     = w0;
                *(float4*)&Bs[li * 36 + kg * 8 + 4] = w1;
            }
            __syncthreads();
#pragma unroll
            for (int k = 0; k < 32; k += 2) {
                float2 av[4], bv[4];
#pragma unroll
                for (int r = 0; r < 4; r++) {
                    av[r] = *(const float2*)&As[(ty * 4 + r) * 36 + k];
                    bv[r] = *(const float2*)&Bs[(tx * 4 + r) * 36 + k];
                }
#pragma unroll
                for (int r = 0; r < 4; r++)
#pragma unroll
                    for (int c = 0; c < 4; c++)
                        acc[r][c] += av[r].x * bv[c].x + av[r].y * bv[c].y;
            }
            __syncthreads();
        }
#pragma unroll
        for (int r = 0; r < 4; r++) {
            const int i = i0 + ty * 4 + r;
            if (i >= N_NODES) continue;
            const float rni = rn[i];
            const float nsi = neg_s[i];
#pragma unroll
            for (int c = 0; c < 4; c++) {
                const int j = j0 + tx * 4 + c;
                if (j < N_NODES && j > i) {
                    const float s = acc[r][c] * rni * rn[j];
                    if (s > 0.95f) {
                        const float d0 = (s - 0.1f) * (1.0f / 0.9f);
                        total += d0 * d0 * log1pf(expf(nsi - s));
                    }
                }
            }
        }
    }
    float red = wred64(total);
    if ((t & 63) == 0) wsum[t >> 6] = red;
    __syncthreads();
    if (t == 0) pexact[blockIdx.x] = wsum[0] + wsum[1] + wsum[2] + wsum[3];
}

// ------------- final reduction ----------------------------------------------
__global__ __launch_bounds__(256) void k_final(const float* __restrict__ preal,
                                               const float* __restrict__ pexact,
                                               const float* __restrict__ plc,
                                               float* __restrict__ out_loss) {
    __shared__ float wsum[4];
    const int t = threadIdx.x;
    float sr = 0.0f, sp = 0.0f, sl = 0.0f;
    for (int i = t; i < RB; i += 256) sr += preal[i];
    if (t < EXACT_BLOCKS) sp = pexact[t];
    if (t < LB) sl = plc[t];
    float contrib = sr + sp - sl * (1.0f / (float)P_PAIRS);
    contrib = wred64(contrib);
    if ((t & 63) == 0) wsum[t >> 6] = contrib;
    __syncthreads();
    if (t == 0) out_loss[0] = wsum[0] + wsum[1] + wsum[2] + wsum[3];
}

extern "C" void kernel_launch(void* const* d_in, const int* in_sizes, int n_in,
                              void* d_out, int out_size, void* d_ws, size_t ws_size,
                              hipStream_t stream) {
    const float* x0   = (const float*)d_in[0];
    const float* x1   = (const float*)d_in[1];
    const int*   a0s  = (const int*)d_in[2];
    const int*   a0d  = (const int*)d_in[3];
    const float* a0v  = (const float*)d_in[4];
    const int*   a1s  = (const int*)d_in[5];
    const int*   a1d  = (const int*)d_in[6];
    const float* a1v  = (const float*)d_in[7];
    const int*   trn  = (const int*)d_in[8];
    const int*   ngi  = (const int*)d_in[9];
    const int*   ngr  = (const int*)d_in[10];
    const int*   na   = (const int*)d_in[11];
    const int*   nb   = (const int*)d_in[12];
    const int*   nl   = (const int*)d_in[13];
    const float* W0   = (const float*)d_in[14];
    const float* b0   = (const float*)d_in[15];
    const float* W1   = (const float*)d_in[16];
    const float* b1   = (const float*)d_in[17];

    float* xall = (float*)d_out;                 // N x 256
    float* loss = xall + (size_t)N_NODES * 256;  // scalar

    float* ws = (float*)d_ws;
    size_t o = 0;
    float*          sup0  = ws;                       // union with xbf
    unsigned short* xbf   = (unsigned short*)ws;      // NPAD2 x 256 bf16
    o += 1294400;                                     // max(1280000, 1294336)
    float* sup1  = ws + o;           o += 1280000;
    unsigned short* xh  = (unsigned short*)(ws + o); o += 2588672;  // 2 halves
    unsigned short* xl  = (unsigned short*)(ws + o); o += 2588672;
    unsigned short* wth = (unsigned short*)(ws + o); o += 32768;
    unsigned short* wtl = (unsigned short*)(ws + o); o += 32768;
    int2*  packed= (int2*)(ws + o);  o += 1280000;    // 2 x E int2
    int*   hist  = (int*)(ws + o);   o += 20480;      // both halves
    int*   count = (int*)(ws + o);   o += 16;         // zeroed with hist
    int*   off   = (int*)(ws + o);   o += 20480;
    int*   cur   = (int*)(ws + o);   o += 20480;
    float* rn    = ws + o;           o += 10000;
    float* negs  = ws + o;           o += 10000;
    float* preal = ws + o;           o += RB;
    float* plc   = ws + o;           o += LB;
    float* pexact= ws + o;           o += EXACT_BLOCKS;
    int*   list  = (int*)(ws + o);   o += NTRI2 * 4 + 16;

    hipMemsetAsync(hist, 0, 20496 * sizeof(int), stream);   // hist both + count
    k_prep<<<7812, 256, 0, stream>>>(x0, x1, W0, W1, a0d, a1d,
                                     xh, xl, wth, wtl, hist);
    k_gemmscan<<<160, 256, 0, stream>>>(xh, xl, wth, wtl, b0, b1,
                                        sup0, sup1, hist, off, cur);
    k_reorder2<<<2500, 256, 0, stream>>>(a0s, a0d, a0v, a1s, a1d, a1v, cur, packed);
    k_agg2<<<5000, 256, 0, stream>>>(sup0, sup1, off, hist, packed, xall);
    k_rowtobf<<<2528, 256, 0, stream>>>(xall, rn, xbf);   // overwrites sup0
    k_fp<<<NTRI2 + RB + LB + NB, 256, 0, stream>>>(xbf, count, list, trn, ngi,
                                                   na, nb, nl, ngr,
                                                   negs, preal, plc);
    k_exact<<<EXACT_BLOCKS, 256, 0, stream>>>(xall, rn, negs, count, list, pexact);
    k_final<<<1, 256, 0, stream>>>(preal, pexact, plc, loss);
}

// Round 7
// 300.489 us; speedup vs baseline: 6.6245x; 1.0007x over previous
//
#include <hip/hip_runtime.h>
#include <math.h>

#define N_NODES 10000
#define E_EDGES 320000
#define M_TRAIN 100000
#define P_PAIRS 15000
#define TILES2  79            // 128-tile count: ceil(10000/128)
#define NTRI2   3160          // TILES2*(TILES2+1)/2
#define NPAD2   10112         // 79*128 padded rows
#define EXACT_BLOCKS 256
#define RB 1563               // real-loss blocks (6250 groups / 4 waves)
#define LB 235                // lc blocks (938 groups / 4 waves)
#define NB 157                // negs blocks (625 groups / 4 waves)
#define AGG_MAIN 5000
#define AGG_PAD  14           // zero 112 pad rows of xbf (3584 uint2 / 256)

typedef __attribute__((ext_vector_type(8))) short short8;   // 8 bf16 (4 VGPRs)
typedef __attribute__((ext_vector_type(4))) float f32x4;

__device__ __forceinline__ float wred64(float v) {
#pragma unroll
    for (int o = 32; o > 0; o >>= 1) v += __shfl_xor(v, o, 64);
    return v;
}

__device__ __forceinline__ unsigned short f2bf(float f) {   // RNE float->bf16
    unsigned u = __float_as_uint(f);
    u += 0x7fffu + ((u >> 16) & 1u);
    return (unsigned short)(u >> 16);
}
__device__ __forceinline__ float bf2f(unsigned short h) {
    return __uint_as_float((unsigned)h << 16);
}

// ======= prep: x hi/lo bf16 split + W^T hi/lo + edge histograms =============
// blocks [0,5056): x-split (2528/half); [5056,5312): W^T (128/half);
// [5312,7812): hist (1250/half)
__global__ __launch_bounds__(256) void k_prep(const float* __restrict__ x0,
                                              const float* __restrict__ x1,
                                              const float* __restrict__ W0,
                                              const float* __restrict__ W1,
                                              const int* __restrict__ d0,
                                              const int* __restrict__ d1,
                                              unsigned short* __restrict__ xh,
                                              unsigned short* __restrict__ xl,
                                              unsigned short* __restrict__ wth,
                                              unsigned short* __restrict__ wtl,
                                              int* __restrict__ hist) {
    int b = blockIdx.x;
    const int t = threadIdx.x;
    if (b < 5056) {                         // ---- x hi/lo split ----
        const int half = b >= 2528;
        if (half) b -= 2528;
        const float* x = half ? x1 : x0;
        unsigned short* ph = xh + (size_t)half * NPAD2 * 256;
        unsigned short* pl = xl + (size_t)half * NPAD2 * 256;
        const int tid = b * 256 + t;        // one float4 per thread
        const int row = tid >> 6;
        uint2 ho = {0, 0}, lo = {0, 0};
        if (row < N_NODES) {
            const float4 v = ((const float4*)x)[tid];
            const unsigned short h0 = f2bf(v.x), h1 = f2bf(v.y);
            const unsigned short h2 = f2bf(v.z), h3 = f2bf(v.w);
            ho.x = (unsigned)h0 | ((unsigned)h1 << 16);
            ho.y = (unsigned)h2 | ((unsigned)h3 << 16);
            lo.x = (unsigned)f2bf(v.x - bf2f(h0)) |
                   ((unsigned)f2bf(v.y - bf2f(h1)) << 16);
            lo.y = (unsigned)f2bf(v.z - bf2f(h2)) |
                   ((unsigned)f2bf(v.w - bf2f(h3)) << 16);
        }
        ((uint2*)ph)[tid] = ho;
        ((uint2*)pl)[tid] = lo;
    } else if (b < 5312) {                  // ---- W^T hi/lo ----
        b -= 5056;
        const int half = b >= 128;
        if (half) b -= 128;
        const float* W = half ? W1 : W0;
        unsigned short* th = wth + half * 32768;
        unsigned short* tl = wtl + half * 32768;
        const int idx = b * 256 + t;        // idx = k*128 + n
        const int k = idx >> 7, n = idx & 127;
        const float v = W[idx];
        const unsigned short h = f2bf(v);
        th[n * 256 + k] = h;
        tl[n * 256 + k] = f2bf(v - bf2f(h));
    } else {                                // ---- histogram ----
        b -= 5312;
        const int* dst;
        int* h;
        if (b < 1250) { dst = d0; h = hist; }
        else { b -= 1250; dst = d1; h = hist + 10240; }
        atomicAdd(&h[dst[b * 256 + t]], 1);
    }
}

// ======= MFMA GEMM (bf16x2-split), 64x64 tiles + fused scan =================
// blocks [0,632): gemm; [632,634): scan. XOR-swizzled LDS staging.
__global__ __launch_bounds__(256) void k_gemmscan(const unsigned short* __restrict__ xh,
                                                  const unsigned short* __restrict__ xl,
                                                  const unsigned short* __restrict__ wth,
                                                  const unsigned short* __restrict__ wtl,
                                                  const float* __restrict__ b0,
                                                  const float* __restrict__ b1,
                                                  float* __restrict__ sup0,
                                                  float* __restrict__ sup1,
                                                  const int* __restrict__ hist_,
                                                  int* __restrict__ off_,
                                                  int* __restrict__ cur_) {
    __shared__ unsigned short Ah[64 * 32], Al[64 * 32];
    __shared__ unsigned short Bh[64 * 32], Bl[64 * 32];
    __shared__ int ss[256];
    const int b = blockIdx.x;
    const int t = threadIdx.x;
    if (b >= 632) {                         // ---- scan ----
        const int h = b - 632;
        const int* hist = hist_ + h * 10240;
        int* off = off_ + h * 10240;
        int* cur = cur_ + h * 10240;
        int loc[40];
        int sum = 0;
        const int base = t * 40;
#pragma unroll
        for (int i = 0; i < 40; i++) { loc[i] = hist[base + i]; sum += loc[i]; }
        ss[t] = sum;
        __syncthreads();
        for (int o = 1; o < 256; o <<= 1) {
            int v = (t >= o) ? ss[t - o] : 0;
            __syncthreads();
            ss[t] += v;
            __syncthreads();
        }
        int run = ss[t] - sum;
#pragma unroll
        for (int i = 0; i < 40; i++) {
            off[base + i] = run;
            cur[base + i] = run;
            run += loc[i];
        }
        return;
    }
    const int half = b >= 316;
    const int r_ = half ? b - 316 : b;
    const int rt = r_ >> 1, ct = r_ & 1;
    const unsigned short* xhp = xh + (size_t)half * NPAD2 * 256;
    const unsigned short* xlp = xl + (size_t)half * NPAD2 * 256;
    const unsigned short* bhp = wth + half * 32768;
    const unsigned short* blp = wtl + half * 32768;
    const float* bias = half ? b1 : b0;
    float* sup = half ? sup1 : sup0;
    const int i0 = rt * 64, j0 = ct * 64;
    const int wave = t >> 6, lane = t & 63;
    const int wi = wave >> 1, wj = wave & 1;
    const int m = lane & 15, kq = lane >> 4;
    const int srow = lane >> 2, scol = lane & 3;
    const int skey = (srow >> 1) & 3;       // staging XOR key
    const int rkey = (m >> 1) & 3;          // read XOR key

    f32x4 acc[2][2];
#pragma unroll
    for (int r = 0; r < 2; r++)
#pragma unroll
        for (int c = 0; c < 2; c++) acc[r][c] = (f32x4){0.f, 0.f, 0.f, 0.f};

    for (int kt = 0; kt < 8; kt++) {
        const int k0 = kt * 32;
        const int grp = wave;               // 16-row group 0..3
        const size_t ra = (size_t)(i0 + grp * 16 + srow) * 256 + k0 + (scol ^ skey) * 8;
        __builtin_amdgcn_global_load_lds(
            (const __attribute__((address_space(1))) void*)(xhp + ra),
            (__attribute__((address_space(3))) void*)(Ah + grp * 512), 16, 0, 0);
        __builtin_amdgcn_global_load_lds(
            (const __attribute__((address_space(1))) void*)(xlp + ra),
            (__attribute__((address_space(3))) void*)(Al + grp * 512), 16, 0, 0);
        const size_t rb = (size_t)(j0 + grp * 16 + srow) * 256 + k0 + (scol ^ skey) * 8;
        __builtin_amdgcn_global_load_lds(
            (const __attribute__((address_space(1))) void*)(bhp + rb),
            (__attribute__((address_space(3))) void*)(Bh + grp * 512), 16, 0, 0);
        __builtin_amdgcn_global_load_lds(
            (const __attribute__((address_space(1))) void*)(blp + rb),
            (__attribute__((address_space(3))) void*)(Bl + grp * 512), 16, 0, 0);
        __syncthreads();
        short8 ah[2], al[2], bh[2], bl[2];
#pragma unroll
        for (int mt = 0; mt < 2; mt++) {
            const int ro = (wi * 32 + mt * 16 + m) * 32 + ((kq ^ rkey) * 8);
            ah[mt] = *(const short8*)&Ah[ro];
            al[mt] = *(const short8*)&Al[ro];
        }
#pragma unroll
        for (int nt = 0; nt < 2; nt++) {
            const int ro = (wj * 32 + nt * 16 + m) * 32 + ((kq ^ rkey) * 8);
            bh[nt] = *(const short8*)&Bh[ro];
            bl[nt] = *(const short8*)&Bl[ro];
        }
#pragma unroll
        for (int mt = 0; mt < 2; mt++)
#pragma unroll
            for (int nt = 0; nt < 2; nt++) {
                acc[mt][nt] = __builtin_amdgcn_mfma_f32_16x16x32_bf16(
                    ah[mt], bh[nt], acc[mt][nt], 0, 0, 0);
                acc[mt][nt] = __builtin_amdgcn_mfma_f32_16x16x32_bf16(
                    ah[mt], bl[nt], acc[mt][nt], 0, 0, 0);
                acc[mt][nt] = __builtin_amdgcn_mfma_f32_16x16x32_bf16(
                    al[mt], bh[nt], acc[mt][nt], 0, 0, 0);
            }
        __syncthreads();
    }
    float bv[2];
#pragma unroll
    for (int nt = 0; nt < 2; nt++) bv[nt] = bias[j0 + wj * 32 + nt * 16 + m];
#pragma unroll
    for (int mt = 0; mt < 2; mt++)
#pragma unroll
        for (int nt = 0; nt < 2; nt++)
#pragma unroll
            for (int reg = 0; reg < 4; reg++) {
                const int row = i0 + wi * 32 + mt * 16 + kq * 4 + reg;
                if (row < N_NODES)
                    sup[(size_t)row * 128 + j0 + wj * 32 + nt * 16 + m] =
                        acc[mt][nt][reg] + bv[nt];
            }
}

// ------- reorder both halves: packed (src, val) -----------------------------
__global__ __launch_bounds__(256) void k_reorder2(const int* __restrict__ s0,
                                                  const int* __restrict__ d0,
                                                  const float* __restrict__ v0,
                                                  const int* __restrict__ s1,
                                                  const int* __restrict__ d1,
                                                  const float* __restrict__ v1,
                                                  int* __restrict__ cur,
                                                  int2* __restrict__ packed) {
    int b = blockIdx.x;
    const int *src, *dst;
    const float* val;
    int* c;
    int2* pk;
    if (b < 1250) { src = s0; dst = d0; val = v0; c = cur; pk = packed; }
    else { b -= 1250; src = s1; dst = d1; val = v1; c = cur + 10240; pk = packed + E_EDGES; }
    const int e = b * 256 + threadIdx.x;
    const int d = dst[e];
    const int p = atomicAdd(&c[d], 1);
    pk[p] = make_int2(src[e], __float_as_int(val[e]));
}

// ------- CSR aggregate + per-half normalize + fused xbf write ---------------
// Block = 2 nodes x 2 halves (one wave each). Wave: half-wave pair processes
// 2 edges/step (float4 per lane), combined via shfl_xor(32). rn == 1/sqrt(2).
__global__ __launch_bounds__(256) void k_agg2(const float* __restrict__ sup0,
                                              const float* __restrict__ sup1,
                                              const int* __restrict__ off_,
                                              const int* __restrict__ hist_,
                                              const int2* __restrict__ packed_,
                                              float* __restrict__ xall,
                                              unsigned short* __restrict__ xbf) {
    const int b = blockIdx.x;
    const int t = threadIdx.x, wave = t >> 6, lane = t & 63;
    if (b >= AGG_MAIN) {                    // zero xbf pad rows
        const int idx = (b - AGG_MAIN) * 256 + t;
        ((uint2*)(xbf + (size_t)N_NODES * 256))[idx] = make_uint2(0u, 0u);
        return;
    }
    const int node = b * 2 + (wave >> 1);
    const int half = wave & 1;
    const int l = lane & 31, side = lane >> 5;
    const float4* S4 = (const float4*)(half ? sup1 : sup0);
    const int* off = off_ + half * 10240;
    const int* hist = hist_ + half * 10240;
    const int2* pk = packed_ + (size_t)half * E_EDGES;
    const int s0 = off[node], cnt = hist[node], end = s0 + cnt;
    float4 acc = {0.f, 0.f, 0.f, 0.f};
    int e = s0;
    for (; e + 3 < end; e += 4) {
        const int2 p0 = pk[e + side];
        const int2 p1 = pk[e + 2 + side];
        const float v0 = __int_as_float(p0.y), v1 = __int_as_float(p1.y);
        const float4 m0 = S4[(size_t)p0.x * 32 + l];
        const float4 m1 = S4[(size_t)p1.x * 32 + l];
        acc.x = fmaf(m0.x, v0, acc.x); acc.y = fmaf(m0.y, v0, acc.y);
        acc.z = fmaf(m0.z, v0, acc.z); acc.w = fmaf(m0.w, v0, acc.w);
        acc.x = fmaf(m1.x, v1, acc.x); acc.y = fmaf(m1.y, v1, acc.y);
        acc.z = fmaf(m1.z, v1, acc.z); acc.w = fmaf(m1.w, v1, acc.w);
    }
    for (; e < end; e += 2) {
        const int ee = e + side;
        if (ee < end) {
            const int2 p = pk[ee];
            const float v = __int_as_float(p.y);
            const float4 m = S4[(size_t)p.x * 32 + l];
            acc.x = fmaf(m.x, v, acc.x); acc.y = fmaf(m.y, v, acc.y);
            acc.z = fmaf(m.z, v, acc.z); acc.w = fmaf(m.w, v, acc.w);
        }
    }
    // combine the two half-wave partial sums (feature f = 4l+c)
    float4 full;
    full.x = acc.x + __shfl_xor(acc.x, 32, 64);
    full.y = acc.y + __shfl_xor(acc.y, 32, 64);
    full.z = acc.z + __shfl_xor(acc.z, 32, 64);
    full.w = acc.w + __shfl_xor(acc.w, 32, 64);
    float ssum = full.x * full.x + full.y * full.y + full.z * full.z + full.w * full.w;
#pragma unroll
    for (int o = 16; o > 0; o >>= 1) ssum += __shfl_xor(ssum, o, 64);
    const float inv = 1.0f / sqrtf(ssum);
    if (side == 0) {
        float4 ov;
        ov.x = full.x * inv; ov.y = full.y * inv;
        ov.z = full.z * inv; ov.w = full.w * inv;
        ((float4*)xall)[(size_t)node * 64 + half * 32 + l] = ov;
        const float s2 = 0.70710678118654752440f;   // 1/sqrt(2) == rn
        uint2 pv;
        pv.x = (unsigned)f2bf(ov.x * s2) | ((unsigned)f2bf(ov.y * s2) << 16);
        pv.y = (unsigned)f2bf(ov.z * s2) | ((unsigned)f2bf(ov.w * s2) << 16);
        ((uint2*)(xbf + (size_t)node * 256 + half * 128))[l] = pv;
    }
}

// ======= mega-kernel: MFMA filter (blocks 0..3159) + MFMA pair losses =======
__global__ __launch_bounds__(256) void k_fp(const unsigned short* __restrict__ xbf,
                                            int* __restrict__ count,
                                            int* __restrict__ list,
                                            const int* __restrict__ train,
                                            const int* __restrict__ negidx,
                                            const int* __restrict__ na,
                                            const int* __restrict__ nb,
                                            const int* __restrict__ nl,
                                            const int* __restrict__ neg_row,
                                            float* __restrict__ neg_s,
                                            float* __restrict__ preal,
                                            float* __restrict__ plc) {
    __shared__ unsigned short As[128 * 32];
    __shared__ unsigned short Bs[128 * 32];
    __shared__ float wsum[4];
    const int b = blockIdx.x;
    const int t = threadIdx.x, wave = t >> 6, lane = t & 63;
    const int m = lane & 15, kq = lane >> 4;
    const int dreg = ((m >> 2) == kq) ? (m & 3) : -1;   // diag ownership

    if (b < NTRI2) {   // ================= filter =================
        const int u = b;
        int i = (int)((2.0 * TILES2 + 1.0 -
                       sqrt((2.0 * TILES2 + 1.0) * (2.0 * TILES2 + 1.0) - 8.0 * (double)u)) * 0.5);
        if (i < 0) i = 0;
        while ((i + 1) * TILES2 - ((i + 1) * i) / 2 <= u) i++;
        while (i * TILES2 - (i * (i - 1)) / 2 > u) i--;
        const int ti = i;
        const int tj = i + (u - (i * TILES2 - (i * (i - 1)) / 2));

        const int wi = wave >> 1, wj = wave & 1;
        const int i0 = ti * 128, j0 = tj * 128;
        const int srow = lane >> 2, scol = lane & 3;
        const int skey = (srow >> 1) & 3;
        const int rkey = (m >> 1) & 3;

        f32x4 acc[4][4];
#pragma unroll
        for (int r = 0; r < 4; r++)
#pragma unroll
            for (int c = 0; c < 4; c++) acc[r][c] = (f32x4){0.f, 0.f, 0.f, 0.f};

        for (int kt = 0; kt < 8; kt++) {
            const int k0 = kt * 32;
#pragma unroll
            for (int p = 0; p < 2; p++) {
                const int grp = wave * 2 + p;
                const size_t ga = (size_t)(i0 + grp * 16 + srow) * 256 + k0 + (scol ^ skey) * 8;
                __builtin_amdgcn_global_load_lds(
                    (const __attribute__((address_space(1))) void*)(xbf + ga),
                    (__attribute__((address_space(3))) void*)(As + grp * 512), 16, 0, 0);
                const size_t gb = (size_t)(j0 + grp * 16 + srow) * 256 + k0 + (scol ^ skey) * 8;
                __builtin_amdgcn_global_load_lds(
                    (const __attribute__((address_space(1))) void*)(xbf + gb),
                    (__attribute__((address_space(3))) void*)(Bs + grp * 512), 16, 0, 0);
            }
            __syncthreads();
            short8 af[4], bfr[4];
#pragma unroll
            for (int mt = 0; mt < 4; mt++)
                af[mt] = *(const short8*)&As[(wi * 64 + mt * 16 + m) * 32 + ((kq ^ rkey) * 8)];
#pragma unroll
            for (int nt = 0; nt < 4; nt++)
                bfr[nt] = *(const short8*)&Bs[(wj * 64 + nt * 16 + m) * 32 + ((kq ^ rkey) * 8)];
#pragma unroll
            for (int mt = 0; mt < 4; mt++)
#pragma unroll
                for (int nt = 0; nt < 4; nt++)
                    acc[mt][nt] = __builtin_amdgcn_mfma_f32_16x16x32_bf16(
                        af[mt], bfr[nt], acc[mt][nt], 0, 0, 0);
            __syncthreads();
        }

        bool hit = false;
        const int rbase = i0 + wi * 64 + kq * 4;
        const int cbase = j0 + wj * 64 + m;
#pragma unroll
        for (int mt = 0; mt < 4; mt++)
#pragma unroll
            for (int nt = 0; nt < 4; nt++) {
                const f32x4 a = acc[mt][nt];
#pragma unroll
                for (int reg = 0; reg < 4; reg++) {
                    if (a[reg] > 0.94f) {
                        const int ii = rbase + mt * 16 + reg;
                        const int jj = cbase + nt * 16;
                        if (jj > ii && ii < N_NODES && jj < N_NODES) hit = true;
                    }
                }
            }
        if (__ballot(hit) != 0ull && lane == 0) {
            const int slot = atomicAdd(count, 1);
            list[slot] = ((ti * 2 + wi) << 16) | (tj * 2 + wj);   // 64-tile coords
        }
        return;
    }

    const int ridx = b - NTRI2;
    if (ridx < RB) {   // ================= loss_real =================
        const int g = ridx * 4 + wave;
        float sum = 0.f;
        if (g < 6250) {
            const int p = g * 16 + m;
            const int2 se = ((const int2*)train)[p];
            const int ng = negidx[p];
            const unsigned short* pa = xbf + (size_t)se.x * 256 + kq * 8;
            const unsigned short* pb = xbf + (size_t)se.y * 256 + kq * 8;
            const unsigned short* pc = xbf + (size_t)ng * 256 + kq * 8;
            f32x4 P = {0.f, 0.f, 0.f, 0.f}, Q = P;
#pragma unroll
            for (int kt = 0; kt < 8; kt++) {
                const short8 a  = *(const short8*)(pa + kt * 32);
                const short8 bb = *(const short8*)(pb + kt * 32);
                const short8 cc = *(const short8*)(pc + kt * 32);
                P = __builtin_amdgcn_mfma_f32_16x16x32_bf16(a, bb, P, 0, 0, 0);
                Q = __builtin_amdgcn_mfma_f32_16x16x32_bf16(a, cc, Q, 0, 0, 0);
            }
            if (dreg >= 0) {
                const float pos = P[dreg], neg = Q[dreg];
                const float d0 = (pos - 0.1f) * (1.0f / 0.9f);
                sum = d0 * d0 * log1pf(expf(neg - pos));
            }
        }
        sum = wred64(sum);
        if (lane == 0) wsum[wave] = sum;
        __syncthreads();
        if (t == 0) preal[ridx] = wsum[0] + wsum[1] + wsum[2] + wsum[3];
    } else if (ridx < RB + LB) {   // ================= lc =================
        const int bi = ridx - RB;
        const int g = bi * 4 + wave;
        float sum = 0.f;
        if (g < 938) {
            const int p = g * 16 + m;
            const bool valid = p < P_PAIRS;
            const int pc_ = valid ? p : (P_PAIRS - 1);
            const int a_ = na[pc_], b_ = nb[pc_];
            const unsigned short* pa = xbf + (size_t)a_ * 256 + kq * 8;
            const unsigned short* pb = xbf + (size_t)b_ * 256 + kq * 8;
            f32x4 P = {0.f, 0.f, 0.f, 0.f};
#pragma unroll
            for (int kt = 0; kt < 8; kt++) {
                const short8 a  = *(const short8*)(pa + kt * 32);
                const short8 bb = *(const short8*)(pb + kt * 32);
                P = __builtin_amdgcn_mfma_f32_16x16x32_bf16(a, bb, P, 0, 0, 0);
            }
            if (dreg >= 0 && valid) {
                const float sim = P[dreg];
                const float z = sim * 2.0f;                 // sim / TAU0
                const float logsig = -log1pf(expf(-z));
                const float gw = ldexpf(1.0f, -(nl[pc_] + 1));
                sum = gw * logsig;
            }
        }
        sum = wred64(sum);
        if (lane == 0) wsum[wave] = sum;
        __syncthreads();
        if (t == 0) plc[bi] = wsum[0] + wsum[1] + wsum[2] + wsum[3];
    } else {   // ================= neg_s =================
        const int bi = ridx - RB - LB;
        const int g = bi * 4 + wave;
        if (g < 625) {
            const int node = g * 16 + m;
            const int j = neg_row[node];
            const unsigned short* pa = xbf + (size_t)node * 256 + kq * 8;
            const unsigned short* pb = xbf + (size_t)j * 256 + kq * 8;
            f32x4 P = {0.f, 0.f, 0.f, 0.f};
#pragma unroll
            for (int kt = 0; kt < 8; kt++) {
                const short8 a  = *(const short8*)(pa + kt * 32);
                const short8 bb = *(const short8*)(pb + kt * 32);
                P = __builtin_amdgcn_mfma_f32_16x16x32_bf16(a, bb, P, 0, 0, 0);
            }
            if (dreg >= 0) neg_s[node] = P[dreg];
        }
    }
}

// ------- phase B: exact fp32 recompute of flagged tiles + fused final -------
__global__ __launch_bounds__(256) void k_exact(const float* __restrict__ xall,
                                               const float* __restrict__ neg_s,
                                               const int* __restrict__ count,
                                               const int* __restrict__ list,
                                               float* __restrict__ pexact,
                                               const float* __restrict__ preal,
                                               const float* __restrict__ plc,
                                               int* __restrict__ donecnt,
                                               float* __restrict__ out_loss) {
    __shared__ float As[64 * 36];
    __shared__ float Bs[64 * 36];
    __shared__ float wsum[4];
    __shared__ int amlast;
    const int t = threadIdx.x;
    const int tx = t & 15, ty = t >> 4;
    const int li = t >> 2, kg = t & 3;
    const float4* X4 = (const float4*)xall;
    const int cnt = *count;
    float total = 0.0f;

    for (int idx = blockIdx.x; idx < cnt; idx += EXACT_BLOCKS) {
        const int pk = list[idx];
        const int ti = pk >> 16, tj = pk & 0xffff;
        const int i0 = ti * 64, j0 = tj * 64;
        float acc[4][4] = {};
        for (int kt = 0; kt < 8; kt++) {
            {
                const int gi = i0 + li;
                float4 v0 = {0, 0, 0, 0}, v1 = {0, 0, 0, 0};
                if (gi < N_NODES) {
                    v0 = X4[gi * 64 + kt * 8 + kg * 2];
                    v1 = X4[gi * 64 + kt * 8 + kg * 2 + 1];
                }
                *(float4*)&As[li * 36 + kg * 8]     = v0;
                *(float4*)&As[li * 36 + kg * 8 + 4] = v1;
                const int gj = j0 + li;
                float4 w0 = {0, 0, 0, 0}, w1 = {0, 0, 0, 0};
                if (gj < N_NODES) {
                    w0 = X4[gj * 64 + kt * 8 + kg * 2];
                    w1 = X4[gj * 64 + kt * 8 + kg * 2 + 1];
                }
                *(float4*)&Bs[li * 36 + kg * 8]     = w0;
                *(float4*)&Bs[li * 36 + kg * 8 + 4] = w1;
            }
            __syncthreads();
#pragma unroll
            for (int k = 0; k < 32; k += 2) {
                float2 av[4], bv[4];
#pragma unroll
                for (int r = 0; r < 4; r++) {
                    av[r] = *(const float2*)&As[(ty * 4 + r) * 36 + k];
                    bv[r] = *(const float2*)&Bs[(tx * 4 + r) * 36 + k];
                }
#pragma unroll
                for (int r = 0; r < 4; r++)
#pragma unroll
                    for (int c = 0; c < 4; c++)
                        acc[r][c] += av[r].x * bv[c].x + av[r].y * bv[c].y;
            }
            __syncthreads();
        }
#pragma unroll
        for (int r = 0; r < 4; r++) {
            const int i = i0 + ty * 4 + r;
            if (i >= N_NODES) continue;
            const float nsi = neg_s[i];
#pragma unroll
            for (int c = 0; c < 4; c++) {
                const int j = j0 + tx * 4 + c;
                if (j < N_NODES && j > i) {
                    const float s = acc[r][c] * 0.5f;   // rn_i*rn_j == 1/2
                    if (s > 0.95f) {
                        const float d0 = (s - 0.1f) * (1.0f / 0.9f);
                        total += d0 * d0 * log1pf(expf(nsi - s));
                    }
                }
            }
        }
    }
    float red = wred64(total);
    if ((t & 63) == 0) wsum[t >> 6] = red;
    __syncthreads();
    if (t == 0) {
        pexact[blockIdx.x] = wsum[0] + wsum[1] + wsum[2] + wsum[3];
        __threadfence();
        amlast = (atomicAdd(donecnt, 1) == EXACT_BLOCKS - 1);
    }
    __syncthreads();
    if (amlast) {                           // last block: final reduction
        __threadfence();
        float sr = 0.0f, sp = 0.0f, sl = 0.0f;
        for (int i = t; i < RB; i += 256) sr += preal[i];
        if (t < EXACT_BLOCKS) sp = pexact[t];
        if (t < LB) sl = plc[t];
        float contrib = sr + sp - sl * (1.0f / (float)P_PAIRS);
        contrib = wred64(contrib);
        if ((t & 63) == 0) wsum[t >> 6] = contrib;
        __syncthreads();
        if (t == 0) out_loss[0] = wsum[0] + wsum[1] + wsum[2] + wsum[3];
    }
}

extern "C" void kernel_launch(void* const* d_in, const int* in_sizes, int n_in,
                              void* d_out, int out_size, void* d_ws, size_t ws_size,
                              hipStream_t stream) {
    const float* x0   = (const float*)d_in[0];
    const float* x1   = (const float*)d_in[1];
    const int*   a0s  = (const int*)d_in[2];
    const int*   a0d  = (const int*)d_in[3];
    const float* a0v  = (const float*)d_in[4];
    const int*   a1s  = (const int*)d_in[5];
    const int*   a1d  = (const int*)d_in[6];
    const float* a1v  = (const float*)d_in[7];
    const int*   trn  = (const int*)d_in[8];
    const int*   ngi  = (const int*)d_in[9];
    const int*   ngr  = (const int*)d_in[10];
    const int*   na   = (const int*)d_in[11];
    const int*   nb   = (const int*)d_in[12];
    const int*   nl   = (const int*)d_in[13];
    const float* W0   = (const float*)d_in[14];
    const float* b0   = (const float*)d_in[15];
    const float* W1   = (const float*)d_in[16];
    const float* b1   = (const float*)d_in[17];

    float* xall = (float*)d_out;                 // N x 256
    float* loss = xall + (size_t)N_NODES * 256;  // scalar

    float* ws = (float*)d_ws;
    size_t o = 0;
    float* sup0 = ws;                o += 1280000;
    float* sup1 = ws + o;            o += 1280000;
    unsigned short* xbf = (unsigned short*)(ws + o); o += 1294336;  // NPAD2x256 bf16
    unsigned short* xh  = (unsigned short*)(ws + o); o += 2588672;  // 2 halves
    unsigned short* xl  = (unsigned short*)(ws + o); o += 2588672;
    unsigned short* wth = (unsigned short*)(ws + o); o += 32768;
    unsigned short* wtl = (unsigned short*)(ws + o); o += 32768;
    int2*  packed= (int2*)(ws + o);  o += 1280000;    // 2 x E int2
    int*   hist  = (int*)(ws + o);   o += 20480;      // both halves
    int*   count = (int*)(ws + o);   o += 16;         // [0]=filter cnt, [1]=done
    int*   off   = (int*)(ws + o);   o += 20480;
    int*   cur   = (int*)(ws + o);   o += 20480;
    float* negs  = ws + o;           o += 10000;
    float* preal = ws + o;           o += RB;
    float* plc   = ws + o;           o += LB;
    float* pexact= ws + o;           o += EXACT_BLOCKS;
    int*   list  = (int*)(ws + o);   o += NTRI2 * 4 + 16;

    hipMemsetAsync(hist, 0, 20496 * sizeof(int), stream);   // hist both + counters
    k_prep<<<7812, 256, 0, stream>>>(x0, x1, W0, W1, a0d, a1d,
                                     xh, xl, wth, wtl, hist);
    k_gemmscan<<<634, 256, 0, stream>>>(xh, xl, wth, wtl, b0, b1,
                                        sup0, sup1, hist, off, cur);
    k_reorder2<<<2500, 256, 0, stream>>>(a0s, a0d, a0v, a1s, a1d, a1v, cur, packed);
    k_agg2<<<AGG_MAIN + AGG_PAD, 256, 0, stream>>>(sup0, sup1, off, hist, packed,
                                                   xall, xbf);
    k_fp<<<NTRI2 + RB + LB + NB, 256, 0, stream>>>(xbf, count, list, trn, ngi,
                                                   na, nb, nl, ngr,
                                                   negs, preal, plc);
    k_exact<<<EXACT_BLOCKS, 256, 0, stream>>>(xall, negs, count, list, pexact,
                                              preal, plc, count + 1, loss);
}

// Round 8
// 294.571 us; speedup vs baseline: 6.7576x; 1.0201x over previous
//
#include <hip/hip_runtime.h>
#include <math.h>

#define N_NODES 10000
#define E_EDGES 320000
#define M_TRAIN 100000
#define P_PAIRS 15000
#define TILES2  79            // 128-tile count: ceil(10000/128)
#define NTRI2   3160          // TILES2*(TILES2+1)/2
#define NPAD2   10112         // 79*128 padded rows
#define EXACT_BLOCKS 256
#define RB 1563               // real-loss blocks (6250 groups / 4 waves)
#define LB 235                // lc blocks (938 groups / 4 waves)
#define NB 157                // negs blocks (625 groups / 4 waves)
#define AGG_MAIN 5000
#define AGG_PAD  14           // zero 112 pad rows of xbf (3584 uint2 / 256)

typedef __attribute__((ext_vector_type(8))) short short8;   // 8 bf16 (4 VGPRs)
typedef __attribute__((ext_vector_type(4))) float f32x4;

__device__ __forceinline__ float wred64(float v) {
#pragma unroll
    for (int o = 32; o > 0; o >>= 1) v += __shfl_xor(v, o, 64);
    return v;
}

__device__ __forceinline__ unsigned short f2bf(float f) {   // RNE float->bf16
    unsigned u = __float_as_uint(f);
    u += 0x7fffu + ((u >> 16) & 1u);
    return (unsigned short)(u >> 16);
}
__device__ __forceinline__ float bf2f(unsigned short h) {
    return __uint_as_float((unsigned)h << 16);
}

// ======= prep: x hi/lo bf16 split + W^T hi/lo + edge histograms =============
__global__ __launch_bounds__(256) void k_prep(const float* __restrict__ x0,
                                              const float* __restrict__ x1,
                                              const float* __restrict__ W0,
                                              const float* __restrict__ W1,
                                              const int* __restrict__ d0,
                                              const int* __restrict__ d1,
                                              unsigned short* __restrict__ xh,
                                              unsigned short* __restrict__ xl,
                                              unsigned short* __restrict__ wth,
                                              unsigned short* __restrict__ wtl,
                                              int* __restrict__ hist) {
    int b = blockIdx.x;
    const int t = threadIdx.x;
    if (b < 5056) {                         // ---- x hi/lo split ----
        const int half = b >= 2528;
        if (half) b -= 2528;
        const float* x = half ? x1 : x0;
        unsigned short* ph = xh + (size_t)half * NPAD2 * 256;
        unsigned short* pl = xl + (size_t)half * NPAD2 * 256;
        const int tid = b * 256 + t;        // one float4 per thread
        const int row = tid >> 6;
        uint2 ho = {0, 0}, lo = {0, 0};
        if (row < N_NODES) {
            const float4 v = ((const float4*)x)[tid];
            const unsigned short h0 = f2bf(v.x), h1 = f2bf(v.y);
            const unsigned short h2 = f2bf(v.z), h3 = f2bf(v.w);
            ho.x = (unsigned)h0 | ((unsigned)h1 << 16);
            ho.y = (unsigned)h2 | ((unsigned)h3 << 16);
            lo.x = (unsigned)f2bf(v.x - bf2f(h0)) |
                   ((unsigned)f2bf(v.y - bf2f(h1)) << 16);
            lo.y = (unsigned)f2bf(v.z - bf2f(h2)) |
                   ((unsigned)f2bf(v.w - bf2f(h3)) << 16);
        }
        ((uint2*)ph)[tid] = ho;
        ((uint2*)pl)[tid] = lo;
    } else if (b < 5312) {                  // ---- W^T hi/lo ----
        b -= 5056;
        const int half = b >= 128;
        if (half) b -= 128;
        const float* W = half ? W1 : W0;
        unsigned short* th = wth + half * 32768;
        unsigned short* tl = wtl + half * 32768;
        const int idx = b * 256 + t;        // idx = k*128 + n
        const int k = idx >> 7, n = idx & 127;
        const float v = W[idx];
        const unsigned short h = f2bf(v);
        th[n * 256 + k] = h;
        tl[n * 256 + k] = f2bf(v - bf2f(h));
    } else {                                // ---- histogram ----
        b -= 5312;
        const int* dst;
        int* h;
        if (b < 1250) { dst = d0; h = hist; }
        else { b -= 1250; dst = d1; h = hist + 10240; }
        atomicAdd(&h[dst[b * 256 + t]], 1);
    }
}

// ======= MFMA GEMM (bf16x2-split), 64x64 tiles + fused scan =================
__global__ __launch_bounds__(256) void k_gemmscan(const unsigned short* __restrict__ xh,
                                                  const unsigned short* __restrict__ xl,
                                                  const unsigned short* __restrict__ wth,
                                                  const unsigned short* __restrict__ wtl,
                                                  const float* __restrict__ b0,
                                                  const float* __restrict__ b1,
                                                  float* __restrict__ sup0,
                                                  float* __restrict__ sup1,
                                                  const int* __restrict__ hist_,
                                                  int* __restrict__ off_,
                                                  int* __restrict__ cur_) {
    __shared__ unsigned short Ah[64 * 32], Al[64 * 32];
    __shared__ unsigned short Bh[64 * 32], Bl[64 * 32];
    __shared__ int ss[256];
    const int b = blockIdx.x;
    const int t = threadIdx.x;
    if (b >= 632) {                         // ---- scan ----
        const int h = b - 632;
        const int* hist = hist_ + h * 10240;
        int* off = off_ + h * 10240;
        int* cur = cur_ + h * 10240;
        int loc[40];
        int sum = 0;
        const int base = t * 40;
#pragma unroll
        for (int i = 0; i < 40; i++) { loc[i] = hist[base + i]; sum += loc[i]; }
        ss[t] = sum;
        __syncthreads();
        for (int o = 1; o < 256; o <<= 1) {
            int v = (t >= o) ? ss[t - o] : 0;
            __syncthreads();
            ss[t] += v;
            __syncthreads();
        }
        int run = ss[t] - sum;
#pragma unroll
        for (int i = 0; i < 40; i++) {
            off[base + i] = run;
            cur[base + i] = run;
            run += loc[i];
        }
        return;
    }
    const int half = b >= 316;
    const int r_ = half ? b - 316 : b;
    const int rt = r_ >> 1, ct = r_ & 1;
    const unsigned short* xhp = xh + (size_t)half * NPAD2 * 256;
    const unsigned short* xlp = xl + (size_t)half * NPAD2 * 256;
    const unsigned short* bhp = wth + half * 32768;
    const unsigned short* blp = wtl + half * 32768;
    const float* bias = half ? b1 : b0;
    float* sup = half ? sup1 : sup0;
    const int i0 = rt * 64, j0 = ct * 64;
    const int wave = t >> 6, lane = t & 63;
    const int wi = wave >> 1, wj = wave & 1;
    const int m = lane & 15, kq = lane >> 4;
    const int srow = lane >> 2, scol = lane & 3;
    const int skey = (srow >> 1) & 3;       // staging XOR key
    const int rkey = (m >> 1) & 3;          // read XOR key

    f32x4 acc[2][2];
#pragma unroll
    for (int r = 0; r < 2; r++)
#pragma unroll
        for (int c = 0; c < 2; c++) acc[r][c] = (f32x4){0.f, 0.f, 0.f, 0.f};

    for (int kt = 0; kt < 8; kt++) {
        const int k0 = kt * 32;
        const int grp = wave;               // 16-row group 0..3
        const size_t ra = (size_t)(i0 + grp * 16 + srow) * 256 + k0 + (scol ^ skey) * 8;
        __builtin_amdgcn_global_load_lds(
            (const __attribute__((address_space(1))) void*)(xhp + ra),
            (__attribute__((address_space(3))) void*)(Ah + grp * 512), 16, 0, 0);
        __builtin_amdgcn_global_load_lds(
            (const __attribute__((address_space(1))) void*)(xlp + ra),
            (__attribute__((address_space(3))) void*)(Al + grp * 512), 16, 0, 0);
        const size_t rb = (size_t)(j0 + grp * 16 + srow) * 256 + k0 + (scol ^ skey) * 8;
        __builtin_amdgcn_global_load_lds(
            (const __attribute__((address_space(1))) void*)(bhp + rb),
            (__attribute__((address_space(3))) void*)(Bh + grp * 512), 16, 0, 0);
        __builtin_amdgcn_global_load_lds(
            (const __attribute__((address_space(1))) void*)(blp + rb),
            (__attribute__((address_space(3))) void*)(Bl + grp * 512), 16, 0, 0);
        __syncthreads();
        short8 ah[2], al[2], bh[2], bl[2];
#pragma unroll
        for (int mt = 0; mt < 2; mt++) {
            const int ro = (wi * 32 + mt * 16 + m) * 32 + ((kq ^ rkey) * 8);
            ah[mt] = *(const short8*)&Ah[ro];
            al[mt] = *(const short8*)&Al[ro];
        }
#pragma unroll
        for (int nt = 0; nt < 2; nt++) {
            const int ro = (wj * 32 + nt * 16 + m) * 32 + ((kq ^ rkey) * 8);
            bh[nt] = *(const short8*)&Bh[ro];
            bl[nt] = *(const short8*)&Bl[ro];
        }
#pragma unroll
        for (int mt = 0; mt < 2; mt++)
#pragma unroll
            for (int nt = 0; nt < 2; nt++) {
                acc[mt][nt] = __builtin_amdgcn_mfma_f32_16x16x32_bf16(
                    ah[mt], bh[nt], acc[mt][nt], 0, 0, 0);
                acc[mt][nt] = __builtin_amdgcn_mfma_f32_16x16x32_bf16(
                    ah[mt], bl[nt], acc[mt][nt], 0, 0, 0);
                acc[mt][nt] = __builtin_amdgcn_mfma_f32_16x16x32_bf16(
                    al[mt], bh[nt], acc[mt][nt], 0, 0, 0);
            }
        __syncthreads();
    }
    float bv[2];
#pragma unroll
    for (int nt = 0; nt < 2; nt++) bv[nt] = bias[j0 + wj * 32 + nt * 16 + m];
#pragma unroll
    for (int mt = 0; mt < 2; mt++)
#pragma unroll
        for (int nt = 0; nt < 2; nt++)
#pragma unroll
            for (int reg = 0; reg < 4; reg++) {
                const int row = i0 + wi * 32 + mt * 16 + kq * 4 + reg;
                if (row < N_NODES)
                    sup[(size_t)row * 128 + j0 + wj * 32 + nt * 16 + m] =
                        acc[mt][nt][reg] + bv[nt];
            }
}

// ------- reorder both halves: packed (src, val) -----------------------------
__global__ __launch_bounds__(256) void k_reorder2(const int* __restrict__ s0,
                                                  const int* __restrict__ d0,
                                                  const float* __restrict__ v0,
                                                  const int* __restrict__ s1,
                                                  const int* __restrict__ d1,
                                                  const float* __restrict__ v1,
                                                  int* __restrict__ cur,
                                                  int2* __restrict__ packed) {
    int b = blockIdx.x;
    const int *src, *dst;
    const float* val;
    int* c;
    int2* pk;
    if (b < 1250) { src = s0; dst = d0; val = v0; c = cur; pk = packed; }
    else { b -= 1250; src = s1; dst = d1; val = v1; c = cur + 10240; pk = packed + E_EDGES; }
    const int e = b * 256 + threadIdx.x;
    const int d = dst[e];
    const int p = atomicAdd(&c[d], 1);
    pk[p] = make_int2(src[e], __float_as_int(val[e]));
}

// ------- CSR aggregate + per-half normalize + fused xbf write ---------------
__global__ __launch_bounds__(256) void k_agg2(const float* __restrict__ sup0,
                                              const float* __restrict__ sup1,
                                              const int* __restrict__ off_,
                                              const int* __restrict__ hist_,
                                              const int2* __restrict__ packed_,
                                              float* __restrict__ xall,
                                              unsigned short* __restrict__ xbf) {
    const int b = blockIdx.x;
    const int t = threadIdx.x, wave = t >> 6, lane = t & 63;
    if (b >= AGG_MAIN) {                    // zero xbf pad rows
        const int idx = (b - AGG_MAIN) * 256 + t;
        ((uint2*)(xbf + (size_t)N_NODES * 256))[idx] = make_uint2(0u, 0u);
        return;
    }
    const int node = b * 2 + (wave >> 1);
    const int half = wave & 1;
    const int l = lane & 31, side = lane >> 5;
    const float4* S4 = (const float4*)(half ? sup1 : sup0);
    const int* off = off_ + half * 10240;
    const int* hist = hist_ + half * 10240;
    const int2* pk = packed_ + (size_t)half * E_EDGES;
    const int s0 = off[node], cnt = hist[node], end = s0 + cnt;
    float4 acc = {0.f, 0.f, 0.f, 0.f};
    float4 acc2 = {0.f, 0.f, 0.f, 0.f};
    int e = s0;
    for (; e + 7 < end; e += 8) {           // 8 edges in flight (4 per side)
        const int2 p0 = pk[e + side];
        const int2 p1 = pk[e + 2 + side];
        const int2 p2 = pk[e + 4 + side];
        const int2 p3 = pk[e + 6 + side];
        const float v0 = __int_as_float(p0.y), v1 = __int_as_float(p1.y);
        const float v2 = __int_as_float(p2.y), v3 = __int_as_float(p3.y);
        const float4 m0 = S4[(size_t)p0.x * 32 + l];
        const float4 m1 = S4[(size_t)p1.x * 32 + l];
        const float4 m2 = S4[(size_t)p2.x * 32 + l];
        const float4 m3 = S4[(size_t)p3.x * 32 + l];
        acc.x  = fmaf(m0.x, v0, acc.x);  acc.y  = fmaf(m0.y, v0, acc.y);
        acc.z  = fmaf(m0.z, v0, acc.z);  acc.w  = fmaf(m0.w, v0, acc.w);
        acc2.x = fmaf(m1.x, v1, acc2.x); acc2.y = fmaf(m1.y, v1, acc2.y);
        acc2.z = fmaf(m1.z, v1, acc2.z); acc2.w = fmaf(m1.w, v1, acc2.w);
        acc.x  = fmaf(m2.x, v2, acc.x);  acc.y  = fmaf(m2.y, v2, acc.y);
        acc.z  = fmaf(m2.z, v2, acc.z);  acc.w  = fmaf(m2.w, v2, acc.w);
        acc2.x = fmaf(m3.x, v3, acc2.x); acc2.y = fmaf(m3.y, v3, acc2.y);
        acc2.z = fmaf(m3.z, v3, acc2.z); acc2.w = fmaf(m3.w, v3, acc2.w);
    }
    for (; e + 3 < end; e += 4) {
        const int2 p0 = pk[e + side];
        const int2 p1 = pk[e + 2 + side];
        const float v0 = __int_as_float(p0.y), v1 = __int_as_float(p1.y);
        const float4 m0 = S4[(size_t)p0.x * 32 + l];
        const float4 m1 = S4[(size_t)p1.x * 32 + l];
        acc.x  = fmaf(m0.x, v0, acc.x);  acc.y  = fmaf(m0.y, v0, acc.y);
        acc.z  = fmaf(m0.z, v0, acc.z);  acc.w  = fmaf(m0.w, v0, acc.w);
        acc2.x = fmaf(m1.x, v1, acc2.x); acc2.y = fmaf(m1.y, v1, acc2.y);
        acc2.z = fmaf(m1.z, v1, acc2.z); acc2.w = fmaf(m1.w, v1, acc2.w);
    }
    for (; e < end; e += 2) {
        const int ee = e + side;
        if (ee < end) {
            const int2 p = pk[ee];
            const float v = __int_as_float(p.y);
            const float4 m = S4[(size_t)p.x * 32 + l];
            acc.x = fmaf(m.x, v, acc.x); acc.y = fmaf(m.y, v, acc.y);
            acc.z = fmaf(m.z, v, acc.z); acc.w = fmaf(m.w, v, acc.w);
        }
    }
    acc.x += acc2.x; acc.y += acc2.y; acc.z += acc2.z; acc.w += acc2.w;
    // combine the two half-wave partial sums (feature f = 4l+c)
    float4 full;
    full.x = acc.x + __shfl_xor(acc.x, 32, 64);
    full.y = acc.y + __shfl_xor(acc.y, 32, 64);
    full.z = acc.z + __shfl_xor(acc.z, 32, 64);
    full.w = acc.w + __shfl_xor(acc.w, 32, 64);
    float ssum = full.x * full.x + full.y * full.y + full.z * full.z + full.w * full.w;
#pragma unroll
    for (int o = 16; o > 0; o >>= 1) ssum += __shfl_xor(ssum, o, 64);
    const float inv = 1.0f / sqrtf(ssum);
    if (side == 0) {
        float4 ov;
        ov.x = full.x * inv; ov.y = full.y * inv;
        ov.z = full.z * inv; ov.w = full.w * inv;
        ((float4*)xall)[(size_t)node * 64 + half * 32 + l] = ov;
        const float s2 = 0.70710678118654752440f;   // 1/sqrt(2) == rn
        uint2 pv;
        pv.x = (unsigned)f2bf(ov.x * s2) | ((unsigned)f2bf(ov.y * s2) << 16);
        pv.y = (unsigned)f2bf(ov.z * s2) | ((unsigned)f2bf(ov.w * s2) << 16);
        ((uint2*)(xbf + (size_t)node * 256 + half * 128))[l] = pv;
    }
}

// ======= mega-kernel: dbuf MFMA filter (blocks 0..3159) + MFMA pair losses ==
__global__ __launch_bounds__(256) void k_fp(const unsigned short* __restrict__ xbf,
                                            int* __restrict__ count,
                                            int* __restrict__ list,
                                            const int* __restrict__ train,
                                            const int* __restrict__ negidx,
                                            const int* __restrict__ na,
                                            const int* __restrict__ nb,
                                            const int* __restrict__ nl,
                                            const int* __restrict__ neg_row,
                                            float* __restrict__ neg_s,
                                            float* __restrict__ preal,
                                            float* __restrict__ plc) {
    __shared__ unsigned short As[2][128 * 32];
    __shared__ unsigned short Bs[2][128 * 32];
    __shared__ float wsum[4];
    const int b = blockIdx.x;
    const int t = threadIdx.x, wave = t >> 6, lane = t & 63;
    const int m = lane & 15, kq = lane >> 4;
    const int dreg = ((m >> 2) == kq) ? (m & 3) : -1;   // diag ownership

    if (b < NTRI2) {   // ================= filter =================
        const int u = b;
        int i = (int)((2.0 * TILES2 + 1.0 -
                       sqrt((2.0 * TILES2 + 1.0) * (2.0 * TILES2 + 1.0) - 8.0 * (double)u)) * 0.5);
        if (i < 0) i = 0;
        while ((i + 1) * TILES2 - ((i + 1) * i) / 2 <= u) i++;
        while (i * TILES2 - (i * (i - 1)) / 2 > u) i--;
        const int ti = i;
        const int tj = i + (u - (i * TILES2 - (i * (i - 1)) / 2));

        const int wi = wave >> 1, wj = wave & 1;
        const int i0 = ti * 128, j0 = tj * 128;
        const int srow = lane >> 2, scol = lane & 3;
        const int skey = (srow >> 1) & 3;
        const int rkey = (m >> 1) & 3;

        f32x4 acc[4][4];
#pragma unroll
        for (int r = 0; r < 4; r++)
#pragma unroll
            for (int c = 0; c < 4; c++) acc[r][c] = (f32x4){0.f, 0.f, 0.f, 0.f};

        // ---- stage kt=0 into buf 0 ----
#pragma unroll
        for (int p = 0; p < 2; p++) {
            const int grp = wave * 2 + p;
            const size_t ga = (size_t)(i0 + grp * 16 + srow) * 256 + 0 + (scol ^ skey) * 8;
            __builtin_amdgcn_global_load_lds(
                (const __attribute__((address_space(1))) void*)(xbf + ga),
                (__attribute__((address_space(3))) void*)(&As[0][grp * 512]), 16, 0, 0);
            const size_t gb = (size_t)(j0 + grp * 16 + srow) * 256 + 0 + (scol ^ skey) * 8;
            __builtin_amdgcn_global_load_lds(
                (const __attribute__((address_space(1))) void*)(xbf + gb),
                (__attribute__((address_space(3))) void*)(&Bs[0][grp * 512]), 16, 0, 0);
        }
        __syncthreads();

        for (int kt = 0; kt < 8; kt++) {
            const int buf = kt & 1;
            if (kt < 7) {                   // prefetch kt+1 into other buffer
                const int k0n = (kt + 1) * 32;
                const int nbuf = buf ^ 1;
#pragma unroll
                for (int p = 0; p < 2; p++) {
                    const int grp = wave * 2 + p;
                    const size_t ga = (size_t)(i0 + grp * 16 + srow) * 256 + k0n + (scol ^ skey) * 8;
                    __builtin_amdgcn_global_load_lds(
                        (const __attribute__((address_space(1))) void*)(xbf + ga),
                        (__attribute__((address_space(3))) void*)(&As[nbuf][grp * 512]), 16, 0, 0);
                    const size_t gb = (size_t)(j0 + grp * 16 + srow) * 256 + k0n + (scol ^ skey) * 8;
                    __builtin_amdgcn_global_load_lds(
                        (const __attribute__((address_space(1))) void*)(xbf + gb),
                        (__attribute__((address_space(3))) void*)(&Bs[nbuf][grp * 512]), 16, 0, 0);
                }
            }
            short8 af[4], bfr[4];
#pragma unroll
            for (int mt = 0; mt < 4; mt++)
                af[mt] = *(const short8*)&As[buf][(wi * 64 + mt * 16 + m) * 32 + ((kq ^ rkey) * 8)];
#pragma unroll
            for (int nt = 0; nt < 4; nt++)
                bfr[nt] = *(const short8*)&Bs[buf][(wj * 64 + nt * 16 + m) * 32 + ((kq ^ rkey) * 8)];
#pragma unroll
            for (int mt = 0; mt < 4; mt++)
#pragma unroll
                for (int nt = 0; nt < 4; nt++)
                    acc[mt][nt] = __builtin_amdgcn_mfma_f32_16x16x32_bf16(
                        af[mt], bfr[nt], acc[mt][nt], 0, 0, 0);
            __syncthreads();                // drains prefetch (hidden by compute)
        }

        bool hit = false;
        const int rbase = i0 + wi * 64 + kq * 4;
        const int cbase = j0 + wj * 64 + m;
#pragma unroll
        for (int mt = 0; mt < 4; mt++)
#pragma unroll
            for (int nt = 0; nt < 4; nt++) {
                const f32x4 a = acc[mt][nt];
#pragma unroll
                for (int reg = 0; reg < 4; reg++) {
                    if (a[reg] > 0.94f) {
                        const int ii = rbase + mt * 16 + reg;
                        const int jj = cbase + nt * 16;
                        if (jj > ii && ii < N_NODES && jj < N_NODES) hit = true;
                    }
                }
            }
        if (__ballot(hit) != 0ull && lane == 0) {
            const int slot = atomicAdd(count, 1);
            list[slot] = ((ti * 2 + wi) << 16) | (tj * 2 + wj);   // 64-tile coords
        }
        return;
    }

    const int ridx = b - NTRI2;
    if (ridx < RB) {   // ================= loss_real =================
        const int g = ridx * 4 + wave;
        float sum = 0.f;
        if (g < 6250) {
            const int p = g * 16 + m;
            const int2 se = ((const int2*)train)[p];
            const int ng = negidx[p];
            const unsigned short* pa = xbf + (size_t)se.x * 256 + kq * 8;
            const unsigned short* pb = xbf + (size_t)se.y * 256 + kq * 8;
            const unsigned short* pc = xbf + (size_t)ng * 256 + kq * 8;
            f32x4 P = {0.f, 0.f, 0.f, 0.f}, Q = P;
#pragma unroll
            for (int kt = 0; kt < 8; kt++) {
                const short8 a  = *(const short8*)(pa + kt * 32);
                const short8 bb = *(const short8*)(pb + kt * 32);
                const short8 cc = *(const short8*)(pc + kt * 32);
                P = __builtin_amdgcn_mfma_f32_16x16x32_bf16(a, bb, P, 0, 0, 0);
                Q = __builtin_amdgcn_mfma_f32_16x16x32_bf16(a, cc, Q, 0, 0, 0);
            }
            if (dreg >= 0) {
                const float pos = P[dreg], neg = Q[dreg];
                const float d0 = (pos - 0.1f) * (1.0f / 0.9f);
                sum = d0 * d0 * log1pf(expf(neg - pos));
            }
        }
        sum = wred64(sum);
        if (lane == 0) wsum[wave] = sum;
        __syncthreads();
        if (t == 0) preal[ridx] = wsum[0] + wsum[1] + wsum[2] + wsum[3];
    } else if (ridx < RB + LB) {   // ================= lc =================
        const int bi = ridx - RB;
        const int g = bi * 4 + wave;
        float sum = 0.f;
        if (g < 938) {
            const int p = g * 16 + m;
            const bool valid = p < P_PAIRS;
            const int pc_ = valid ? p : (P_PAIRS - 1);
            const int a_ = na[pc_], b_ = nb[pc_];
            const unsigned short* pa = xbf + (size_t)a_ * 256 + kq * 8;
            const unsigned short* pb = xbf + (size_t)b_ * 256 + kq * 8;
            f32x4 P = {0.f, 0.f, 0.f, 0.f};
#pragma unroll
            for (int kt = 0; kt < 8; kt++) {
                const short8 a  = *(const short8*)(pa + kt * 32);
                const short8 bb = *(const short8*)(pb + kt * 32);
                P = __builtin_amdgcn_mfma_f32_16x16x32_bf16(a, bb, P, 0, 0, 0);
            }
            if (dreg >= 0 && valid) {
                const float sim = P[dreg];
                const float z = sim * 2.0f;                 // sim / TAU0
                const float logsig = -log1pf(expf(-z));
                const float gw = ldexpf(1.0f, -(nl[pc_] + 1));
                sum = gw * logsig;
            }
        }
        sum = wred64(sum);
        if (lane == 0) wsum[wave] = sum;
        __syncthreads();
        if (t == 0) plc[bi] = wsum[0] + wsum[1] + wsum[2] + wsum[3];
    } else {   // ================= neg_s =================
        const int bi = ridx - RB - LB;
        const int g = bi * 4 + wave;
        if (g < 625) {
            const int node = g * 16 + m;
            const int j = neg_row[node];
            const unsigned short* pa = xbf + (size_t)node * 256 + kq * 8;
            const unsigned short* pb = xbf + (size_t)j * 256 + kq * 8;
            f32x4 P = {0.f, 0.f, 0.f, 0.f};
#pragma unroll
            for (int kt = 0; kt < 8; kt++) {
                const short8 a  = *(const short8*)(pa + kt * 32);
                const short8 bb = *(const short8*)(pb + kt * 32);
                P = __builtin_amdgcn_mfma_f32_16x16x32_bf16(a, bb, P, 0, 0, 0);
            }
            if (dreg >= 0) neg_s[node] = P[dreg];
        }
    }
}

// ------- phase B: exact fp32 recompute of flagged tiles + fused final -------
__global__ __launch_bounds__(256) void k_exact(const float* __restrict__ xall,
                                               const float* __restrict__ neg_s,
                                               const int* __restrict__ count,
                                               const int* __restrict__ list,
                                               float* __restrict__ pexact,
                                               const float* __restrict__ preal,
                                               const float* __restrict__ plc,
                                               int* __restrict__ donecnt,
                                               float* __restrict__ out_loss) {
    __shared__ float As[64 * 36];
    __shared__ float Bs[64 * 36];
    __shared__ float wsum[4];
    __shared__ int amlast;
    const int t = threadIdx.x;
    const int tx = t & 15, ty = t >> 4;
    const int li = t >> 2, kg = t & 3;
    const float4* X4 = (const float4*)xall;
    const int cnt = *count;
    float total = 0.0f;

    for (int idx = blockIdx.x; idx < cnt; idx += EXACT_BLOCKS) {
        const int pk = list[idx];
        const int ti = pk >> 16, tj = pk & 0xffff;
        const int i0 = ti * 64, j0 = tj * 64;
        float acc[4][4] = {};
        for (int kt = 0; kt < 8; kt++) {
            {
                const int gi = i0 + li;
                float4 v0 = {0, 0, 0, 0}, v1 = {0, 0, 0, 0};
                if (gi < N_NODES) {
                    v0 = X4[gi * 64 + kt * 8 + kg * 2];
                    v1 = X4[gi * 64 + kt * 8 + kg * 2 + 1];
                }
                *(float4*)&As[li * 36 + kg * 8]     = v0;
                *(float4*)&As[li * 36 + kg * 8 + 4] = v1;
                const int gj = j0 + li;
                float4 w0 = {0, 0, 0, 0}, w1 = {0, 0, 0, 0};
                if (gj < N_NODES) {
                    w0 = X4[gj * 64 + kt * 8 + kg * 2];
                    w1 = X4[gj * 64 + kt * 8 + kg * 2 + 1];
                }
                *(float4*)&Bs[li * 36 + kg * 8]     = w0;
                *(float4*)&Bs[li * 36 + kg * 8 + 4] = w1;
            }
            __syncthreads();
#pragma unroll
            for (int k = 0; k < 32; k += 2) {
                float2 av[4], bv[4];
#pragma unroll
                for (int r = 0; r < 4; r++) {
                    av[r] = *(const float2*)&As[(ty * 4 + r) * 36 + k];
                    bv[r] = *(const float2*)&Bs[(tx * 4 + r) * 36 + k];
                }
#pragma unroll
                for (int r = 0; r < 4; r++)
#pragma unroll
                    for (int c = 0; c < 4; c++)
                        acc[r][c] += av[r].x * bv[c].x + av[r].y * bv[c].y;
            }
            __syncthreads();
        }
#pragma unroll
        for (int r = 0; r < 4; r++) {
            const int i = i0 + ty * 4 + r;
            if (i >= N_NODES) continue;
            const float nsi = neg_s[i];
#pragma unroll
            for (int c = 0; c < 4; c++) {
                const int j = j0 + tx * 4 + c;
                if (j < N_NODES && j > i) {
                    const float s = acc[r][c] * 0.5f;   // rn_i*rn_j == 1/2
                    if (s > 0.95f) {
                        const float d0 = (s - 0.1f) * (1.0f / 0.9f);
                        total += d0 * d0 * log1pf(expf(nsi - s));
                    }
                }
            }
        }
    }
    float red = wred64(total);
    if ((t & 63) == 0) wsum[t >> 6] = red;
    __syncthreads();
    if (t == 0) {
        pexact[blockIdx.x] = wsum[0] + wsum[1] + wsum[2] + wsum[3];
        __threadfence();
        amlast = (atomicAdd(donecnt, 1) == EXACT_BLOCKS - 1);
    }
    __syncthreads();
    if (amlast) {                           // last block: final reduction
        __threadfence();
        float sr = 0.0f, sp = 0.0f, sl = 0.0f;
        for (int i = t; i < RB; i += 256) sr += preal[i];
        if (t < EXACT_BLOCKS) sp = pexact[t];
        if (t < LB) sl = plc[t];
        float contrib = sr + sp - sl * (1.0f / (float)P_PAIRS);
        contrib = wred64(contrib);
        if ((t & 63) == 0) wsum[t >> 6] = contrib;
        __syncthreads();
        if (t == 0) out_loss[0] = wsum[0] + wsum[1] + wsum[2] + wsum[3];
    }
}

extern "C" void kernel_launch(void* const* d_in, const int* in_sizes, int n_in,
                              void* d_out, int out_size, void* d_ws, size_t ws_size,
                              hipStream_t stream) {
    const float* x0   = (const float*)d_in[0];
    const float* x1   = (const float*)d_in[1];
    const int*   a0s  = (const int*)d_in[2];
    const int*   a0d  = (const int*)d_in[3];
    const float* a0v  = (const float*)d_in[4];
    const int*   a1s  = (const int*)d_in[5];
    const int*   a1d  = (const int*)d_in[6];
    const float* a1v  = (const float*)d_in[7];
    const int*   trn  = (const int*)d_in[8];
    const int*   ngi  = (const int*)d_in[9];
    const int*   ngr  = (const int*)d_in[10];
    const int*   na   = (const int*)d_in[11];
    const int*   nb   = (const int*)d_in[12];
    const int*   nl   = (const int*)d_in[13];
    const float* W0   = (const float*)d_in[14];
    const float* b0   = (const float*)d_in[15];
    const float* W1   = (const float*)d_in[16];
    const float* b1   = (const float*)d_in[17];

    float* xall = (float*)d_out;                 // N x 256
    float* loss = xall + (size_t)N_NODES * 256;  // scalar

    float* ws = (float*)d_ws;
    size_t o = 0;
    float* sup0 = ws;                o += 1280000;
    float* sup1 = ws + o;            o += 1280000;
    unsigned short* xbf = (unsigned short*)(ws + o); o += 1294336;  // NPAD2x256 bf16
    unsigned short* xh  = (unsigned short*)(ws + o); o += 2588672;  // 2 halves
    unsigned short* xl  = (unsigned short*)(ws + o); o += 2588672;
    unsigned short* wth = (unsigned short*)(ws + o); o += 32768;
    unsigned short* wtl = (unsigned short*)(ws + o); o += 32768;
    int2*  packed= (int2*)(ws + o);  o += 1280000;    // 2 x E int2
    int*   hist  = (int*)(ws + o);   o += 20480;      // both halves
    int*   count = (int*)(ws + o);   o += 16;         // [0]=filter cnt, [1]=done
    int*   off   = (int*)(ws + o);   o += 20480;
    int*   cur   = (int*)(ws + o);   o += 20480;
    float* negs  = ws + o;           o += 10000;
    float* preal = ws + o;           o += RB;
    float* plc   = ws + o;           o += LB;
    float* pexact= ws + o;           o += EXACT_BLOCKS;
    int*   list  = (int*)(ws + o);   o += NTRI2 * 4 + 16;

    hipMemsetAsync(hist, 0, 20496 * sizeof(int), stream);   // hist both + counters
    k_prep<<<7812, 256, 0, stream>>>(x0, x1, W0, W1, a0d, a1d,
                                     xh, xl, wth, wtl, hist);
    k_gemmscan<<<634, 256, 0, stream>>>(xh, xl, wth, wtl, b0, b1,
                                        sup0, sup1, hist, off, cur);
    k_reorder2<<<2500, 256, 0, stream>>>(a0s, a0d, a0v, a1s, a1d, a1v, cur, packed);
    k_agg2<<<AGG_MAIN + AGG_PAD, 256, 0, stream>>>(sup0, sup1, off, hist, packed,
                                                   xall, xbf);
    k_fp<<<NTRI2 + RB + LB + NB, 256, 0, stream>>>(xbf, count, list, trn, ngi,
                                                   na, nb, nl, ngr,
                                                   negs, preal, plc);
    k_exact<<<EXACT_BLOCKS, 256, 0, stream>>>(xall, negs, count, list, pexact,
                                              preal, plc, count + 1, loss);
}